// Round 6
// baseline (1411.314 us; speedup 1.0000x reference)
//
#include <hip/hip_runtime.h>
#include <hip/hip_bf16.h>

#define K 5
#define F 64
#define EMBD 200
#define HID 256
#define NH 3
#define NL 3
#define CB 8            // crystals per block for POOL kernels
#define NB (CB * K)     // 40 nodes per pool block

// layer kernel: 4 waves x 3 crystals = 12 crystals / block
#define CW 3            // crystals per wave
#define NWN (CW * K)    // 15 nodes per wave
#define EWE (CW * K * K) // 75 edges per wave
#define ET 5            // edge tiles of 16

typedef _Float16 half8 __attribute__((ext_vector_type(8)));
typedef _Float16 h2 __attribute__((ext_vector_type(2)));
typedef _Float16 h4 __attribute__((ext_vector_type(4)));
typedef __fp16 fp16x2 __attribute__((ext_vector_type(2)));
typedef float f32x4 __attribute__((ext_vector_type(4)));

__device__ __forceinline__ float lrelu(float v) { return v >= 0.f ? v : 0.01f * v; }

// cvt_pkrtz returns __fp16x2; bitcast to _Float16x2 (same bits, distinct clang types)
__device__ __forceinline__ h2 cvt_pk(float a, float b) {
    union { fp16x2 f; h2 h; } u;
    u.f = __builtin_amdgcn_cvt_pkrtz(a, b);
    return u.h;
}

__device__ __forceinline__ half8 lrelu8(half8 t) {
    half8 z = 0;
    half8 p = __builtin_elementwise_max(t, z);
    half8 n = __builtin_elementwise_min(t, z);
    return p + n * (_Float16)0.01f;
}

// ---- swizzled-weight element counts (fp16) ----
#define W1SW_ELEMS 589824    // 9 lh * 2 net * 2 half * 4 chunk * 4 nt * 2 ks * 64 * 8
#define W2SW_ELEMS 147456    // 9 lh * 8 ks2 * 4 nt * 64 * 8
#define CW1_ELEMS   98304    // 3 h * 2 net * 4 chunk * 4 nt * 2 ks * 64 * 8
#define CW2_ELEMS   49152    // 3 h * 8 ks2 * 4 nt * 64 * 8
#define WALL_ELEMS (W1SW_ELEMS + W2SW_ELEMS + CW1_ELEMS + CW2_ELEMS)  // 884736

// per-layer (fallback) sizes
#define W1L_ELEMS 196608
#define W2L_ELEMS 49152

// ---------------------------------------------------------------------------
// Fast path: swizzle ALL weights (layers + pool) fp32 -> fp16 B-frag order.
// ---------------------------------------------------------------------------
__global__ __launch_bounds__(256)
void prep_all(const float* __restrict__ gW1, const float* __restrict__ mW1,
              const float* __restrict__ mW2,
              const float* __restrict__ cgW1, const float* __restrict__ cmW1,
              const float* __restrict__ cmW2,
              _Float16* __restrict__ Wall)
{
    int tid = blockIdx.x * 256 + threadIdx.x;
    if (tid >= WALL_ELEMS) return;
    float v;
    if (tid < W1SW_ELEMS) {
        int j = tid & 7, lane = (tid >> 3) & 63;
        int r1 = tid >> 9;                       // [lh][net][half][chunk][nt][ks]
        int ks = r1 & 1, nt = (r1 >> 1) & 3, chunk = (r1 >> 3) & 3;
        int half = (r1 >> 5) & 1, net = (r1 >> 6) & 1, lh = r1 >> 7;   // 0..8
        int q = lane >> 4, n16 = lane & 15;
        const float* src = net ? mW1 : gW1;
        v = src[((size_t)lh * 128 + half * 64 + ks * 32 + q * 8 + j) * 256
                + chunk * 64 + nt * 16 + n16];
    } else if (tid < W1SW_ELEMS + W2SW_ELEMS) {
        int t2 = tid - W1SW_ELEMS;
        int j = t2 & 7, lane = (t2 >> 3) & 63;
        int r1 = t2 >> 9;                        // [lh][ks2][nt]
        int nt = r1 & 3, ks2 = (r1 >> 2) & 7, lh = r1 >> 5;            // 0..8
        int q = lane >> 4, n16 = lane & 15;
        v = mW2[((size_t)lh * 256 + ks2 * 32 + q * 8 + j) * 64 + nt * 16 + n16];
    } else if (tid < W1SW_ELEMS + W2SW_ELEMS + CW1_ELEMS) {
        int t2 = tid - (W1SW_ELEMS + W2SW_ELEMS);
        int j = t2 & 7, lane = (t2 >> 3) & 63;
        int r1 = t2 >> 9;                        // [h][net][chunk][nt][ks]
        int ks = r1 & 1, nt = (r1 >> 1) & 3, chunk = (r1 >> 3) & 3;
        int net = (r1 >> 5) & 1, h = r1 >> 6;                          // 0..2
        int q = lane >> 4, n16 = lane & 15;
        const float* src = net ? cmW1 : cgW1;
        v = src[((size_t)h * 64 + ks * 32 + q * 8 + j) * 256
                + chunk * 64 + nt * 16 + n16];
    } else {
        int t2 = tid - (W1SW_ELEMS + W2SW_ELEMS + CW1_ELEMS);
        int j = t2 & 7, lane = (t2 >> 3) & 63;
        int r1 = t2 >> 9;                        // [h][ks2][nt]
        int nt = r1 & 3, ks2 = (r1 >> 2) & 7, h = r1 >> 5;             // 0..2
        int q = lane >> 4, n16 = lane & 15;
        v = cmW2[((size_t)h * 256 + ks2 * 32 + q * 8 + j) * 64 + nt * 16 + n16];
    }
    Wall[tid] = (_Float16)v;
}

// ---------------------------------------------------------------------------
// Fallback: per-layer prep into d_out scratch (round-4 proven).
// ---------------------------------------------------------------------------
__global__ __launch_bounds__(256)
void prep_layer(const float* __restrict__ gW1, const float* __restrict__ mW1,
                const float* __restrict__ mW2,
                _Float16* __restrict__ W1sw, _Float16* __restrict__ W2sw, int l)
{
    int tid = blockIdx.x * 256 + threadIdx.x;
    if (tid < W1L_ELEMS) {
        int j = tid & 7, lane = (tid >> 3) & 63;
        int r1 = tid >> 9;
        int ks = r1 & 1, nt = (r1 >> 1) & 3, chunk = (r1 >> 3) & 3;
        int half = (r1 >> 5) & 1, net = (r1 >> 6) & 1, hh = r1 >> 7;
        int q = lane >> 4, n16 = lane & 15;
        const float* src = net ? mW1 : gW1;
        float v = src[((size_t)(l * NH + hh) * 128 + half * 64 + ks * 32 + q * 8 + j) * 256
                      + chunk * 64 + nt * 16 + n16];
        W1sw[tid] = (_Float16)v;
    } else {
        int t2 = tid - W1L_ELEMS;
        if (t2 < W2L_ELEMS) {
            int j = t2 & 7, lane = (t2 >> 3) & 63;
            int r1 = t2 >> 9;
            int nt = r1 & 3, ks2 = (r1 >> 2) & 7, hh = r1 >> 5;
            int q = lane >> 4, n16 = lane & 15;
            float v = mW2[((size_t)(l * NH + hh) * 256 + ks2 * 32 + q * 8 + j) * 64
                          + nt * 16 + n16];
            W2sw[t2] = (_Float16)v;
        }
    }
}

// ---------------------------------------------------------------------------
// Embedding — 16 nodes / 256-thread block; fea tile staged in LDS; thread
// (nl,o) computes 4 output cols {o, o+16, o+32, o+48} for node nl.
// ---------------------------------------------------------------------------
#define ENB 16   // nodes per embed block

__global__ __launch_bounds__(256)
void embed_kernel(const float* __restrict__ fea, const float* __restrict__ W,
                  const float* __restrict__ b, const float* __restrict__ wts,
                  float* __restrict__ x, int Ntot)
{
    __shared__ float fs[ENB * EMBD];
    const int t = threadIdx.x;
    const int node0 = blockIdx.x * ENB;
    int nvalid = Ntot - node0;
    if (nvalid > ENB) nvalid = ENB;
    if (nvalid <= 0) return;
    const int lim = nvalid * EMBD;
    for (int d = t; d < lim; d += 256) fs[d] = fea[(size_t)node0 * EMBD + d];
    __syncthreads();

    const int nl = t >> 4;          // local node 0..15
    const int o  = t & 15;          // output column group
    if (nl >= nvalid) return;
    const int n = node0 + nl;

    float acc[4];
#pragma unroll
    for (int k2 = 0; k2 < 4; ++k2) {
        int oc = o + 16 * k2;
        acc[k2] = (oc < F - 1) ? b[oc] : wts[n];
    }
    const float* fsr = fs + nl * EMBD;
#pragma unroll 4
    for (int e = 0; e < EMBD; ++e) {
        float xv = fsr[e];                       // quad-broadcast LDS read
        const float* wr = W + (size_t)e * (F - 1);
#pragma unroll
        for (int k2 = 0; k2 < 4; ++k2) {
            int oc = o + 16 * k2;
            if (oc < F - 1) acc[k2] += xv * wr[oc];
        }
    }
#pragma unroll
    for (int k2 = 0; k2 < 4; ++k2)
        x[(size_t)n * F + o + 16 * k2] = acc[k2];
}

// ---------------------------------------------------------------------------
// One graph layer — barrier-free, 4 independent waves / block, each wave owns
// 3 crystals (15 nodes, 75 edges). (256,2): 2 blocks/CU, occupancy 18%.
// Round 12 proven: transposed stage-1 mfma + packed b64 PQ writes + fdot2 gate.
//
// Round 13 (this round): break the chunk-pipeline WAR serialization.
//  - PQ DOUBLE-BUFFERED (ping-pong on chunk parity): chunk c+1's stage-1
//    (W1 loads + MFMAs + PQ writes) no longer aliases the PQ region that
//    chunk c's consume is reading, so the scheduler can overlap them.
//  - c-loop fully unrolled so the parity is compile-time and the scheduler
//    sees the whole head body. VGPR headroom 124->256 absorbs the pressure.
//  Wave slice 19136 B (2x9216 PQ + gate/anorm/wpow); block 76.5 KB; still
//  2 blocks/CU (153 KB < 160 KB). Spill tripwire: WRITE_SIZE must stay 12.5 MB.
// ---------------------------------------------------------------------------
#define WAVE_LDS 19136   // bytes per wave slice

__global__ __launch_bounds__(256, 2)
void layer_wave(float* __restrict__ x,
                const _Float16* __restrict__ W1sw,
                const _Float16* __restrict__ W2sw,
                const float* __restrict__ gb1, const float* __restrict__ gb2v,
                const float* __restrict__ mb1, const float* __restrict__ mb2,
                const float* __restrict__ gW2, const float* __restrict__ gpw,
                const float* __restrict__ wts, int l, int lhw0, int Ntot)
{
    __shared__ __align__(16) char smem[4 * WAVE_LDS];

    const int t = threadIdx.x, w = t >> 6, lane = t & 63;
    const int q = lane >> 4, m16 = lane & 15;

    char* wb = smem + w * WAVE_LDS;
    _Float16 (*PQ0)[16][72] = (_Float16 (*)[16][72])wb;          // [4][16][72] = 9216 B
    _Float16 (*PQ1)[16][72] = (_Float16 (*)[16][72])(wb + 9216); // ping-pong buffer
    _Float16 (*msgL)[72]    = (_Float16 (*)[72])wb;              // [80][72] aliases PQ bufs
    float* gateS  = (float*)(wb + 18432);                        // [80]
    float* anormS = (float*)(wb + 18752);                        // [80]
    float* wpowS  = (float*)(wb + 19072);                        // [16]

    const int nw0 = (blockIdx.x * 12 + w * CW) * K;      // first node of this wave
    const int vn  = (Ntot - nw0 < NWN) ? (Ntot - nw0) : NWN;  // valid nodes (may be <=0)

    // ---- A-fragments of x (head/half-invariant), fp16, loaded once ----
    half8 A[2];
    {
        int arow = nw0 + m16;
        if (arow > Ntot - 1) arow = Ntot - 1;            // clamp pad rows (finite junk)
        if (arow < 0) arow = 0;
        const float* xr = x + (size_t)arow * F;
#pragma unroll
        for (int ks = 0; ks < 2; ++ks) {
            float4 f0 = *(const float4*)(xr + ks * 32 + q * 8);
            float4 f1 = *(const float4*)(xr + ks * 32 + q * 8 + 4);
            half8 a;
            a[0] = (_Float16)f0.x; a[1] = (_Float16)f0.y;
            a[2] = (_Float16)f0.z; a[3] = (_Float16)f0.w;
            a[4] = (_Float16)f1.x; a[5] = (_Float16)f1.y;
            a[6] = (_Float16)f1.z; a[7] = (_Float16)f1.w;
            A[ks] = a;
        }
    }

    // ---- per-lane edge -> local node rows (75 valid edges in 5 tiles of 16) ----
    int iR[ET], jR[ET];
#pragma unroll
    for (int et = 0; et < ET; ++et) {
        int e = et * 16 + m16;
        if (e < EWE) {
            int cl = e / 25, rm = e % 25;
            iR[et] = cl * K + rm / K;
            jR[et] = cl * K + rm % K;
        } else { iR[et] = 15; jR[et] = 15; }             // pad row (clamped x, finite)
    }

    float oacc[NWN];
#pragma unroll
    for (int n = 0; n < NWN; ++n) oacc[n] = 0.f;

    for (int h = 0; h < NH; ++h) {
        const int lh = l * NH + h, lhw = lhw0 + h;

        if (lane < NWN) {
            int wi = nw0 + lane;
            if (wi > Ntot - 1) wi = Ntot - 1;
            if (wi < 0) wi = 0;
            wpowS[lane] = powf(wts[wi], gpw[lh]);
        }
        if (lane >= NWN && lane < NWN + 5) anormS[EWE + (lane - NWN)] = 0.f;  // pad slots 75..79

        f32x4 acc2[ET][4];
#pragma unroll
        for (int et = 0; et < ET; ++et)
#pragma unroll
            for (int nt = 0; nt < 4; ++nt) acc2[et][nt] = (f32x4){0.f, 0.f, 0.f, 0.f};
        float gacc[ET] = {0.f, 0.f, 0.f, 0.f, 0.f};

#pragma unroll
        for (int c = 0; c < 4; ++c) {
            // ping-pong: chunk parity selects PQ buffer (compile-time after unroll)
            _Float16 (*PQ)[16][72] = (c & 1) ? PQ1 : PQ0;

            // ---- GEMM2 B-frags for this chunk: issue early, reuse for 5 et ----
            half8 B2[8];
            {
                const _Float16* W2b = W2sw + ((size_t)lhw * 8 + c * 2) * 2048;
#pragma unroll
                for (int f = 0; f < 8; ++f)
                    B2[f] = *(const half8*)(W2b + ((size_t)f * 64 + lane) * 8);
            }

            // ---- stage-1: all 4 net-halves, TRANSPOSED mfma -> packed writes ----
#pragma unroll
            for (int hf = 0; hf < 4; ++hf) {
                f32x4 accS[4];
#pragma unroll
                for (int nt = 0; nt < 4; ++nt) accS[nt] = (f32x4){0.f, 0.f, 0.f, 0.f};
                const _Float16* Wb = W1sw + ((size_t)lhw * 4 + hf) * 16384 + c * 4096;
#pragma unroll
                for (int nt = 0; nt < 4; ++nt)
#pragma unroll
                    for (int ks = 0; ks < 2; ++ks) {
                        half8 B = *(const half8*)(Wb + ((nt * 2 + ks) * 64 + lane) * 8);
                        // swapped operands: D[hid][node]
                        accS[nt] = __builtin_amdgcn_mfma_f32_16x16x32_f16(
                            B, A[ks], accS[nt], 0, 0, 0);
                    }
                // lane holds hid = nt*16 + q*4 + rg for node = m16 -> one b64/nt
#pragma unroll
                for (int nt = 0; nt < 4; ++nt) {
                    h2 lo = cvt_pk(accS[nt][0], accS[nt][1]);
                    h2 hi = cvt_pk(accS[nt][2], accS[nt][3]);
                    h4 pk = __builtin_shufflevector(lo, hi, 0, 1, 2, 3);
                    *(h4*)&PQ[hf][m16][nt * 16 + q * 4] = pk;
                }
            }

            // ---- per-chunk bias slices (global, L1-hot); wg packed to f16 ----
            half8 bg8[2], bm8[2];
            h2 wgh2[2][4];
#pragma unroll
            for (int ks = 0; ks < 2; ++ks) {
                const int ub = c * 64 + ks * 32 + q * 8;
                float4 g0 = *(const float4*)(gb1 + (size_t)lh * HID + ub);
                float4 g1 = *(const float4*)(gb1 + (size_t)lh * HID + ub + 4);
                float4 m0 = *(const float4*)(mb1 + (size_t)lh * HID + ub);
                float4 m1 = *(const float4*)(mb1 + (size_t)lh * HID + ub + 4);
                float4 w0 = *(const float4*)(gW2 + (size_t)lh * HID + ub);
                float4 w1 = *(const float4*)(gW2 + (size_t)lh * HID + ub + 4);
                half8 bg, bm;
                bg[0]=(_Float16)g0.x; bg[1]=(_Float16)g0.y; bg[2]=(_Float16)g0.z; bg[3]=(_Float16)g0.w;
                bg[4]=(_Float16)g1.x; bg[5]=(_Float16)g1.y; bg[6]=(_Float16)g1.z; bg[7]=(_Float16)g1.w;
                bm[0]=(_Float16)m0.x; bm[1]=(_Float16)m0.y; bm[2]=(_Float16)m0.z; bm[3]=(_Float16)m0.w;
                bm[4]=(_Float16)m1.x; bm[5]=(_Float16)m1.y; bm[6]=(_Float16)m1.z; bm[7]=(_Float16)m1.w;
                bg8[ks] = bg; bm8[ks] = bm;
                wgh2[ks][0] = cvt_pk(w0.x, w0.y);
                wgh2[ks][1] = cvt_pk(w0.z, w0.w);
                wgh2[ks][2] = cvt_pk(w1.x, w1.y);
                wgh2[ks][3] = cvt_pk(w1.z, w1.w);
            }

            // ---- consume: gate fdot2 + hm A-frags + GEMM2 (B2 reused) ----
#pragma unroll
            for (int et = 0; et < ET; ++et) {
                half8 af[2];
#pragma unroll
                for (int ks = 0; ks < 2; ++ks) {
                    const int ub = ks * 32 + q * 8;
                    half8 pg = *(const half8*)&PQ[0][iR[et]][ub];
                    half8 qg = *(const half8*)&PQ[1][jR[et]][ub];
                    half8 pm = *(const half8*)&PQ[2][iR[et]][ub];
                    half8 qm = *(const half8*)&PQ[3][jR[et]][ub];
                    half8 tg = lrelu8(pg + qg + bg8[ks]);
                    h2 t01 = __builtin_shufflevector(tg, tg, 0, 1);
                    h2 t23 = __builtin_shufflevector(tg, tg, 2, 3);
                    h2 t45 = __builtin_shufflevector(tg, tg, 4, 5);
                    h2 t67 = __builtin_shufflevector(tg, tg, 6, 7);
                    gacc[et] = __builtin_amdgcn_fdot2(t01, wgh2[ks][0], gacc[et], false);
                    gacc[et] = __builtin_amdgcn_fdot2(t23, wgh2[ks][1], gacc[et], false);
                    gacc[et] = __builtin_amdgcn_fdot2(t45, wgh2[ks][2], gacc[et], false);
                    gacc[et] = __builtin_amdgcn_fdot2(t67, wgh2[ks][3], gacc[et], false);
                    af[ks] = lrelu8(pm + qm + bm8[ks]);
                }
#pragma unroll
                for (int nt = 0; nt < 4; ++nt)
#pragma unroll
                    for (int ks = 0; ks < 2; ++ks)
                        acc2[et][nt] = __builtin_amdgcn_mfma_f32_16x16x32_f16(
                            af[ks], B2[ks * 4 + nt], acc2[et][nt], 0, 0, 0);
            }
        }

        // ---- gate reduce across quads (k-slices) ----
        const float gb2s = gb2v[lh];
#pragma unroll
        for (int et = 0; et < ET; ++et) {
            float g = gacc[et];
            g += __shfl_xor(g, 16);
            g += __shfl_xor(g, 32);
            if (q == 0) gateS[et * 16 + m16] = g + gb2s;
        }

        // ---- segment softmax: lane n (0..14) handles local node n (5 edges) ----
        if (lane < NWN) {
            const int cl5 = (lane / K) * K;
            float gg[K], mx = -1e30f;
#pragma unroll
            for (int jj = 0; jj < K; ++jj) {
                gg[jj] = gateS[lane * K + jj];
                mx = fmaxf(mx, gg[jj]);
            }
            float s = 0.f, wv[K];
#pragma unroll
            for (int jj = 0; jj < K; ++jj) {
                wv[jj] = wpowS[cl5 + jj] * expf(gg[jj] - mx);
                s += wv[jj];
            }
            float inv = 1.f / (s + 1e-10f) * (1.f / 3.f);  // fold head mean
#pragma unroll
            for (int jj = 0; jj < K; ++jj) anormS[lane * K + jj] = wv[jj] * inv;
        }

        // ---- weighted msg -> msgL (PQ region dead) ----
        float b2v[4];
#pragma unroll
        for (int nt = 0; nt < 4; ++nt) b2v[nt] = mb2[(size_t)lh * F + nt * 16 + m16];
#pragma unroll
        for (int et = 0; et < ET; ++et) {
            f32x4 an = *(const f32x4*)&anormS[et * 16 + q * 4];
#pragma unroll
            for (int nt = 0; nt < 4; ++nt)
#pragma unroll
                for (int rg = 0; rg < 4; ++rg) {
                    float v = (acc2[et][nt][rg] + b2v[nt]) * an[rg];
                    msgL[et * 16 + q * 4 + rg][nt * 16 + m16] = (_Float16)v;
                }
        }

        // ---- aggregate: lane = output col, 15 nodes x 5 edges ----
#pragma unroll
        for (int n = 0; n < NWN; ++n) {
            float s = 0.f;
#pragma unroll
            for (int jj = 0; jj < K; ++jj) s += (float)msgL[n * K + jj][lane];
            oacc[n] += s;
        }
    }

    // ---- residual + write back (own valid rows only) ----
#pragma unroll
    for (int n = 0; n < NWN; ++n) {
        if (n < vn) {
            size_t idx = (size_t)(nw0 + n) * F + lane;
            x[idx] = oacc[n] + x[idx];
        }
    }
}

// ---------------------------------------------------------------------------
// MFMA pool (round-5 proven)
// ---------------------------------------------------------------------------
__global__ __launch_bounds__(256)
void pool_mfma(const float* __restrict__ x,
               const _Float16* __restrict__ cW1sw,
               const _Float16* __restrict__ cW2sw,
               const float* __restrict__ cgb1, const float* __restrict__ cgb2v,
               const float* __restrict__ cmb1, const float* __restrict__ cmb2,
               const float* __restrict__ cgW2, const float* __restrict__ cpw,
               const float* __restrict__ wts, float* __restrict__ out)
{
    __shared__ __align__(16) _Float16 xh[48][72];
    __shared__ __align__(16) char PQraw[2 * 48 * 72 * 2];
    __shared__ float outacc[CB * F];
    __shared__ float b1gS[HID], b1mS[HID], w2gS[HID], b2mS[F];
    __shared__ float gateS[48], anormS[48], wpowS[48];

    _Float16 (*P)[48][72] = (_Float16 (*)[48][72])PQraw;
    _Float16 (*msgW)[72]  = (_Float16 (*)[72])PQraw;

    const int t = threadIdx.x, w = t >> 6, lane = t & 63;
    const int quad = lane >> 4, m16 = lane & 15;
    const int node0 = blockIdx.x * NB;

    for (int d = t; d < 48 * 64; d += 256) {
        int r = d >> 6, cc = d & 63;
        float v = (r < NB) ? x[(size_t)(node0 + r) * F + cc] : 0.f;
        xh[r][cc] = (_Float16)v;
    }
    for (int d = t; d < CB * F; d += 256) outacc[d] = 0.f;
    __syncthreads();

    half8 A[3][2];
#pragma unroll
    for (int Mt = 0; Mt < 3; ++Mt)
#pragma unroll
        for (int ks = 0; ks < 2; ++ks)
            A[Mt][ks] = *(const half8*)&xh[Mt * 16 + m16][ks * 32 + quad * 8];

    const int net = w >> 1, ntp = w & 1;

    for (int h = 0; h < NH; ++h) {
        if (t < HID) {
            b1gS[t] = cgb1[(size_t)h * HID + t];
            b1mS[t] = cmb1[(size_t)h * HID + t];
            w2gS[t] = cgW2[(size_t)h * HID + t];
        }
        if (t < F)  b2mS[t] = cmb2[(size_t)h * F + t];
        if (t < NB) wpowS[t] = powf(wts[node0 + t], cpw[h]);
        const float gb2s = cgb2v[h];

        f32x4 acc2[4];
#pragma unroll
        for (int nt = 0; nt < 4; ++nt) acc2[nt] = (f32x4){0.f, 0.f, 0.f, 0.f};
        float gacc = 0.f;

        for (int chunk = 0; chunk < 4; ++chunk) {
            {
                f32x4 accS[3][2];
#pragma unroll
                for (int Mt = 0; Mt < 3; ++Mt)
#pragma unroll
                    for (int n2 = 0; n2 < 2; ++n2) accS[Mt][n2] = (f32x4){0.f, 0.f, 0.f, 0.f};
                const _Float16* Wb = cW1sw + ((size_t)(h * 2 + net) * 4 + chunk) * 4096;
#pragma unroll
                for (int n2 = 0; n2 < 2; ++n2) {
                    int nt = ntp * 2 + n2;
#pragma unroll
                    for (int ks = 0; ks < 2; ++ks) {
                        half8 B = *(const half8*)(Wb + ((nt * 2 + ks) * 64 + lane) * 8);
#pragma unroll
                        for (int Mt = 0; Mt < 3; ++Mt)
                            accS[Mt][n2] = __builtin_amdgcn_mfma_f32_16x16x32_f16(
                                A[Mt][ks], B, accS[Mt][n2], 0, 0, 0);
                    }
                }
#pragma unroll
                for (int Mt = 0; Mt < 3; ++Mt)
#pragma unroll
                    for (int n2 = 0; n2 < 2; ++n2)
#pragma unroll
                        for (int rg = 0; rg < 4; ++rg)
                            P[net][Mt * 16 + quad * 4 + rg][(ntp * 2 + n2) * 16 + m16] =
                                (_Float16)accS[Mt][n2][rg];
            }
            __syncthreads();

            if (w < 3) {
                half8 af[2];
#pragma unroll
                for (int ks = 0; ks < 2; ++ks) {
                    const int ub = ks * 32 + quad * 8;
                    half8 pg = *(const half8*)&P[0][w * 16 + m16][ub];
                    half8 pm = *(const half8*)&P[1][w * 16 + m16][ub];
#pragma unroll
                    for (int j = 0; j < 8; ++j) {
                        int u = chunk * 64 + ub + j;
                        float gh = lrelu((float)pg[j] + b1gS[u]);
                        gacc += gh * w2gS[u];
                        float hv = lrelu((float)pm[j] + b1mS[u]);
                        af[ks][j] = (_Float16)hv;
                    }
                }
                const _Float16* W2b = cW2sw + (size_t)h * 16384 + chunk * 4096;
#pragma unroll
                for (int nt = 0; nt < 4; ++nt)
#pragma unroll
                    for (int ks = 0; ks < 2; ++ks) {
                        half8 B = *(const half8*)(W2b + ((size_t)(ks * 4 + nt) * 64 + lane) * 8);
                        acc2[nt] = __builtin_amdgcn_mfma_f32_16x16x32_f16(
                            af[ks], B, acc2[nt], 0, 0, 0);
                    }
            }
            __syncthreads();
        }

        if (w < 3) {
            float g = gacc;
            g += __shfl_xor(g, 16);
            g += __shfl_xor(g, 32);
            if (quad == 0) gateS[w * 16 + m16] = g + gb2s;
        }
        __syncthreads();

        if (t < CB) {
            float mx = -1e30f;
#pragma unroll
            for (int j = 0; j < K; ++j) mx = fmaxf(mx, gateS[t * K + j]);
            float s = 0.f, wv[K];
#pragma unroll
            for (int j = 0; j < K; ++j) {
                wv[j] = wpowS[t * K + j] * expf(gateS[t * K + j] - mx);
                s += wv[j];
            }
            float inv = 1.f / (s + 1e-10f) * (1.f / 3.f);
#pragma unroll
            for (int j = 0; j < K; ++j) anormS[t * K + j] = wv[j] * inv;
        }
        __syncthreads();

        if (w < 3) {
#pragma unroll
            for (int nt = 0; nt < 4; ++nt)
#pragma unroll
                for (int rg = 0; rg < 4; ++rg) {
                    int row = w * 16 + quad * 4 + rg;
                    float a = (row < NB) ? anormS[row] : 0.f;
                    float v = (acc2[nt][rg] + b2mS[nt * 16 + m16]) * a;
                    msgW[row][nt * 16 + m16] = (_Float16)v;
                }
        }
        __syncthreads();

        for (int d = t; d < CB * F; d += 256) {
            int cr = d >> 6, o = d & 63;
            float s = 0.f;
#pragma unroll
            for (int j = 0; j < K; ++j) s += (float)msgW[cr * K + j][o];
            outacc[d] += s;
        }
        __syncthreads();
    }

    for (int d = t; d < CB * F; d += 256)
        out[(size_t)blockIdx.x * (CB * F) + d] = outacc[d];
}

// ---------------------------------------------------------------------------
// Fallback fp32 pool (round-4 proven)
// ---------------------------------------------------------------------------
__global__ __launch_bounds__(256)
void pool_kernel(const float* __restrict__ x,
                 const float* __restrict__ cgW1, const float* __restrict__ cgb1,
                 const float* __restrict__ cgW2, const float* __restrict__ cgb2,
                 const float* __restrict__ cmW1, const float* __restrict__ cmb1,
                 const float* __restrict__ cmW2, const float* __restrict__ cmb2,
                 const float* __restrict__ cpw, const float* __restrict__ wts,
                 float* __restrict__ out)
{
    __shared__ float xs[K * F];
    __shared__ float hmS[K][HID];
    __shared__ float msgS[K][F];
    __shared__ float outacc[F];
    __shared__ float b1g[HID], b1m[HID], w2g[HID];
    __shared__ float b2mS[F];
    __shared__ float gpart[K][2];
    __shared__ float gate_s[K];
    __shared__ float anorm[K];
    __shared__ float wn[K], wpow[K];

    const int c = blockIdx.x;
    const int t = threadIdx.x;
    const int wave = t >> 6, lane = t & 63;

    for (int d = t; d < K * F; d += 256) xs[d] = x[c * K * F + d];
    if (t < F) outacc[t] = 0.f;
    if (t < K) wn[t] = wts[c * K + t];
    __syncthreads();

    for (int h = 0; h < NH; ++h) {
        if (t < HID) {
            b1g[t] = cgb1[(size_t)h * HID + t];
            b1m[t] = cmb1[(size_t)h * HID + t];
            w2g[t] = cgW2[(size_t)h * HID + t];
        }
        if (t < F) b2mS[t] = cmb2[(size_t)h * F + t];
        if (t < K) wpow[t] = powf(wn[t], cpw[h]);
        __syncthreads();

        {
            const int grp = t >> 7;
            const int up  = t & 127;
            const float* Wb = (grp == 0 ? cgW1 : cmW1) + (size_t)h * F * HID;
            const float2* W2p = (const float2*)Wb;
            float acc[K][2];
#pragma unroll
            for (int i = 0; i < K; ++i) { acc[i][0] = 0.f; acc[i][1] = 0.f; }
            for (int k = 0; k < F; ++k) {
                float2 wv = W2p[k * (HID / 2) + up];
#pragma unroll
                for (int i = 0; i < K; ++i) {
                    float xv = xs[i * F + k];
                    acc[i][0] += xv * wv.x;
                    acc[i][1] += xv * wv.y;
                }
            }
            if (grp == 0) {
#pragma unroll
                for (int i = 0; i < K; ++i) {
                    float h0 = lrelu(acc[i][0] + b1g[2 * up]);
                    float h1 = lrelu(acc[i][1] + b1g[2 * up + 1]);
                    float part = h0 * w2g[2 * up] + h1 * w2g[2 * up + 1];
#pragma unroll
                    for (int s = 32; s; s >>= 1) part += __shfl_xor(part, s);
                    if (lane == 0) gpart[i][wave & 1] = part;
                }
            } else {
#pragma unroll
                for (int i = 0; i < K; ++i) {
                    hmS[i][2 * up]     = lrelu(acc[i][0] + b1m[2 * up]);
                    hmS[i][2 * up + 1] = lrelu(acc[i][1] + b1m[2 * up + 1]);
                }
            }
        }
        __syncthreads();
        if (t < K) gate_s[t] = cgb2[h] + gpart[t][0] + gpart[t][1];

        {
            const float2* W232 = (const float2*)(cmW2 + (size_t)h * HID * F);
            if (t < K * (F / 2)) {
                int i  = t >> 5;
                int op = t & 31;
                float a0 = b2mS[2 * op], a1 = b2mS[2 * op + 1];
#pragma unroll 8
                for (int u = 0; u < HID; ++u) {
                    float2 wv = W232[u * (F / 2) + op];
                    float hv = hmS[i][u];
                    a0 += hv * wv.x;
                    a1 += hv * wv.y;
                }
                msgS[i][2 * op]     = a0;
                msgS[i][2 * op + 1] = a1;
            }
        }
        __syncthreads();

        if (t == 0) {
            float mx = -1e30f;
#pragma unroll
            for (int i = 0; i < K; ++i) mx = fmaxf(mx, gate_s[i]);
            float wv[K], s = 0.f;
#pragma unroll
            for (int i = 0; i < K; ++i) {
                wv[i] = wpow[i] * expf(gate_s[i] - mx);
                s += wv[i];
            }
            float inv = 1.f / (s + 1e-10f);
#pragma unroll
            for (int i = 0; i < K; ++i) anorm[i] = wv[i] * inv;
        }
        __syncthreads();

        if (t < F) {
            float s = 0.f;
#pragma unroll
            for (int i = 0; i < K; ++i) s += anorm[i] * msgS[i][t];
            outacc[t] += s * (1.f / 3.f);
        }
        __syncthreads();
    }

    if (t < F) out[(size_t)c * F + t] = outacc[t];
}

// ---------------------------------------------------------------------------
extern "C" void kernel_launch(void* const* d_in, const int* in_sizes, int n_in,
                              void* d_out, int out_size, void* d_ws, size_t ws_size,
                              hipStream_t stream)
{
    const float* wts  = (const float*)d_in[0];
    const float* fea  = (const float*)d_in[1];
    const float* embW = (const float*)d_in[6];
    const float* embB = (const float*)d_in[7];
    const float* gW1  = (const float*)d_in[8];
    const float* gb1  = (const float*)d_in[9];
    const float* gW2  = (const float*)d_in[10];
    const float* gb2  = (const float*)d_in[11];
    const float* mW1  = (const float*)d_in[12];
    const float* mb1  = (const float*)d_in[13];
    const float* mW2  = (const float*)d_in[14];
    const float* mb2  = (const float*)d_in[15];
    const float* gpw  = (const float*)d_in[16];
    const float* cgW1 = (const float*)d_in[17];
    const float* cgb1 = (const float*)d_in[18];
    const float* cgW2 = (const float*)d_in[19];
    const float* cgb2 = (const float*)d_in[20];
    const float* cmW1 = (const float*)d_in[21];
    const float* cmb1 = (const float*)d_in[22];
    const float* cmW2 = (const float*)d_in[23];
    const float* cmb2 = (const float*)d_in[24];
    const float* cpw  = (const float*)d_in[25];

    const int N = in_sizes[0];   // 50000
    const int C = N / K;         // 10000
    const int layer_blocks = (C + 11) / 12;   // 834 (tail block guarded)

    float* x = (float*)d_ws;                       // [N,F] fp32, 12.8 MB
    const size_t xbytes = (size_t)N * F * 4;
    const size_t need = xbytes + (size_t)WALL_ELEMS * 2;

    embed_kernel<<<(N + ENB - 1) / ENB, 256, 0, stream>>>(fea, embW, embB, wts, x, N);

    if (ws_size >= need) {
        // ---- fast path ----
        _Float16* Wall  = (_Float16*)((char*)d_ws + xbytes);
        _Float16* W1sw  = Wall;
        _Float16* W2sw  = Wall + W1SW_ELEMS;
        _Float16* cW1sw = Wall + W1SW_ELEMS + W2SW_ELEMS;
        _Float16* cW2sw = Wall + W1SW_ELEMS + W2SW_ELEMS + CW1_ELEMS;

        prep_all<<<(WALL_ELEMS + 255) / 256, 256, 0, stream>>>(
            gW1, mW1, mW2, cgW1, cmW1, cmW2, Wall);
        for (int l = 0; l < NL; ++l)
            layer_wave<<<layer_blocks, 256, 0, stream>>>(x, W1sw, W2sw,
                                                         gb1, gb2, mb1, mb2, gW2, gpw, wts,
                                                         l, l * NH, N);
        pool_mfma<<<C / CB, 256, 0, stream>>>(x, cW1sw, cW2sw,
                                              cgb1, cgb2, cmb1, cmb2, cgW2, cpw, wts,
                                              (float*)d_out);
    } else {
        // ---- fallback: per-layer prep into d_out scratch ----
        _Float16* W1sw = (_Float16*)d_out;
        _Float16* W2sw = (_Float16*)((char*)d_out + 393216);
        for (int l = 0; l < NL; ++l) {
            prep_layer<<<(W1L_ELEMS + W2L_ELEMS) / 256, 256, 0, stream>>>(
                gW1, mW1, mW2, W1sw, W2sw, l);
            layer_wave<<<layer_blocks, 256, 0, stream>>>(x, W1sw, W2sw,
                                                         gb1, gb2, mb1, mb2, gW2, gpw, wts,
                                                         l, 0, N);
        }
        pool_kernel<<<C, 256, 0, stream>>>(x, cgW1, cgb1, cgW2, cgb2,
                                           cmW1, cmb1, cmW2, cmb2, cpw, wts,
                                           (float*)d_out);
    }
}

// Round 7
// 860.715 us; speedup vs baseline: 1.6397x; 1.6397x over previous
//
#include <hip/hip_runtime.h>
#include <hip/hip_bf16.h>

#define K 5
#define F 64
#define EMBD 200
#define HID 256
#define NH 3
#define NL 3
#define CB 8            // crystals per block for POOL kernels
#define NB (CB * K)     // 40 nodes per pool block

// layer kernel: 4 waves x 3 crystals = 12 crystals / block
#define CW 3            // crystals per wave
#define NWN (CW * K)    // 15 nodes per wave
#define EWE (CW * K * K) // 75 edges per wave
#define ET 5            // edge tiles of 16

typedef _Float16 half8 __attribute__((ext_vector_type(8)));
typedef _Float16 h2 __attribute__((ext_vector_type(2)));
typedef _Float16 h4 __attribute__((ext_vector_type(4)));
typedef __fp16 fp16x2 __attribute__((ext_vector_type(2)));
typedef float f32x4 __attribute__((ext_vector_type(4)));

__device__ __forceinline__ float lrelu(float v) { return v >= 0.f ? v : 0.01f * v; }

// cvt_pkrtz returns __fp16x2; bitcast to _Float16x2 (same bits, distinct clang types)
__device__ __forceinline__ h2 cvt_pk(float a, float b) {
    union { fp16x2 f; h2 h; } u;
    u.f = __builtin_amdgcn_cvt_pkrtz(a, b);
    return u.h;
}

__device__ __forceinline__ half8 lrelu8(half8 t) {
    half8 z = 0;
    half8 p = __builtin_elementwise_max(t, z);
    half8 n = __builtin_elementwise_min(t, z);
    return p + n * (_Float16)0.01f;
}

// ---- swizzled-weight element counts (fp16) ----
#define W1SW_ELEMS 589824    // 9 lh * 2 net * 2 half * 4 chunk * 4 nt * 2 ks * 64 * 8
#define W2SW_ELEMS 147456    // 9 lh * 8 ks2 * 4 nt * 64 * 8
#define CW1_ELEMS   98304    // 3 h * 2 net * 4 chunk * 4 nt * 2 ks * 64 * 8
#define CW2_ELEMS   49152    // 3 h * 8 ks2 * 4 nt * 64 * 8
#define WALL_ELEMS (W1SW_ELEMS + W2SW_ELEMS + CW1_ELEMS + CW2_ELEMS)  // 884736

// per-layer (fallback) sizes
#define W1L_ELEMS 196608
#define W2L_ELEMS 49152

// ---------------------------------------------------------------------------
// Fast path: swizzle ALL weights (layers + pool) fp32 -> fp16 B-frag order.
// ---------------------------------------------------------------------------
__global__ __launch_bounds__(256)
void prep_all(const float* __restrict__ gW1, const float* __restrict__ mW1,
              const float* __restrict__ mW2,
              const float* __restrict__ cgW1, const float* __restrict__ cmW1,
              const float* __restrict__ cmW2,
              _Float16* __restrict__ Wall)
{
    int tid = blockIdx.x * 256 + threadIdx.x;
    if (tid >= WALL_ELEMS) return;
    float v;
    if (tid < W1SW_ELEMS) {
        int j = tid & 7, lane = (tid >> 3) & 63;
        int r1 = tid >> 9;                       // [lh][net][half][chunk][nt][ks]
        int ks = r1 & 1, nt = (r1 >> 1) & 3, chunk = (r1 >> 3) & 3;
        int half = (r1 >> 5) & 1, net = (r1 >> 6) & 1, lh = r1 >> 7;   // 0..8
        int q = lane >> 4, n16 = lane & 15;
        const float* src = net ? mW1 : gW1;
        v = src[((size_t)lh * 128 + half * 64 + ks * 32 + q * 8 + j) * 256
                + chunk * 64 + nt * 16 + n16];
    } else if (tid < W1SW_ELEMS + W2SW_ELEMS) {
        int t2 = tid - W1SW_ELEMS;
        int j = t2 & 7, lane = (t2 >> 3) & 63;
        int r1 = t2 >> 9;                        // [lh][ks2][nt]
        int nt = r1 & 3, ks2 = (r1 >> 2) & 7, lh = r1 >> 5;            // 0..8
        int q = lane >> 4, n16 = lane & 15;
        v = mW2[((size_t)lh * 256 + ks2 * 32 + q * 8 + j) * 64 + nt * 16 + n16];
    } else if (tid < W1SW_ELEMS + W2SW_ELEMS + CW1_ELEMS) {
        int t2 = tid - (W1SW_ELEMS + W2SW_ELEMS);
        int j = t2 & 7, lane = (t2 >> 3) & 63;
        int r1 = t2 >> 9;                        // [h][net][chunk][nt][ks]
        int ks = r1 & 1, nt = (r1 >> 1) & 3, chunk = (r1 >> 3) & 3;
        int net = (r1 >> 5) & 1, h = r1 >> 6;                          // 0..2
        int q = lane >> 4, n16 = lane & 15;
        const float* src = net ? cmW1 : cgW1;
        v = src[((size_t)h * 64 + ks * 32 + q * 8 + j) * 256
                + chunk * 64 + nt * 16 + n16];
    } else {
        int t2 = tid - (W1SW_ELEMS + W2SW_ELEMS + CW1_ELEMS);
        int j = t2 & 7, lane = (t2 >> 3) & 63;
        int r1 = t2 >> 9;                        // [h][ks2][nt]
        int nt = r1 & 3, ks2 = (r1 >> 2) & 7, h = r1 >> 5;             // 0..2
        int q = lane >> 4, n16 = lane & 15;
        v = cmW2[((size_t)h * 256 + ks2 * 32 + q * 8 + j) * 64 + nt * 16 + n16];
    }
    Wall[tid] = (_Float16)v;
}

// ---------------------------------------------------------------------------
// Fallback: per-layer prep into d_out scratch (round-4 proven).
// ---------------------------------------------------------------------------
__global__ __launch_bounds__(256)
void prep_layer(const float* __restrict__ gW1, const float* __restrict__ mW1,
                const float* __restrict__ mW2,
                _Float16* __restrict__ W1sw, _Float16* __restrict__ W2sw, int l)
{
    int tid = blockIdx.x * 256 + threadIdx.x;
    if (tid < W1L_ELEMS) {
        int j = tid & 7, lane = (tid >> 3) & 63;
        int r1 = tid >> 9;
        int ks = r1 & 1, nt = (r1 >> 1) & 3, chunk = (r1 >> 3) & 3;
        int half = (r1 >> 5) & 1, net = (r1 >> 6) & 1, hh = r1 >> 7;
        int q = lane >> 4, n16 = lane & 15;
        const float* src = net ? mW1 : gW1;
        float v = src[((size_t)(l * NH + hh) * 128 + half * 64 + ks * 32 + q * 8 + j) * 256
                      + chunk * 64 + nt * 16 + n16];
        W1sw[tid] = (_Float16)v;
    } else {
        int t2 = tid - W1L_ELEMS;
        if (t2 < W2L_ELEMS) {
            int j = t2 & 7, lane = (t2 >> 3) & 63;
            int r1 = t2 >> 9;
            int nt = r1 & 3, ks2 = (r1 >> 2) & 7, hh = r1 >> 5;
            int q = lane >> 4, n16 = lane & 15;
            float v = mW2[((size_t)(l * NH + hh) * 256 + ks2 * 32 + q * 8 + j) * 64
                          + nt * 16 + n16];
            W2sw[t2] = (_Float16)v;
        }
    }
}

// ---------------------------------------------------------------------------
// Embedding — 16 nodes / 256-thread block; fea tile staged in LDS; thread
// (nl,o) computes 4 output cols {o, o+16, o+32, o+48} for node nl.
// ---------------------------------------------------------------------------
#define ENB 16   // nodes per embed block

__global__ __launch_bounds__(256)
void embed_kernel(const float* __restrict__ fea, const float* __restrict__ W,
                  const float* __restrict__ b, const float* __restrict__ wts,
                  float* __restrict__ x, int Ntot)
{
    __shared__ float fs[ENB * EMBD];
    const int t = threadIdx.x;
    const int node0 = blockIdx.x * ENB;
    int nvalid = Ntot - node0;
    if (nvalid > ENB) nvalid = ENB;
    if (nvalid <= 0) return;
    const int lim = nvalid * EMBD;
    for (int d = t; d < lim; d += 256) fs[d] = fea[(size_t)node0 * EMBD + d];
    __syncthreads();

    const int nl = t >> 4;          // local node 0..15
    const int o  = t & 15;          // output column group
    if (nl >= nvalid) return;
    const int n = node0 + nl;

    float acc[4];
#pragma unroll
    for (int k2 = 0; k2 < 4; ++k2) {
        int oc = o + 16 * k2;
        acc[k2] = (oc < F - 1) ? b[oc] : wts[n];
    }
    const float* fsr = fs + nl * EMBD;
#pragma unroll 4
    for (int e = 0; e < EMBD; ++e) {
        float xv = fsr[e];                       // quad-broadcast LDS read
        const float* wr = W + (size_t)e * (F - 1);
#pragma unroll
        for (int k2 = 0; k2 < 4; ++k2) {
            int oc = o + 16 * k2;
            if (oc < F - 1) acc[k2] += xv * wr[oc];
        }
    }
#pragma unroll
    for (int k2 = 0; k2 < 4; ++k2)
        x[(size_t)n * F + o + 16 * k2] = acc[k2];
}

// ---------------------------------------------------------------------------
// One graph layer — barrier-free, 4 independent waves / block, each wave owns
// 3 crystals (15 nodes, 75 edges). GEMM2 B-frags hoisted. Wave LDS 12288 B.
// (256,2): round-10 proven — 2 blocks/CU, occupancy 18%, no spill.
// Round 12 proven: transposed stage-1 mfma + packed b64 PQ writes + fdot2 gate
// (186.7 us/layer). Round 13 (PQ dbuf + full c-unroll) REGRESSED to 370 us:
// unified register pressure blew past the (256,2) cap and spilled accumulators
// to scratch (WRITE_SIZE 12.5 MB -> 552 MB). Round 14: reverted to round-12.
// Schedule-restructure lessons: LDS DS ops are wave-in-order (WAR needs no
// wait), so cross-chunk overlap requires unrolling, which spills. This
// structure is pinned at 2 waves/SIMD; wins came from occupancy + in-place
// strength reduction only.
// ---------------------------------------------------------------------------
#define WAVE_LDS 12288   // bytes per wave slice

__global__ __launch_bounds__(256, 2)
void layer_wave(float* __restrict__ x,
                const _Float16* __restrict__ W1sw,
                const _Float16* __restrict__ W2sw,
                const float* __restrict__ gb1, const float* __restrict__ gb2v,
                const float* __restrict__ mb1, const float* __restrict__ mb2,
                const float* __restrict__ gW2, const float* __restrict__ gpw,
                const float* __restrict__ wts, int l, int lhw0, int Ntot)
{
    __shared__ __align__(16) char smem[4 * WAVE_LDS];

    const int t = threadIdx.x, w = t >> 6, lane = t & 63;
    const int q = lane >> 4, m16 = lane & 15;

    char* wb = smem + w * WAVE_LDS;
    _Float16 (*PQ)[16][72] = (_Float16 (*)[16][72])wb;   // [4][16][72] = 9216 B
    _Float16 (*msgL)[72]   = (_Float16 (*)[72])wb;       // [80][72] = 11520 B (aliases PQ)
    float* gateS  = (float*)(wb + 11520);                // [80]
    float* anormS = (float*)(wb + 11840);                // [80]
    float* wpowS  = (float*)(wb + 12160);                // [16]

    const int nw0 = (blockIdx.x * 12 + w * CW) * K;      // first node of this wave
    const int vn  = (Ntot - nw0 < NWN) ? (Ntot - nw0) : NWN;  // valid nodes (may be <=0)

    // ---- A-fragments of x (head/half-invariant), fp16, loaded once ----
    half8 A[2];
    {
        int arow = nw0 + m16;
        if (arow > Ntot - 1) arow = Ntot - 1;            // clamp pad rows (finite junk)
        if (arow < 0) arow = 0;
        const float* xr = x + (size_t)arow * F;
#pragma unroll
        for (int ks = 0; ks < 2; ++ks) {
            float4 f0 = *(const float4*)(xr + ks * 32 + q * 8);
            float4 f1 = *(const float4*)(xr + ks * 32 + q * 8 + 4);
            half8 a;
            a[0] = (_Float16)f0.x; a[1] = (_Float16)f0.y;
            a[2] = (_Float16)f0.z; a[3] = (_Float16)f0.w;
            a[4] = (_Float16)f1.x; a[5] = (_Float16)f1.y;
            a[6] = (_Float16)f1.z; a[7] = (_Float16)f1.w;
            A[ks] = a;
        }
    }

    // ---- per-lane edge -> local node rows (75 valid edges in 5 tiles of 16) ----
    int iR[ET], jR[ET];
#pragma unroll
    for (int et = 0; et < ET; ++et) {
        int e = et * 16 + m16;
        if (e < EWE) {
            int cl = e / 25, rm = e % 25;
            iR[et] = cl * K + rm / K;
            jR[et] = cl * K + rm % K;
        } else { iR[et] = 15; jR[et] = 15; }             // pad row (clamped x, finite)
    }

    float oacc[NWN];
#pragma unroll
    for (int n = 0; n < NWN; ++n) oacc[n] = 0.f;

    for (int h = 0; h < NH; ++h) {
        const int lh = l * NH + h, lhw = lhw0 + h;

        if (lane < NWN) {
            int wi = nw0 + lane;
            if (wi > Ntot - 1) wi = Ntot - 1;
            if (wi < 0) wi = 0;
            wpowS[lane] = powf(wts[wi], gpw[lh]);
        }
        if (lane >= NWN && lane < NWN + 5) anormS[EWE + (lane - NWN)] = 0.f;  // pad slots 75..79

        f32x4 acc2[ET][4];
#pragma unroll
        for (int et = 0; et < ET; ++et)
#pragma unroll
            for (int nt = 0; nt < 4; ++nt) acc2[et][nt] = (f32x4){0.f, 0.f, 0.f, 0.f};
        float gacc[ET] = {0.f, 0.f, 0.f, 0.f, 0.f};

        for (int c = 0; c < 4; ++c) {
            // ---- GEMM2 B-frags for this chunk: issue early, reuse for 5 et ----
            half8 B2[8];
            {
                const _Float16* W2b = W2sw + ((size_t)lhw * 8 + c * 2) * 2048;
#pragma unroll
                for (int f = 0; f < 8; ++f)
                    B2[f] = *(const half8*)(W2b + ((size_t)f * 64 + lane) * 8);
            }

            // ---- stage-1: all 4 net-halves, TRANSPOSED mfma -> packed writes ----
#pragma unroll
            for (int hf = 0; hf < 4; ++hf) {
                f32x4 accS[4];
#pragma unroll
                for (int nt = 0; nt < 4; ++nt) accS[nt] = (f32x4){0.f, 0.f, 0.f, 0.f};
                const _Float16* Wb = W1sw + ((size_t)lhw * 4 + hf) * 16384 + c * 4096;
#pragma unroll
                for (int nt = 0; nt < 4; ++nt)
#pragma unroll
                    for (int ks = 0; ks < 2; ++ks) {
                        half8 B = *(const half8*)(Wb + ((nt * 2 + ks) * 64 + lane) * 8);
                        // swapped operands: D[hid][node]
                        accS[nt] = __builtin_amdgcn_mfma_f32_16x16x32_f16(
                            B, A[ks], accS[nt], 0, 0, 0);
                    }
                // lane holds hid = nt*16 + q*4 + rg for node = m16 -> one b64/nt
#pragma unroll
                for (int nt = 0; nt < 4; ++nt) {
                    h2 lo = cvt_pk(accS[nt][0], accS[nt][1]);
                    h2 hi = cvt_pk(accS[nt][2], accS[nt][3]);
                    h4 pk = __builtin_shufflevector(lo, hi, 0, 1, 2, 3);
                    *(h4*)&PQ[hf][m16][nt * 16 + q * 4] = pk;
                }
            }

            // ---- per-chunk bias slices (global, L1-hot); wg packed to f16 ----
            half8 bg8[2], bm8[2];
            h2 wgh2[2][4];
#pragma unroll
            for (int ks = 0; ks < 2; ++ks) {
                const int ub = c * 64 + ks * 32 + q * 8;
                float4 g0 = *(const float4*)(gb1 + (size_t)lh * HID + ub);
                float4 g1 = *(const float4*)(gb1 + (size_t)lh * HID + ub + 4);
                float4 m0 = *(const float4*)(mb1 + (size_t)lh * HID + ub);
                float4 m1 = *(const float4*)(mb1 + (size_t)lh * HID + ub + 4);
                float4 w0 = *(const float4*)(gW2 + (size_t)lh * HID + ub);
                float4 w1 = *(const float4*)(gW2 + (size_t)lh * HID + ub + 4);
                half8 bg, bm;
                bg[0]=(_Float16)g0.x; bg[1]=(_Float16)g0.y; bg[2]=(_Float16)g0.z; bg[3]=(_Float16)g0.w;
                bg[4]=(_Float16)g1.x; bg[5]=(_Float16)g1.y; bg[6]=(_Float16)g1.z; bg[7]=(_Float16)g1.w;
                bm[0]=(_Float16)m0.x; bm[1]=(_Float16)m0.y; bm[2]=(_Float16)m0.z; bm[3]=(_Float16)m0.w;
                bm[4]=(_Float16)m1.x; bm[5]=(_Float16)m1.y; bm[6]=(_Float16)m1.z; bm[7]=(_Float16)m1.w;
                bg8[ks] = bg; bm8[ks] = bm;
                wgh2[ks][0] = cvt_pk(w0.x, w0.y);
                wgh2[ks][1] = cvt_pk(w0.z, w0.w);
                wgh2[ks][2] = cvt_pk(w1.x, w1.y);
                wgh2[ks][3] = cvt_pk(w1.z, w1.w);
            }

            // ---- consume: gate fdot2 + hm A-frags + GEMM2 (B2 reused) ----
#pragma unroll
            for (int et = 0; et < ET; ++et) {
                half8 af[2];
#pragma unroll
                for (int ks = 0; ks < 2; ++ks) {
                    const int ub = ks * 32 + q * 8;
                    half8 pg = *(const half8*)&PQ[0][iR[et]][ub];
                    half8 qg = *(const half8*)&PQ[1][jR[et]][ub];
                    half8 pm = *(const half8*)&PQ[2][iR[et]][ub];
                    half8 qm = *(const half8*)&PQ[3][jR[et]][ub];
                    half8 tg = lrelu8(pg + qg + bg8[ks]);
                    h2 t01 = __builtin_shufflevector(tg, tg, 0, 1);
                    h2 t23 = __builtin_shufflevector(tg, tg, 2, 3);
                    h2 t45 = __builtin_shufflevector(tg, tg, 4, 5);
                    h2 t67 = __builtin_shufflevector(tg, tg, 6, 7);
                    gacc[et] = __builtin_amdgcn_fdot2(t01, wgh2[ks][0], gacc[et], false);
                    gacc[et] = __builtin_amdgcn_fdot2(t23, wgh2[ks][1], gacc[et], false);
                    gacc[et] = __builtin_amdgcn_fdot2(t45, wgh2[ks][2], gacc[et], false);
                    gacc[et] = __builtin_amdgcn_fdot2(t67, wgh2[ks][3], gacc[et], false);
                    af[ks] = lrelu8(pm + qm + bm8[ks]);
                }
#pragma unroll
                for (int nt = 0; nt < 4; ++nt)
#pragma unroll
                    for (int ks = 0; ks < 2; ++ks)
                        acc2[et][nt] = __builtin_amdgcn_mfma_f32_16x16x32_f16(
                            af[ks], B2[ks * 4 + nt], acc2[et][nt], 0, 0, 0);
            }
        }

        // ---- gate reduce across quads (k-slices) ----
        const float gb2s = gb2v[lh];
#pragma unroll
        for (int et = 0; et < ET; ++et) {
            float g = gacc[et];
            g += __shfl_xor(g, 16);
            g += __shfl_xor(g, 32);
            if (q == 0) gateS[et * 16 + m16] = g + gb2s;
        }

        // ---- segment softmax: lane n (0..14) handles local node n (5 edges) ----
        if (lane < NWN) {
            const int cl5 = (lane / K) * K;
            float gg[K], mx = -1e30f;
#pragma unroll
            for (int jj = 0; jj < K; ++jj) {
                gg[jj] = gateS[lane * K + jj];
                mx = fmaxf(mx, gg[jj]);
            }
            float s = 0.f, wv[K];
#pragma unroll
            for (int jj = 0; jj < K; ++jj) {
                wv[jj] = wpowS[cl5 + jj] * expf(gg[jj] - mx);
                s += wv[jj];
            }
            float inv = 1.f / (s + 1e-10f) * (1.f / 3.f);  // fold head mean
#pragma unroll
            for (int jj = 0; jj < K; ++jj) anormS[lane * K + jj] = wv[jj] * inv;
        }

        // ---- weighted msg -> msgL (PQ region dead) ----
        float b2v[4];
#pragma unroll
        for (int nt = 0; nt < 4; ++nt) b2v[nt] = mb2[(size_t)lh * F + nt * 16 + m16];
#pragma unroll
        for (int et = 0; et < ET; ++et) {
            f32x4 an = *(const f32x4*)&anormS[et * 16 + q * 4];
#pragma unroll
            for (int nt = 0; nt < 4; ++nt)
#pragma unroll
                for (int rg = 0; rg < 4; ++rg) {
                    float v = (acc2[et][nt][rg] + b2v[nt]) * an[rg];
                    msgL[et * 16 + q * 4 + rg][nt * 16 + m16] = (_Float16)v;
                }
        }

        // ---- aggregate: lane = output col, 15 nodes x 5 edges ----
#pragma unroll
        for (int n = 0; n < NWN; ++n) {
            float s = 0.f;
#pragma unroll
            for (int jj = 0; jj < K; ++jj) s += (float)msgL[n * K + jj][lane];
            oacc[n] += s;
        }
    }

    // ---- residual + write back (own valid rows only) ----
#pragma unroll
    for (int n = 0; n < NWN; ++n) {
        if (n < vn) {
            size_t idx = (size_t)(nw0 + n) * F + lane;
            x[idx] = oacc[n] + x[idx];
        }
    }
}

// ---------------------------------------------------------------------------
// MFMA pool (round-5 proven)
// ---------------------------------------------------------------------------
__global__ __launch_bounds__(256)
void pool_mfma(const float* __restrict__ x,
               const _Float16* __restrict__ cW1sw,
               const _Float16* __restrict__ cW2sw,
               const float* __restrict__ cgb1, const float* __restrict__ cgb2v,
               const float* __restrict__ cmb1, const float* __restrict__ cmb2,
               const float* __restrict__ cgW2, const float* __restrict__ cpw,
               const float* __restrict__ wts, float* __restrict__ out)
{
    __shared__ __align__(16) _Float16 xh[48][72];
    __shared__ __align__(16) char PQraw[2 * 48 * 72 * 2];
    __shared__ float outacc[CB * F];
    __shared__ float b1gS[HID], b1mS[HID], w2gS[HID], b2mS[F];
    __shared__ float gateS[48], anormS[48], wpowS[48];

    _Float16 (*P)[48][72] = (_Float16 (*)[48][72])PQraw;
    _Float16 (*msgW)[72]  = (_Float16 (*)[72])PQraw;

    const int t = threadIdx.x, w = t >> 6, lane = t & 63;
    const int quad = lane >> 4, m16 = lane & 15;
    const int node0 = blockIdx.x * NB;

    for (int d = t; d < 48 * 64; d += 256) {
        int r = d >> 6, cc = d & 63;
        float v = (r < NB) ? x[(size_t)(node0 + r) * F + cc] : 0.f;
        xh[r][cc] = (_Float16)v;
    }
    for (int d = t; d < CB * F; d += 256) outacc[d] = 0.f;
    __syncthreads();

    half8 A[3][2];
#pragma unroll
    for (int Mt = 0; Mt < 3; ++Mt)
#pragma unroll
        for (int ks = 0; ks < 2; ++ks)
            A[Mt][ks] = *(const half8*)&xh[Mt * 16 + m16][ks * 32 + quad * 8];

    const int net = w >> 1, ntp = w & 1;

    for (int h = 0; h < NH; ++h) {
        if (t < HID) {
            b1gS[t] = cgb1[(size_t)h * HID + t];
            b1mS[t] = cmb1[(size_t)h * HID + t];
            w2gS[t] = cgW2[(size_t)h * HID + t];
        }
        if (t < F)  b2mS[t] = cmb2[(size_t)h * F + t];
        if (t < NB) wpowS[t] = powf(wts[node0 + t], cpw[h]);
        const float gb2s = cgb2v[h];

        f32x4 acc2[4];
#pragma unroll
        for (int nt = 0; nt < 4; ++nt) acc2[nt] = (f32x4){0.f, 0.f, 0.f, 0.f};
        float gacc = 0.f;

        for (int chunk = 0; chunk < 4; ++chunk) {
            {
                f32x4 accS[3][2];
#pragma unroll
                for (int Mt = 0; Mt < 3; ++Mt)
#pragma unroll
                    for (int n2 = 0; n2 < 2; ++n2) accS[Mt][n2] = (f32x4){0.f, 0.f, 0.f, 0.f};
                const _Float16* Wb = cW1sw + ((size_t)(h * 2 + net) * 4 + chunk) * 4096;
#pragma unroll
                for (int n2 = 0; n2 < 2; ++n2) {
                    int nt = ntp * 2 + n2;
#pragma unroll
                    for (int ks = 0; ks < 2; ++ks) {
                        half8 B = *(const half8*)(Wb + ((nt * 2 + ks) * 64 + lane) * 8);
#pragma unroll
                        for (int Mt = 0; Mt < 3; ++Mt)
                            accS[Mt][n2] = __builtin_amdgcn_mfma_f32_16x16x32_f16(
                                A[Mt][ks], B, accS[Mt][n2], 0, 0, 0);
                    }
                }
#pragma unroll
                for (int Mt = 0; Mt < 3; ++Mt)
#pragma unroll
                    for (int n2 = 0; n2 < 2; ++n2)
#pragma unroll
                        for (int rg = 0; rg < 4; ++rg)
                            P[net][Mt * 16 + quad * 4 + rg][(ntp * 2 + n2) * 16 + m16] =
                                (_Float16)accS[Mt][n2][rg];
            }
            __syncthreads();

            if (w < 3) {
                half8 af[2];
#pragma unroll
                for (int ks = 0; ks < 2; ++ks) {
                    const int ub = ks * 32 + quad * 8;
                    half8 pg = *(const half8*)&P[0][w * 16 + m16][ub];
                    half8 pm = *(const half8*)&P[1][w * 16 + m16][ub];
#pragma unroll
                    for (int j = 0; j < 8; ++j) {
                        int u = chunk * 64 + ub + j;
                        float gh = lrelu((float)pg[j] + b1gS[u]);
                        gacc += gh * w2gS[u];
                        float hv = lrelu((float)pm[j] + b1mS[u]);
                        af[ks][j] = (_Float16)hv;
                    }
                }
                const _Float16* W2b = cW2sw + (size_t)h * 16384 + chunk * 4096;
#pragma unroll
                for (int nt = 0; nt < 4; ++nt)
#pragma unroll
                    for (int ks = 0; ks < 2; ++ks) {
                        half8 B = *(const half8*)(W2b + ((size_t)(ks * 4 + nt) * 64 + lane) * 8);
                        acc2[nt] = __builtin_amdgcn_mfma_f32_16x16x32_f16(
                            af[ks], B, acc2[nt], 0, 0, 0);
                    }
            }
            __syncthreads();
        }

        if (w < 3) {
            float g = gacc;
            g += __shfl_xor(g, 16);
            g += __shfl_xor(g, 32);
            if (quad == 0) gateS[w * 16 + m16] = g + gb2s;
        }
        __syncthreads();

        if (t < CB) {
            float mx = -1e30f;
#pragma unroll
            for (int j = 0; j < K; ++j) mx = fmaxf(mx, gateS[t * K + j]);
            float s = 0.f, wv[K];
#pragma unroll
            for (int j = 0; j < K; ++j) {
                wv[j] = wpowS[t * K + j] * expf(gateS[t * K + j] - mx);
                s += wv[j];
            }
            float inv = 1.f / (s + 1e-10f) * (1.f / 3.f);
#pragma unroll
            for (int j = 0; j < K; ++j) anormS[t * K + j] = wv[j] * inv;
        }
        __syncthreads();

        if (w < 3) {
#pragma unroll
            for (int nt = 0; nt < 4; ++nt)
#pragma unroll
                for (int rg = 0; rg < 4; ++rg) {
                    int row = w * 16 + quad * 4 + rg;
                    float a = (row < NB) ? anormS[row] : 0.f;
                    float v = (acc2[nt][rg] + b2mS[nt * 16 + m16]) * a;
                    msgW[row][nt * 16 + m16] = (_Float16)v;
                }
        }
        __syncthreads();

        for (int d = t; d < CB * F; d += 256) {
            int cr = d >> 6, o = d & 63;
            float s = 0.f;
#pragma unroll
            for (int j = 0; j < K; ++j) s += (float)msgW[cr * K + j][o];
            outacc[d] += s;
        }
        __syncthreads();
    }

    for (int d = t; d < CB * F; d += 256)
        out[(size_t)blockIdx.x * (CB * F) + d] = outacc[d];
}

// ---------------------------------------------------------------------------
// Fallback fp32 pool (round-4 proven)
// ---------------------------------------------------------------------------
__global__ __launch_bounds__(256)
void pool_kernel(const float* __restrict__ x,
                 const float* __restrict__ cgW1, const float* __restrict__ cgb1,
                 const float* __restrict__ cgW2, const float* __restrict__ cgb2,
                 const float* __restrict__ cmW1, const float* __restrict__ cmb1,
                 const float* __restrict__ cmW2, const float* __restrict__ cmb2,
                 const float* __restrict__ cpw, const float* __restrict__ wts,
                 float* __restrict__ out)
{
    __shared__ float xs[K * F];
    __shared__ float hmS[K][HID];
    __shared__ float msgS[K][F];
    __shared__ float outacc[F];
    __shared__ float b1g[HID], b1m[HID], w2g[HID];
    __shared__ float b2mS[F];
    __shared__ float gpart[K][2];
    __shared__ float gate_s[K];
    __shared__ float anorm[K];
    __shared__ float wn[K], wpow[K];

    const int c = blockIdx.x;
    const int t = threadIdx.x;
    const int wave = t >> 6, lane = t & 63;

    for (int d = t; d < K * F; d += 256) xs[d] = x[c * K * F + d];
    if (t < F) outacc[t] = 0.f;
    if (t < K) wn[t] = wts[c * K + t];
    __syncthreads();

    for (int h = 0; h < NH; ++h) {
        if (t < HID) {
            b1g[t] = cgb1[(size_t)h * HID + t];
            b1m[t] = cmb1[(size_t)h * HID + t];
            w2g[t] = cgW2[(size_t)h * HID + t];
        }
        if (t < F) b2mS[t] = cmb2[(size_t)h * F + t];
        if (t < K) wpow[t] = powf(wn[t], cpw[h]);
        __syncthreads();

        {
            const int grp = t >> 7;
            const int up  = t & 127;
            const float* Wb = (grp == 0 ? cgW1 : cmW1) + (size_t)h * F * HID;
            const float2* W2p = (const float2*)Wb;
            float acc[K][2];
#pragma unroll
            for (int i = 0; i < K; ++i) { acc[i][0] = 0.f; acc[i][1] = 0.f; }
            for (int k = 0; k < F; ++k) {
                float2 wv = W2p[k * (HID / 2) + up];
#pragma unroll
                for (int i = 0; i < K; ++i) {
                    float xv = xs[i * F + k];
                    acc[i][0] += xv * wv.x;
                    acc[i][1] += xv * wv.y;
                }
            }
            if (grp == 0) {
#pragma unroll
                for (int i = 0; i < K; ++i) {
                    float h0 = lrelu(acc[i][0] + b1g[2 * up]);
                    float h1 = lrelu(acc[i][1] + b1g[2 * up + 1]);
                    float part = h0 * w2g[2 * up] + h1 * w2g[2 * up + 1];
#pragma unroll
                    for (int s = 32; s; s >>= 1) part += __shfl_xor(part, s);
                    if (lane == 0) gpart[i][wave & 1] = part;
                }
            } else {
#pragma unroll
                for (int i = 0; i < K; ++i) {
                    hmS[i][2 * up]     = lrelu(acc[i][0] + b1m[2 * up]);
                    hmS[i][2 * up + 1] = lrelu(acc[i][1] + b1m[2 * up + 1]);
                }
            }
        }
        __syncthreads();
        if (t < K) gate_s[t] = cgb2[h] + gpart[t][0] + gpart[t][1];

        {
            const float2* W232 = (const float2*)(cmW2 + (size_t)h * HID * F);
            if (t < K * (F / 2)) {
                int i  = t >> 5;
                int op = t & 31;
                float a0 = b2mS[2 * op], a1 = b2mS[2 * op + 1];
#pragma unroll 8
                for (int u = 0; u < HID; ++u) {
                    float2 wv = W232[u * (F / 2) + op];
                    float hv = hmS[i][u];
                    a0 += hv * wv.x;
                    a1 += hv * wv.y;
                }
                msgS[i][2 * op]     = a0;
                msgS[i][2 * op + 1] = a1;
            }
        }
        __syncthreads();

        if (t == 0) {
            float mx = -1e30f;
#pragma unroll
            for (int i = 0; i < K; ++i) mx = fmaxf(mx, gate_s[i]);
            float wv[K], s = 0.f;
#pragma unroll
            for (int i = 0; i < K; ++i) {
                wv[i] = wpow[i] * expf(gate_s[i] - mx);
                s += wv[i];
            }
            float inv = 1.f / (s + 1e-10f);
#pragma unroll
            for (int i = 0; i < K; ++i) anorm[i] = wv[i] * inv;
        }
        __syncthreads();

        if (t < F) {
            float s = 0.f;
#pragma unroll
            for (int i = 0; i < K; ++i) s += anorm[i] * msgS[i][t];
            outacc[t] += s * (1.f / 3.f);
        }
        __syncthreads();
    }

    if (t < F) out[(size_t)c * F + t] = outacc[t];
}

// ---------------------------------------------------------------------------
extern "C" void kernel_launch(void* const* d_in, const int* in_sizes, int n_in,
                              void* d_out, int out_size, void* d_ws, size_t ws_size,
                              hipStream_t stream)
{
    const float* wts  = (const float*)d_in[0];
    const float* fea  = (const float*)d_in[1];
    const float* embW = (const float*)d_in[6];
    const float* embB = (const float*)d_in[7];
    const float* gW1  = (const float*)d_in[8];
    const float* gb1  = (const float*)d_in[9];
    const float* gW2  = (const float*)d_in[10];
    const float* gb2  = (const float*)d_in[11];
    const float* mW1  = (const float*)d_in[12];
    const float* mb1  = (const float*)d_in[13];
    const float* mW2  = (const float*)d_in[14];
    const float* mb2  = (const float*)d_in[15];
    const float* gpw  = (const float*)d_in[16];
    const float* cgW1 = (const float*)d_in[17];
    const float* cgb1 = (const float*)d_in[18];
    const float* cgW2 = (const float*)d_in[19];
    const float* cgb2 = (const float*)d_in[20];
    const float* cmW1 = (const float*)d_in[21];
    const float* cmb1 = (const float*)d_in[22];
    const float* cmW2 = (const float*)d_in[23];
    const float* cmb2 = (const float*)d_in[24];
    const float* cpw  = (const float*)d_in[25];

    const int N = in_sizes[0];   // 50000
    const int C = N / K;         // 10000
    const int layer_blocks = (C + 11) / 12;   // 834 (tail block guarded)

    float* x = (float*)d_ws;                       // [N,F] fp32, 12.8 MB
    const size_t xbytes = (size_t)N * F * 4;
    const size_t need = xbytes + (size_t)WALL_ELEMS * 2;

    embed_kernel<<<(N + ENB - 1) / ENB, 256, 0, stream>>>(fea, embW, embB, wts, x, N);

    if (ws_size >= need) {
        // ---- fast path ----
        _Float16* Wall  = (_Float16*)((char*)d_ws + xbytes);
        _Float16* W1sw  = Wall;
        _Float16* W2sw  = Wall + W1SW_ELEMS;
        _Float16* cW1sw = Wall + W1SW_ELEMS + W2SW_ELEMS;
        _Float16* cW2sw = Wall + W1SW_ELEMS + W2SW_ELEMS + CW1_ELEMS;

        prep_all<<<(WALL_ELEMS + 255) / 256, 256, 0, stream>>>(
            gW1, mW1, mW2, cgW1, cmW1, cmW2, Wall);
        for (int l = 0; l < NL; ++l)
            layer_wave<<<layer_blocks, 256, 0, stream>>>(x, W1sw, W2sw,
                                                         gb1, gb2, mb1, mb2, gW2, gpw, wts,
                                                         l, l * NH, N);
        pool_mfma<<<C / CB, 256, 0, stream>>>(x, cW1sw, cW2sw,
                                              cgb1, cgb2, cmb1, cmb2, cgW2, cpw, wts,
                                              (float*)d_out);
    } else {
        // ---- fallback: per-layer prep into d_out scratch ----
        _Float16* W1sw = (_Float16*)d_out;
        _Float16* W2sw = (_Float16*)((char*)d_out + 393216);
        for (int l = 0; l < NL; ++l) {
            prep_layer<<<(W1L_ELEMS + W2L_ELEMS) / 256, 256, 0, stream>>>(
                gW1, mW1, mW2, W1sw, W2sw, l);
            layer_wave<<<layer_blocks, 256, 0, stream>>>(x, W1sw, W2sw,
                                                         gb1, gb2, mb1, mb2, gW2, gpw, wts,
                                                         l, 0, N);
        }
        pool_kernel<<<C, 256, 0, stream>>>(x, cgW1, cgb1, cgW2, cgb2,
                                           cmW1, cmb1, cmW2, cmb2, cpw, wts,
                                           (float*)d_out);
    }
}

// Round 8
// 832.706 us; speedup vs baseline: 1.6949x; 1.0336x over previous
//
#include <hip/hip_runtime.h>
#include <hip/hip_bf16.h>

#define K 5
#define F 64
#define EMBD 200
#define HID 256
#define NH 3
#define NL 3
#define CB 8            // crystals per block for POOL kernels
#define NB (CB * K)     // 40 nodes per pool block

// layer kernel: 4 waves x 3 crystals = 12 crystals / block
#define CW 3            // crystals per wave
#define NWN (CW * K)    // 15 nodes per wave
#define EWE (CW * K * K) // 75 edges per wave
#define ET 5            // edge tiles of 16

typedef _Float16 half8 __attribute__((ext_vector_type(8)));
typedef _Float16 h2 __attribute__((ext_vector_type(2)));
typedef _Float16 h4 __attribute__((ext_vector_type(4)));
typedef __fp16 fp16x2 __attribute__((ext_vector_type(2)));
typedef float f32x4 __attribute__((ext_vector_type(4)));

__device__ __forceinline__ float lrelu(float v) { return v >= 0.f ? v : 0.01f * v; }

// cvt_pkrtz returns __fp16x2; bitcast to _Float16x2 (same bits, distinct clang types)
__device__ __forceinline__ h2 cvt_pk(float a, float b) {
    union { fp16x2 f; h2 h; } u;
    u.f = __builtin_amdgcn_cvt_pkrtz(a, b);
    return u.h;
}

__device__ __forceinline__ half8 lrelu8(half8 t) {
    half8 z = 0;
    half8 p = __builtin_elementwise_max(t, z);
    half8 n = __builtin_elementwise_min(t, z);
    return p + n * (_Float16)0.01f;
}

// ---- swizzled-weight element counts (fp16) ----
#define W1SW_ELEMS 589824    // 9 lh * 2 net * 2 half * 4 chunk * 4 nt * 2 ks * 64 * 8
#define W2SW_ELEMS 147456    // 9 lh * 8 ks2 * 4 nt * 64 * 8
#define CW1_ELEMS   98304    // 3 h * 2 net * 4 chunk * 4 nt * 2 ks * 64 * 8
#define CW2_ELEMS   49152    // 3 h * 8 ks2 * 4 nt * 64 * 8
#define WALL_ELEMS (W1SW_ELEMS + W2SW_ELEMS + CW1_ELEMS + CW2_ELEMS)  // 884736

// per-layer (fallback) sizes
#define W1L_ELEMS 196608
#define W2L_ELEMS 49152

// ---------------------------------------------------------------------------
// Fast path: swizzle ALL weights (layers + pool) fp32 -> fp16 B-frag order.
// ---------------------------------------------------------------------------
__global__ __launch_bounds__(256)
void prep_all(const float* __restrict__ gW1, const float* __restrict__ mW1,
              const float* __restrict__ mW2,
              const float* __restrict__ cgW1, const float* __restrict__ cmW1,
              const float* __restrict__ cmW2,
              _Float16* __restrict__ Wall)
{
    int tid = blockIdx.x * 256 + threadIdx.x;
    if (tid >= WALL_ELEMS) return;
    float v;
    if (tid < W1SW_ELEMS) {
        int j = tid & 7, lane = (tid >> 3) & 63;
        int r1 = tid >> 9;                       // [lh][net][half][chunk][nt][ks]
        int ks = r1 & 1, nt = (r1 >> 1) & 3, chunk = (r1 >> 3) & 3;
        int half = (r1 >> 5) & 1, net = (r1 >> 6) & 1, lh = r1 >> 7;   // 0..8
        int q = lane >> 4, n16 = lane & 15;
        const float* src = net ? mW1 : gW1;
        v = src[((size_t)lh * 128 + half * 64 + ks * 32 + q * 8 + j) * 256
                + chunk * 64 + nt * 16 + n16];
    } else if (tid < W1SW_ELEMS + W2SW_ELEMS) {
        int t2 = tid - W1SW_ELEMS;
        int j = t2 & 7, lane = (t2 >> 3) & 63;
        int r1 = t2 >> 9;                        // [lh][ks2][nt]
        int nt = r1 & 3, ks2 = (r1 >> 2) & 7, lh = r1 >> 5;            // 0..8
        int q = lane >> 4, n16 = lane & 15;
        v = mW2[((size_t)lh * 256 + ks2 * 32 + q * 8 + j) * 64 + nt * 16 + n16];
    } else if (tid < W1SW_ELEMS + W2SW_ELEMS + CW1_ELEMS) {
        int t2 = tid - (W1SW_ELEMS + W2SW_ELEMS);
        int j = t2 & 7, lane = (t2 >> 3) & 63;
        int r1 = t2 >> 9;                        // [h][net][chunk][nt][ks]
        int ks = r1 & 1, nt = (r1 >> 1) & 3, chunk = (r1 >> 3) & 3;
        int net = (r1 >> 5) & 1, h = r1 >> 6;                          // 0..2
        int q = lane >> 4, n16 = lane & 15;
        const float* src = net ? cmW1 : cgW1;
        v = src[((size_t)h * 64 + ks * 32 + q * 8 + j) * 256
                + chunk * 64 + nt * 16 + n16];
    } else {
        int t2 = tid - (W1SW_ELEMS + W2SW_ELEMS + CW1_ELEMS);
        int j = t2 & 7, lane = (t2 >> 3) & 63;
        int r1 = t2 >> 9;                        // [h][ks2][nt]
        int nt = r1 & 3, ks2 = (r1 >> 2) & 7, h = r1 >> 5;             // 0..2
        int q = lane >> 4, n16 = lane & 15;
        v = cmW2[((size_t)h * 256 + ks2 * 32 + q * 8 + j) * 64 + nt * 16 + n16];
    }
    Wall[tid] = (_Float16)v;
}

// ---------------------------------------------------------------------------
// Fallback: per-layer prep into d_out scratch (round-4 proven).
// ---------------------------------------------------------------------------
__global__ __launch_bounds__(256)
void prep_layer(const float* __restrict__ gW1, const float* __restrict__ mW1,
                const float* __restrict__ mW2,
                _Float16* __restrict__ W1sw, _Float16* __restrict__ W2sw, int l)
{
    int tid = blockIdx.x * 256 + threadIdx.x;
    if (tid < W1L_ELEMS) {
        int j = tid & 7, lane = (tid >> 3) & 63;
        int r1 = tid >> 9;
        int ks = r1 & 1, nt = (r1 >> 1) & 3, chunk = (r1 >> 3) & 3;
        int half = (r1 >> 5) & 1, net = (r1 >> 6) & 1, hh = r1 >> 7;
        int q = lane >> 4, n16 = lane & 15;
        const float* src = net ? mW1 : gW1;
        float v = src[((size_t)(l * NH + hh) * 128 + half * 64 + ks * 32 + q * 8 + j) * 256
                      + chunk * 64 + nt * 16 + n16];
        W1sw[tid] = (_Float16)v;
    } else {
        int t2 = tid - W1L_ELEMS;
        if (t2 < W2L_ELEMS) {
            int j = t2 & 7, lane = (t2 >> 3) & 63;
            int r1 = t2 >> 9;
            int nt = r1 & 3, ks2 = (r1 >> 2) & 7, hh = r1 >> 5;
            int q = lane >> 4, n16 = lane & 15;
            float v = mW2[((size_t)(l * NH + hh) * 256 + ks2 * 32 + q * 8 + j) * 64
                          + nt * 16 + n16];
            W2sw[t2] = (_Float16)v;
        }
    }
}

// ---------------------------------------------------------------------------
// Embedding — 16 nodes / 256-thread block; fea tile staged in LDS; thread
// (nl,o) computes 4 output cols {o, o+16, o+32, o+48} for node nl.
// ---------------------------------------------------------------------------
#define ENB 16   // nodes per embed block

__global__ __launch_bounds__(256)
void embed_kernel(const float* __restrict__ fea, const float* __restrict__ W,
                  const float* __restrict__ b, const float* __restrict__ wts,
                  float* __restrict__ x, int Ntot)
{
    __shared__ float fs[ENB * EMBD];
    const int t = threadIdx.x;
    const int node0 = blockIdx.x * ENB;
    int nvalid = Ntot - node0;
    if (nvalid > ENB) nvalid = ENB;
    if (nvalid <= 0) return;
    const int lim = nvalid * EMBD;
    for (int d = t; d < lim; d += 256) fs[d] = fea[(size_t)node0 * EMBD + d];
    __syncthreads();

    const int nl = t >> 4;          // local node 0..15
    const int o  = t & 15;          // output column group
    if (nl >= nvalid) return;
    const int n = node0 + nl;

    float acc[4];
#pragma unroll
    for (int k2 = 0; k2 < 4; ++k2) {
        int oc = o + 16 * k2;
        acc[k2] = (oc < F - 1) ? b[oc] : wts[n];
    }
    const float* fsr = fs + nl * EMBD;
#pragma unroll 4
    for (int e = 0; e < EMBD; ++e) {
        float xv = fsr[e];                       // quad-broadcast LDS read
        const float* wr = W + (size_t)e * (F - 1);
#pragma unroll
        for (int k2 = 0; k2 < 4; ++k2) {
            int oc = o + 16 * k2;
            if (oc < F - 1) acc[k2] += xv * wr[oc];
        }
    }
#pragma unroll
    for (int k2 = 0; k2 < 4; ++k2)
        x[(size_t)n * F + o + 16 * k2] = acc[k2];
}

// ---------------------------------------------------------------------------
// One graph layer — barrier-free, 4 independent waves / block, each wave owns
// 3 crystals (15 nodes, 75 edges). GEMM2 B-frags hoisted. Wave LDS 12288 B.
// (256,2): round-10 proven — 2 blocks/CU, occupancy 18%, no spill.
// Round 12 proven: transposed stage-1 mfma + packed b64 PQ writes + fdot2 gate
// (186.7 us/layer). Round 13 (PQ dbuf + full c-unroll) REGRESSED to 370 us:
// register pressure blew the (256,2) cap and spilled accumulators to scratch.
// This structure is pinned at 2 waves/SIMD; do not restructure its schedule.
// ---------------------------------------------------------------------------
#define WAVE_LDS 12288   // bytes per wave slice

__global__ __launch_bounds__(256, 2)
void layer_wave(float* __restrict__ x,
                const _Float16* __restrict__ W1sw,
                const _Float16* __restrict__ W2sw,
                const float* __restrict__ gb1, const float* __restrict__ gb2v,
                const float* __restrict__ mb1, const float* __restrict__ mb2,
                const float* __restrict__ gW2, const float* __restrict__ gpw,
                const float* __restrict__ wts, int l, int lhw0, int Ntot)
{
    __shared__ __align__(16) char smem[4 * WAVE_LDS];

    const int t = threadIdx.x, w = t >> 6, lane = t & 63;
    const int q = lane >> 4, m16 = lane & 15;

    char* wb = smem + w * WAVE_LDS;
    _Float16 (*PQ)[16][72] = (_Float16 (*)[16][72])wb;   // [4][16][72] = 9216 B
    _Float16 (*msgL)[72]   = (_Float16 (*)[72])wb;       // [80][72] = 11520 B (aliases PQ)
    float* gateS  = (float*)(wb + 11520);                // [80]
    float* anormS = (float*)(wb + 11840);                // [80]
    float* wpowS  = (float*)(wb + 12160);                // [16]

    const int nw0 = (blockIdx.x * 12 + w * CW) * K;      // first node of this wave
    const int vn  = (Ntot - nw0 < NWN) ? (Ntot - nw0) : NWN;  // valid nodes (may be <=0)

    // ---- A-fragments of x (head/half-invariant), fp16, loaded once ----
    half8 A[2];
    {
        int arow = nw0 + m16;
        if (arow > Ntot - 1) arow = Ntot - 1;            // clamp pad rows (finite junk)
        if (arow < 0) arow = 0;
        const float* xr = x + (size_t)arow * F;
#pragma unroll
        for (int ks = 0; ks < 2; ++ks) {
            float4 f0 = *(const float4*)(xr + ks * 32 + q * 8);
            float4 f1 = *(const float4*)(xr + ks * 32 + q * 8 + 4);
            half8 a;
            a[0] = (_Float16)f0.x; a[1] = (_Float16)f0.y;
            a[2] = (_Float16)f0.z; a[3] = (_Float16)f0.w;
            a[4] = (_Float16)f1.x; a[5] = (_Float16)f1.y;
            a[6] = (_Float16)f1.z; a[7] = (_Float16)f1.w;
            A[ks] = a;
        }
    }

    // ---- per-lane edge -> local node rows (75 valid edges in 5 tiles of 16) ----
    int iR[ET], jR[ET];
#pragma unroll
    for (int et = 0; et < ET; ++et) {
        int e = et * 16 + m16;
        if (e < EWE) {
            int cl = e / 25, rm = e % 25;
            iR[et] = cl * K + rm / K;
            jR[et] = cl * K + rm % K;
        } else { iR[et] = 15; jR[et] = 15; }             // pad row (clamped x, finite)
    }

    float oacc[NWN];
#pragma unroll
    for (int n = 0; n < NWN; ++n) oacc[n] = 0.f;

    for (int h = 0; h < NH; ++h) {
        const int lh = l * NH + h, lhw = lhw0 + h;

        if (lane < NWN) {
            int wi = nw0 + lane;
            if (wi > Ntot - 1) wi = Ntot - 1;
            if (wi < 0) wi = 0;
            wpowS[lane] = powf(wts[wi], gpw[lh]);
        }
        if (lane >= NWN && lane < NWN + 5) anormS[EWE + (lane - NWN)] = 0.f;  // pad slots 75..79

        f32x4 acc2[ET][4];
#pragma unroll
        for (int et = 0; et < ET; ++et)
#pragma unroll
            for (int nt = 0; nt < 4; ++nt) acc2[et][nt] = (f32x4){0.f, 0.f, 0.f, 0.f};
        float gacc[ET] = {0.f, 0.f, 0.f, 0.f, 0.f};

        for (int c = 0; c < 4; ++c) {
            // ---- GEMM2 B-frags for this chunk: issue early, reuse for 5 et ----
            half8 B2[8];
            {
                const _Float16* W2b = W2sw + ((size_t)lhw * 8 + c * 2) * 2048;
#pragma unroll
                for (int f = 0; f < 8; ++f)
                    B2[f] = *(const half8*)(W2b + ((size_t)f * 64 + lane) * 8);
            }

            // ---- stage-1: all 4 net-halves, TRANSPOSED mfma -> packed writes ----
#pragma unroll
            for (int hf = 0; hf < 4; ++hf) {
                f32x4 accS[4];
#pragma unroll
                for (int nt = 0; nt < 4; ++nt) accS[nt] = (f32x4){0.f, 0.f, 0.f, 0.f};
                const _Float16* Wb = W1sw + ((size_t)lhw * 4 + hf) * 16384 + c * 4096;
#pragma unroll
                for (int nt = 0; nt < 4; ++nt)
#pragma unroll
                    for (int ks = 0; ks < 2; ++ks) {
                        half8 B = *(const half8*)(Wb + ((nt * 2 + ks) * 64 + lane) * 8);
                        // swapped operands: D[hid][node]
                        accS[nt] = __builtin_amdgcn_mfma_f32_16x16x32_f16(
                            B, A[ks], accS[nt], 0, 0, 0);
                    }
                // lane holds hid = nt*16 + q*4 + rg for node = m16 -> one b64/nt
#pragma unroll
                for (int nt = 0; nt < 4; ++nt) {
                    h2 lo = cvt_pk(accS[nt][0], accS[nt][1]);
                    h2 hi = cvt_pk(accS[nt][2], accS[nt][3]);
                    h4 pk = __builtin_shufflevector(lo, hi, 0, 1, 2, 3);
                    *(h4*)&PQ[hf][m16][nt * 16 + q * 4] = pk;
                }
            }

            // ---- per-chunk bias slices (global, L1-hot); wg packed to f16 ----
            half8 bg8[2], bm8[2];
            h2 wgh2[2][4];
#pragma unroll
            for (int ks = 0; ks < 2; ++ks) {
                const int ub = c * 64 + ks * 32 + q * 8;
                float4 g0 = *(const float4*)(gb1 + (size_t)lh * HID + ub);
                float4 g1 = *(const float4*)(gb1 + (size_t)lh * HID + ub + 4);
                float4 m0 = *(const float4*)(mb1 + (size_t)lh * HID + ub);
                float4 m1 = *(const float4*)(mb1 + (size_t)lh * HID + ub + 4);
                float4 w0 = *(const float4*)(gW2 + (size_t)lh * HID + ub);
                float4 w1 = *(const float4*)(gW2 + (size_t)lh * HID + ub + 4);
                half8 bg, bm;
                bg[0]=(_Float16)g0.x; bg[1]=(_Float16)g0.y; bg[2]=(_Float16)g0.z; bg[3]=(_Float16)g0.w;
                bg[4]=(_Float16)g1.x; bg[5]=(_Float16)g1.y; bg[6]=(_Float16)g1.z; bg[7]=(_Float16)g1.w;
                bm[0]=(_Float16)m0.x; bm[1]=(_Float16)m0.y; bm[2]=(_Float16)m0.z; bm[3]=(_Float16)m0.w;
                bm[4]=(_Float16)m1.x; bm[5]=(_Float16)m1.y; bm[6]=(_Float16)m1.z; bm[7]=(_Float16)m1.w;
                bg8[ks] = bg; bm8[ks] = bm;
                wgh2[ks][0] = cvt_pk(w0.x, w0.y);
                wgh2[ks][1] = cvt_pk(w0.z, w0.w);
                wgh2[ks][2] = cvt_pk(w1.x, w1.y);
                wgh2[ks][3] = cvt_pk(w1.z, w1.w);
            }

            // ---- consume: gate fdot2 + hm A-frags + GEMM2 (B2 reused) ----
#pragma unroll
            for (int et = 0; et < ET; ++et) {
                half8 af[2];
#pragma unroll
                for (int ks = 0; ks < 2; ++ks) {
                    const int ub = ks * 32 + q * 8;
                    half8 pg = *(const half8*)&PQ[0][iR[et]][ub];
                    half8 qg = *(const half8*)&PQ[1][jR[et]][ub];
                    half8 pm = *(const half8*)&PQ[2][iR[et]][ub];
                    half8 qm = *(const half8*)&PQ[3][jR[et]][ub];
                    half8 tg = lrelu8(pg + qg + bg8[ks]);
                    h2 t01 = __builtin_shufflevector(tg, tg, 0, 1);
                    h2 t23 = __builtin_shufflevector(tg, tg, 2, 3);
                    h2 t45 = __builtin_shufflevector(tg, tg, 4, 5);
                    h2 t67 = __builtin_shufflevector(tg, tg, 6, 7);
                    gacc[et] = __builtin_amdgcn_fdot2(t01, wgh2[ks][0], gacc[et], false);
                    gacc[et] = __builtin_amdgcn_fdot2(t23, wgh2[ks][1], gacc[et], false);
                    gacc[et] = __builtin_amdgcn_fdot2(t45, wgh2[ks][2], gacc[et], false);
                    gacc[et] = __builtin_amdgcn_fdot2(t67, wgh2[ks][3], gacc[et], false);
                    af[ks] = lrelu8(pm + qm + bm8[ks]);
                }
#pragma unroll
                for (int nt = 0; nt < 4; ++nt)
#pragma unroll
                    for (int ks = 0; ks < 2; ++ks)
                        acc2[et][nt] = __builtin_amdgcn_mfma_f32_16x16x32_f16(
                            af[ks], B2[ks * 4 + nt], acc2[et][nt], 0, 0, 0);
            }
        }

        // ---- gate reduce across quads (k-slices) ----
        const float gb2s = gb2v[lh];
#pragma unroll
        for (int et = 0; et < ET; ++et) {
            float g = gacc[et];
            g += __shfl_xor(g, 16);
            g += __shfl_xor(g, 32);
            if (q == 0) gateS[et * 16 + m16] = g + gb2s;
        }

        // ---- segment softmax: lane n (0..14) handles local node n (5 edges) ----
        if (lane < NWN) {
            const int cl5 = (lane / K) * K;
            float gg[K], mx = -1e30f;
#pragma unroll
            for (int jj = 0; jj < K; ++jj) {
                gg[jj] = gateS[lane * K + jj];
                mx = fmaxf(mx, gg[jj]);
            }
            float s = 0.f, wv[K];
#pragma unroll
            for (int jj = 0; jj < K; ++jj) {
                wv[jj] = wpowS[cl5 + jj] * expf(gg[jj] - mx);
                s += wv[jj];
            }
            float inv = 1.f / (s + 1e-10f) * (1.f / 3.f);  // fold head mean
#pragma unroll
            for (int jj = 0; jj < K; ++jj) anormS[lane * K + jj] = wv[jj] * inv;
        }

        // ---- weighted msg -> msgL (PQ region dead) ----
        float b2v[4];
#pragma unroll
        for (int nt = 0; nt < 4; ++nt) b2v[nt] = mb2[(size_t)lh * F + nt * 16 + m16];
#pragma unroll
        for (int et = 0; et < ET; ++et) {
            f32x4 an = *(const f32x4*)&anormS[et * 16 + q * 4];
#pragma unroll
            for (int nt = 0; nt < 4; ++nt)
#pragma unroll
                for (int rg = 0; rg < 4; ++rg) {
                    float v = (acc2[et][nt][rg] + b2v[nt]) * an[rg];
                    msgL[et * 16 + q * 4 + rg][nt * 16 + m16] = (_Float16)v;
                }
        }

        // ---- aggregate: lane = output col, 15 nodes x 5 edges ----
#pragma unroll
        for (int n = 0; n < NWN; ++n) {
            float s = 0.f;
#pragma unroll
            for (int jj = 0; jj < K; ++jj) s += (float)msgL[n * K + jj][lane];
            oacc[n] += s;
        }
    }

    // ---- residual + write back (own valid rows only) ----
#pragma unroll
    for (int n = 0; n < NWN; ++n) {
        if (n < vn) {
            size_t idx = (size_t)(nw0 + n) * F + lane;
            x[idx] = oacc[n] + x[idx];
        }
    }
}

// ---------------------------------------------------------------------------
// Round 15: pool_wave — pool rewritten in the PROVEN layer_wave structure.
// Barrier-free, 4 independent waves/block, wave owns 3 crystals (15 nodes).
// Same transposed stage-1 (2 net-halves: gate, msg), same fdot2 gate, consume
// is ONE 16-row tile (nodes, no edge gather) -> acc2[4] only. Softmax over 5
// nodes/crystal, aggregate, single store per crystal. Reuses cW1sw/cW2sw with
// pool_mfma's exact fragment indexing. Replaces the 24-barrier pool_mfma.
// Wave LDS slice 4800 B (PQ [2][16][72] + gate/anorm/wpow; msgL aliases PQ).
// ---------------------------------------------------------------------------
#define PWAVE_LDS 4800

__global__ __launch_bounds__(256, 2)
void pool_wave(const float* __restrict__ x,
               const _Float16* __restrict__ cW1sw,
               const _Float16* __restrict__ cW2sw,
               const float* __restrict__ cgb1, const float* __restrict__ cgb2v,
               const float* __restrict__ cmb1, const float* __restrict__ cmb2,
               const float* __restrict__ cgW2, const float* __restrict__ cpw,
               const float* __restrict__ wts, float* __restrict__ out, int Ctot)
{
    __shared__ __align__(16) char smem[4 * PWAVE_LDS];

    const int t = threadIdx.x, w = t >> 6, lane = t & 63;
    const int q = lane >> 4, m16 = lane & 15;

    char* wb = smem + w * PWAVE_LDS;
    _Float16 (*PQ)[16][72] = (_Float16 (*)[16][72])wb;   // [2][16][72] = 4608 B
    _Float16 (*msgL)[72]   = (_Float16 (*)[72])wb;       // [16][72] (aliases PQ)
    float* gateS  = (float*)(wb + 4608);                 // [16]
    float* anormS = (float*)(wb + 4672);                 // [16]
    float* wpowS  = (float*)(wb + 4736);                 // [16]

    const int c0  = blockIdx.x * 12 + w * CW;            // first crystal of wave
    const int nw0 = c0 * K;
    const int Ntot = Ctot * K;
    const int vc  = (Ctot - c0 < CW) ? (Ctot - c0) : CW; // valid crystals (may be <=0)

    // ---- A-fragments of x rows (same as layer_wave) ----
    half8 A[2];
    {
        int arow = nw0 + m16;
        if (arow > Ntot - 1) arow = Ntot - 1;
        if (arow < 0) arow = 0;
        const float* xr = x + (size_t)arow * F;
#pragma unroll
        for (int ks = 0; ks < 2; ++ks) {
            float4 f0 = *(const float4*)(xr + ks * 32 + q * 8);
            float4 f1 = *(const float4*)(xr + ks * 32 + q * 8 + 4);
            half8 a;
            a[0] = (_Float16)f0.x; a[1] = (_Float16)f0.y;
            a[2] = (_Float16)f0.z; a[3] = (_Float16)f0.w;
            a[4] = (_Float16)f1.x; a[5] = (_Float16)f1.y;
            a[6] = (_Float16)f1.z; a[7] = (_Float16)f1.w;
            A[ks] = a;
        }
    }

    float oacc[CW] = {0.f, 0.f, 0.f};   // per-lane output col, per crystal

    for (int h = 0; h < NH; ++h) {
        if (lane < NWN) {
            int wi = nw0 + lane;
            if (wi > Ntot - 1) wi = Ntot - 1;
            if (wi < 0) wi = 0;
            wpowS[lane] = powf(wts[wi], cpw[h]);
        }
        if (lane == NWN) anormS[15] = 0.f;               // pad node row

        f32x4 acc2[4];
#pragma unroll
        for (int nt = 0; nt < 4; ++nt) acc2[nt] = (f32x4){0.f, 0.f, 0.f, 0.f};
        float gacc = 0.f;

        for (int c = 0; c < 4; ++c) {
            // ---- GEMM2 B-frags (pool_mfma's indexing) ----
            half8 B2[8];
            {
                const _Float16* W2b = cW2sw + (size_t)h * 16384 + c * 4096;
#pragma unroll
                for (int f = 0; f < 8; ++f)
                    B2[f] = *(const half8*)(W2b + ((size_t)f * 64 + lane) * 8);
            }

            // ---- stage-1: 2 nets (0=gate, 1=msg), transposed mfma ----
#pragma unroll
            for (int net = 0; net < 2; ++net) {
                f32x4 accS[4];
#pragma unroll
                for (int nt = 0; nt < 4; ++nt) accS[nt] = (f32x4){0.f, 0.f, 0.f, 0.f};
                const _Float16* Wb = cW1sw + ((size_t)(h * 2 + net) * 4 + c) * 4096;
#pragma unroll
                for (int nt = 0; nt < 4; ++nt)
#pragma unroll
                    for (int ks = 0; ks < 2; ++ks) {
                        half8 B = *(const half8*)(Wb + ((nt * 2 + ks) * 64 + lane) * 8);
                        accS[nt] = __builtin_amdgcn_mfma_f32_16x16x32_f16(
                            B, A[ks], accS[nt], 0, 0, 0);
                    }
#pragma unroll
                for (int nt = 0; nt < 4; ++nt) {
                    h2 lo = cvt_pk(accS[nt][0], accS[nt][1]);
                    h2 hi = cvt_pk(accS[nt][2], accS[nt][3]);
                    h4 pk = __builtin_shufflevector(lo, hi, 0, 1, 2, 3);
                    *(h4*)&PQ[net][m16][nt * 16 + q * 4] = pk;
                }
            }

            // ---- per-chunk bias slices; gate W2 packed to f16 ----
            half8 bg8[2], bm8[2];
            h2 wgh2[2][4];
#pragma unroll
            for (int ks = 0; ks < 2; ++ks) {
                const int ub = c * 64 + ks * 32 + q * 8;
                float4 g0 = *(const float4*)(cgb1 + (size_t)h * HID + ub);
                float4 g1 = *(const float4*)(cgb1 + (size_t)h * HID + ub + 4);
                float4 m0 = *(const float4*)(cmb1 + (size_t)h * HID + ub);
                float4 m1 = *(const float4*)(cmb1 + (size_t)h * HID + ub + 4);
                float4 w0 = *(const float4*)(cgW2 + (size_t)h * HID + ub);
                float4 w1 = *(const float4*)(cgW2 + (size_t)h * HID + ub + 4);
                half8 bg, bm;
                bg[0]=(_Float16)g0.x; bg[1]=(_Float16)g0.y; bg[2]=(_Float16)g0.z; bg[3]=(_Float16)g0.w;
                bg[4]=(_Float16)g1.x; bg[5]=(_Float16)g1.y; bg[6]=(_Float16)g1.z; bg[7]=(_Float16)g1.w;
                bm[0]=(_Float16)m0.x; bm[1]=(_Float16)m0.y; bm[2]=(_Float16)m0.z; bm[3]=(_Float16)m0.w;
                bm[4]=(_Float16)m1.x; bm[5]=(_Float16)m1.y; bm[6]=(_Float16)m1.z; bm[7]=(_Float16)m1.w;
                bg8[ks] = bg; bm8[ks] = bm;
                wgh2[ks][0] = cvt_pk(w0.x, w0.y);
                wgh2[ks][1] = cvt_pk(w0.z, w0.w);
                wgh2[ks][2] = cvt_pk(w1.x, w1.y);
                wgh2[ks][3] = cvt_pk(w1.z, w1.w);
            }

            // ---- consume: single node tile (rows = m16, no gather) ----
            {
                half8 af[2];
#pragma unroll
                for (int ks = 0; ks < 2; ++ks) {
                    const int ub = ks * 32 + q * 8;
                    half8 pg = *(const half8*)&PQ[0][m16][ub];
                    half8 pm = *(const half8*)&PQ[1][m16][ub];
                    half8 tg = lrelu8(pg + bg8[ks]);
                    h2 t01 = __builtin_shufflevector(tg, tg, 0, 1);
                    h2 t23 = __builtin_shufflevector(tg, tg, 2, 3);
                    h2 t45 = __builtin_shufflevector(tg, tg, 4, 5);
                    h2 t67 = __builtin_shufflevector(tg, tg, 6, 7);
                    gacc = __builtin_amdgcn_fdot2(t01, wgh2[ks][0], gacc, false);
                    gacc = __builtin_amdgcn_fdot2(t23, wgh2[ks][1], gacc, false);
                    gacc = __builtin_amdgcn_fdot2(t45, wgh2[ks][2], gacc, false);
                    gacc = __builtin_amdgcn_fdot2(t67, wgh2[ks][3], gacc, false);
                    af[ks] = lrelu8(pm + bm8[ks]);
                }
#pragma unroll
                for (int nt = 0; nt < 4; ++nt)
#pragma unroll
                    for (int ks = 0; ks < 2; ++ks)
                        acc2[nt] = __builtin_amdgcn_mfma_f32_16x16x32_f16(
                            af[ks], B2[ks * 4 + nt], acc2[nt], 0, 0, 0);
            }
        }

        // ---- gate reduce across quads ----
        const float gb2s = cgb2v[h];
        {
            float g = gacc;
            g += __shfl_xor(g, 16);
            g += __shfl_xor(g, 32);
            if (q == 0) gateS[m16] = g + gb2s;
        }

        // ---- segment softmax: lane cl (0..2) handles crystal cl (5 nodes) ----
        if (lane < CW) {
            const int n0 = lane * K;
            float gg[K], mx = -1e30f;
#pragma unroll
            for (int jj = 0; jj < K; ++jj) {
                gg[jj] = gateS[n0 + jj];
                mx = fmaxf(mx, gg[jj]);
            }
            float s = 0.f, wv[K];
#pragma unroll
            for (int jj = 0; jj < K; ++jj) {
                wv[jj] = wpowS[n0 + jj] * expf(gg[jj] - mx);
                s += wv[jj];
            }
            float inv = 1.f / (s + 1e-10f) * (1.f / 3.f);  // fold head mean
#pragma unroll
            for (int jj = 0; jj < K; ++jj) anormS[n0 + jj] = wv[jj] * inv;
        }

        // ---- weighted msg -> msgL (PQ region dead after consume) ----
        float b2v[4];
#pragma unroll
        for (int nt = 0; nt < 4; ++nt) b2v[nt] = cmb2[(size_t)h * F + nt * 16 + m16];
#pragma unroll
        for (int nt = 0; nt < 4; ++nt)
#pragma unroll
            for (int rg = 0; rg < 4; ++rg) {
                int row = q * 4 + rg;
                float v = (acc2[nt][rg] + b2v[nt]) * anormS[row];
                msgL[row][nt * 16 + m16] = (_Float16)v;
            }

        // ---- aggregate: lane = output col, 3 crystals x 5 nodes ----
#pragma unroll
        for (int cl = 0; cl < CW; ++cl) {
            float s = 0.f;
#pragma unroll
            for (int jj = 0; jj < K; ++jj) s += (float)msgL[cl * K + jj][lane];
            oacc[cl] += s;
        }
    }

    // ---- store (valid crystals only) ----
#pragma unroll
    for (int cl = 0; cl < CW; ++cl)
        if (cl < vc)
            out[(size_t)(c0 + cl) * F + lane] = oacc[cl];
}

// ---------------------------------------------------------------------------
// MFMA pool (round-5 proven) — kept as reference; superseded by pool_wave.
// ---------------------------------------------------------------------------
__global__ __launch_bounds__(256)
void pool_mfma(const float* __restrict__ x,
               const _Float16* __restrict__ cW1sw,
               const _Float16* __restrict__ cW2sw,
               const float* __restrict__ cgb1, const float* __restrict__ cgb2v,
               const float* __restrict__ cmb1, const float* __restrict__ cmb2,
               const float* __restrict__ cgW2, const float* __restrict__ cpw,
               const float* __restrict__ wts, float* __restrict__ out)
{
    __shared__ __align__(16) _Float16 xh[48][72];
    __shared__ __align__(16) char PQraw[2 * 48 * 72 * 2];
    __shared__ float outacc[CB * F];
    __shared__ float b1gS[HID], b1mS[HID], w2gS[HID], b2mS[F];
    __shared__ float gateS[48], anormS[48], wpowS[48];

    _Float16 (*P)[48][72] = (_Float16 (*)[48][72])PQraw;
    _Float16 (*msgW)[72]  = (_Float16 (*)[72])PQraw;

    const int t = threadIdx.x, w = t >> 6, lane = t & 63;
    const int quad = lane >> 4, m16 = lane & 15;
    const int node0 = blockIdx.x * NB;

    for (int d = t; d < 48 * 64; d += 256) {
        int r = d >> 6, cc = d & 63;
        float v = (r < NB) ? x[(size_t)(node0 + r) * F + cc] : 0.f;
        xh[r][cc] = (_Float16)v;
    }
    for (int d = t; d < CB * F; d += 256) outacc[d] = 0.f;
    __syncthreads();

    half8 A[3][2];
#pragma unroll
    for (int Mt = 0; Mt < 3; ++Mt)
#pragma unroll
        for (int ks = 0; ks < 2; ++ks)
            A[Mt][ks] = *(const half8*)&xh[Mt * 16 + m16][ks * 32 + quad * 8];

    const int net = w >> 1, ntp = w & 1;

    for (int h = 0; h < NH; ++h) {
        if (t < HID) {
            b1gS[t] = cgb1[(size_t)h * HID + t];
            b1mS[t] = cmb1[(size_t)h * HID + t];
            w2gS[t] = cgW2[(size_t)h * HID + t];
        }
        if (t < F)  b2mS[t] = cmb2[(size_t)h * F + t];
        if (t < NB) wpowS[t] = powf(wts[node0 + t], cpw[h]);
        const float gb2s = cgb2v[h];

        f32x4 acc2[4];
#pragma unroll
        for (int nt = 0; nt < 4; ++nt) acc2[nt] = (f32x4){0.f, 0.f, 0.f, 0.f};
        float gacc = 0.f;

        for (int chunk = 0; chunk < 4; ++chunk) {
            {
                f32x4 accS[3][2];
#pragma unroll
                for (int Mt = 0; Mt < 3; ++Mt)
#pragma unroll
                    for (int n2 = 0; n2 < 2; ++n2) accS[Mt][n2] = (f32x4){0.f, 0.f, 0.f, 0.f};
                const _Float16* Wb = cW1sw + ((size_t)(h * 2 + net) * 4 + chunk) * 4096;
#pragma unroll
                for (int n2 = 0; n2 < 2; ++n2) {
                    int nt = ntp * 2 + n2;
#pragma unroll
                    for (int ks = 0; ks < 2; ++ks) {
                        half8 B = *(const half8*)(Wb + ((nt * 2 + ks) * 64 + lane) * 8);
#pragma unroll
                        for (int Mt = 0; Mt < 3; ++Mt)
                            accS[Mt][n2] = __builtin_amdgcn_mfma_f32_16x16x32_f16(
                                A[Mt][ks], B, accS[Mt][n2], 0, 0, 0);
                    }
                }
#pragma unroll
                for (int Mt = 0; Mt < 3; ++Mt)
#pragma unroll
                    for (int n2 = 0; n2 < 2; ++n2)
#pragma unroll
                        for (int rg = 0; rg < 4; ++rg)
                            P[net][Mt * 16 + quad * 4 + rg][(ntp * 2 + n2) * 16 + m16] =
                                (_Float16)accS[Mt][n2][rg];
            }
            __syncthreads();

            if (w < 3) {
                half8 af[2];
#pragma unroll
                for (int ks = 0; ks < 2; ++ks) {
                    const int ub = ks * 32 + quad * 8;
                    half8 pg = *(const half8*)&P[0][w * 16 + m16][ub];
                    half8 pm = *(const half8*)&P[1][w * 16 + m16][ub];
#pragma unroll
                    for (int j = 0; j < 8; ++j) {
                        int u = chunk * 64 + ub + j;
                        float gh = lrelu((float)pg[j] + b1gS[u]);
                        gacc += gh * w2gS[u];
                        float hv = lrelu((float)pm[j] + b1mS[u]);
                        af[ks][j] = (_Float16)hv;
                    }
                }
                const _Float16* W2b = cW2sw + (size_t)h * 16384 + chunk * 4096;
#pragma unroll
                for (int nt = 0; nt < 4; ++nt)
#pragma unroll
                    for (int ks = 0; ks < 2; ++ks) {
                        half8 B = *(const half8*)(W2b + ((size_t)(ks * 4 + nt) * 64 + lane) * 8);
                        acc2[nt] = __builtin_amdgcn_mfma_f32_16x16x32_f16(
                            af[ks], B, acc2[nt], 0, 0, 0);
                    }
            }
            __syncthreads();
        }

        if (w < 3) {
            float g = gacc;
            g += __shfl_xor(g, 16);
            g += __shfl_xor(g, 32);
            if (quad == 0) gateS[w * 16 + m16] = g + gb2s;
        }
        __syncthreads();

        if (t < CB) {
            float mx = -1e30f;
#pragma unroll
            for (int j = 0; j < K; ++j) mx = fmaxf(mx, gateS[t * K + j]);
            float s = 0.f, wv[K];
#pragma unroll
            for (int j = 0; j < K; ++j) {
                wv[j] = wpowS[t * K + j] * expf(gateS[t * K + j] - mx);
                s += wv[j];
            }
            float inv = 1.f / (s + 1e-10f) * (1.f / 3.f);
#pragma unroll
            for (int j = 0; j < K; ++j) anormS[t * K + j] = wv[j] * inv;
        }
        __syncthreads();

        if (w < 3) {
#pragma unroll
            for (int nt = 0; nt < 4; ++nt)
#pragma unroll
                for (int rg = 0; rg < 4; ++rg) {
                    int row = w * 16 + quad * 4 + rg;
                    float a = (row < NB) ? anormS[row] : 0.f;
                    float v = (acc2[nt][rg] + b2mS[nt * 16 + m16]) * a;
                    msgW[row][nt * 16 + m16] = (_Float16)v;
                }
        }
        __syncthreads();

        for (int d = t; d < CB * F; d += 256) {
            int cr = d >> 6, o = d & 63;
            float s = 0.f;
#pragma unroll
            for (int j = 0; j < K; ++j) s += (float)msgW[cr * K + j][o];
            outacc[d] += s;
        }
        __syncthreads();
    }

    for (int d = t; d < CB * F; d += 256)
        out[(size_t)blockIdx.x * (CB * F) + d] = outacc[d];
}

// ---------------------------------------------------------------------------
// Fallback fp32 pool (round-4 proven)
// ---------------------------------------------------------------------------
__global__ __launch_bounds__(256)
void pool_kernel(const float* __restrict__ x,
                 const float* __restrict__ cgW1, const float* __restrict__ cgb1,
                 const float* __restrict__ cgW2, const float* __restrict__ cgb2,
                 const float* __restrict__ cmW1, const float* __restrict__ cmb1,
                 const float* __restrict__ cmW2, const float* __restrict__ cmb2,
                 const float* __restrict__ cpw, const float* __restrict__ wts,
                 float* __restrict__ out)
{
    __shared__ float xs[K * F];
    __shared__ float hmS[K][HID];
    __shared__ float msgS[K][F];
    __shared__ float outacc[F];
    __shared__ float b1g[HID], b1m[HID], w2g[HID];
    __shared__ float b2mS[F];
    __shared__ float gpart[K][2];
    __shared__ float gate_s[K];
    __shared__ float anorm[K];
    __shared__ float wn[K], wpow[K];

    const int c = blockIdx.x;
    const int t = threadIdx.x;
    const int wave = t >> 6, lane = t & 63;

    for (int d = t; d < K * F; d += 256) xs[d] = x[c * K * F + d];
    if (t < F) outacc[t] = 0.f;
    if (t < K) wn[t] = wts[c * K + t];
    __syncthreads();

    for (int h = 0; h < NH; ++h) {
        if (t < HID) {
            b1g[t] = cgb1[(size_t)h * HID + t];
            b1m[t] = cmb1[(size_t)h * HID + t];
            w2g[t] = cgW2[(size_t)h * HID + t];
        }
        if (t < F) b2mS[t] = cmb2[(size_t)h * F + t];
        if (t < K) wpow[t] = powf(wn[t], cpw[h]);
        __syncthreads();

        {
            const int grp = t >> 7;
            const int up  = t & 127;
            const float* Wb = (grp == 0 ? cgW1 : cmW1) + (size_t)h * F * HID;
            const float2* W2p = (const float2*)Wb;
            float acc[K][2];
#pragma unroll
            for (int i = 0; i < K; ++i) { acc[i][0] = 0.f; acc[i][1] = 0.f; }
            for (int k = 0; k < F; ++k) {
                float2 wv = W2p[k * (HID / 2) + up];
#pragma unroll
                for (int i = 0; i < K; ++i) {
                    float xv = xs[i * F + k];
                    acc[i][0] += xv * wv.x;
                    acc[i][1] += xv * wv.y;
                }
            }
            if (grp == 0) {
#pragma unroll
                for (int i = 0; i < K; ++i) {
                    float h0 = lrelu(acc[i][0] + b1g[2 * up]);
                    float h1 = lrelu(acc[i][1] + b1g[2 * up + 1]);
                    float part = h0 * w2g[2 * up] + h1 * w2g[2 * up + 1];
#pragma unroll
                    for (int s = 32; s; s >>= 1) part += __shfl_xor(part, s);
                    if (lane == 0) gpart[i][wave & 1] = part;
                }
            } else {
#pragma unroll
                for (int i = 0; i < K; ++i) {
                    hmS[i][2 * up]     = lrelu(acc[i][0] + b1m[2 * up]);
                    hmS[i][2 * up + 1] = lrelu(acc[i][1] + b1m[2 * up + 1]);
                }
            }
        }
        __syncthreads();
        if (t < K) gate_s[t] = cgb2[h] + gpart[t][0] + gpart[t][1];

        {
            const float2* W232 = (const float2*)(cmW2 + (size_t)h * HID * F);
            if (t < K * (F / 2)) {
                int i  = t >> 5;
                int op = t & 31;
                float a0 = b2mS[2 * op], a1 = b2mS[2 * op + 1];
#pragma unroll 8
                for (int u = 0; u < HID; ++u) {
                    float2 wv = W232[u * (F / 2) + op];
                    float hv = hmS[i][u];
                    a0 += hv * wv.x;
                    a1 += hv * wv.y;
                }
                msgS[i][2 * op]     = a0;
                msgS[i][2 * op + 1] = a1;
            }
        }
        __syncthreads();

        if (t == 0) {
            float mx = -1e30f;
#pragma unroll
            for (int i = 0; i < K; ++i) mx = fmaxf(mx, gate_s[i]);
            float wv[K], s = 0.f;
#pragma unroll
            for (int i = 0; i < K; ++i) {
                wv[i] = wpow[i] * expf(gate_s[i] - mx);
                s += wv[i];
            }
            float inv = 1.f / (s + 1e-10f);
#pragma unroll
            for (int i = 0; i < K; ++i) anorm[i] = wv[i] * inv;
        }
        __syncthreads();

        if (t < F) {
            float s = 0.f;
#pragma unroll
            for (int i = 0; i < K; ++i) s += anorm[i] * msgS[i][t];
            outacc[t] += s * (1.f / 3.f);
        }
        __syncthreads();
    }

    if (t < F) out[(size_t)c * F + t] = outacc[t];
}

// ---------------------------------------------------------------------------
extern "C" void kernel_launch(void* const* d_in, const int* in_sizes, int n_in,
                              void* d_out, int out_size, void* d_ws, size_t ws_size,
                              hipStream_t stream)
{
    const float* wts  = (const float*)d_in[0];
    const float* fea  = (const float*)d_in[1];
    const float* embW = (const float*)d_in[6];
    const float* embB = (const float*)d_in[7];
    const float* gW1  = (const float*)d_in[8];
    const float* gb1  = (const float*)d_in[9];
    const float* gW2  = (const float*)d_in[10];
    const float* gb2  = (const float*)d_in[11];
    const float* mW1  = (const float*)d_in[12];
    const float* mb1  = (const float*)d_in[13];
    const float* mW2  = (const float*)d_in[14];
    const float* mb2  = (const float*)d_in[15];
    const float* gpw  = (const float*)d_in[16];
    const float* cgW1 = (const float*)d_in[17];
    const float* cgb1 = (const float*)d_in[18];
    const float* cgW2 = (const float*)d_in[19];
    const float* cgb2 = (const float*)d_in[20];
    const float* cmW1 = (const float*)d_in[21];
    const float* cmb1 = (const float*)d_in[22];
    const float* cmW2 = (const float*)d_in[23];
    const float* cmb2 = (const float*)d_in[24];
    const float* cpw  = (const float*)d_in[25];

    const int N = in_sizes[0];   // 50000
    const int C = N / K;         // 10000
    const int layer_blocks = (C + 11) / 12;   // 834 (tail block guarded)

    float* x = (float*)d_ws;                       // [N,F] fp32, 12.8 MB
    const size_t xbytes = (size_t)N * F * 4;
    const size_t need = xbytes + (size_t)WALL_ELEMS * 2;

    embed_kernel<<<(N + ENB - 1) / ENB, 256, 0, stream>>>(fea, embW, embB, wts, x, N);

    if (ws_size >= need) {
        // ---- fast path ----
        _Float16* Wall  = (_Float16*)((char*)d_ws + xbytes);
        _Float16* W1sw  = Wall;
        _Float16* W2sw  = Wall + W1SW_ELEMS;
        _Float16* cW1sw = Wall + W1SW_ELEMS + W2SW_ELEMS;
        _Float16* cW2sw = Wall + W1SW_ELEMS + W2SW_ELEMS + CW1_ELEMS;

        prep_all<<<(WALL_ELEMS + 255) / 256, 256, 0, stream>>>(
            gW1, mW1, mW2, cgW1, cmW1, cmW2, Wall);
        for (int l = 0; l < NL; ++l)
            layer_wave<<<layer_blocks, 256, 0, stream>>>(x, W1sw, W2sw,
                                                         gb1, gb2, mb1, mb2, gW2, gpw, wts,
                                                         l, l * NH, N);
        pool_wave<<<layer_blocks, 256, 0, stream>>>(x, cW1sw, cW2sw,
                                                    cgb1, cgb2, cmb1, cmb2, cgW2, cpw, wts,
                                                    (float*)d_out, C);
    } else {
        // ---- fallback: per-layer prep into d_out scratch ----
        _Float16* W1sw = (_Float16*)d_out;
        _Float16* W2sw = (_Float16*)((char*)d_out + 393216);
        for (int l = 0; l < NL; ++l) {
            prep_layer<<<(W1L_ELEMS + W2L_ELEMS) / 256, 256, 0, stream>>>(
                gW1, mW1, mW2, W1sw, W2sw, l);
            layer_wave<<<layer_blocks, 256, 0, stream>>>(x, W1sw, W2sw,
                                                         gb1, gb2, mb1, mb2, gW2, gpw, wts,
                                                         l, 0, N);
        }
        pool_kernel<<<C, 256, 0, stream>>>(x, cgW1, cgb1, cgW2, cgb2,
                                           cmW1, cmb1, cmW2, cmb2, cpw, wts,
                                           (float*)d_out);
    }
}

// Round 9
// 781.425 us; speedup vs baseline: 1.8061x; 1.0656x over previous
//
#include <hip/hip_runtime.h>
#include <hip/hip_bf16.h>

#define K 5
#define F 64
#define EMBD 200
#define HID 256
#define NH 3
#define NL 3
#define CB 8            // crystals per block for POOL kernels
#define NB (CB * K)     // 40 nodes per pool block

// layer kernel: 4 waves x 3 crystals = 12 crystals / block
#define CW 3            // crystals per wave
#define NWN (CW * K)    // 15 nodes per wave
#define EWE (CW * K * K) // 75 edges per wave
#define ET 5            // edge tiles of 16

typedef _Float16 half8 __attribute__((ext_vector_type(8)));
typedef _Float16 h2 __attribute__((ext_vector_type(2)));
typedef _Float16 h4 __attribute__((ext_vector_type(4)));
typedef __fp16 fp16x2 __attribute__((ext_vector_type(2)));
typedef float f32x4 __attribute__((ext_vector_type(4)));

__device__ __forceinline__ float lrelu(float v) { return v >= 0.f ? v : 0.01f * v; }

// cvt_pkrtz returns __fp16x2; bitcast to _Float16x2 (same bits, distinct clang types)
__device__ __forceinline__ h2 cvt_pk(float a, float b) {
    union { fp16x2 f; h2 h; } u;
    u.f = __builtin_amdgcn_cvt_pkrtz(a, b);
    return u.h;
}

__device__ __forceinline__ half8 lrelu8(half8 t) {
    half8 z = 0;
    half8 p = __builtin_elementwise_max(t, z);
    half8 n = __builtin_elementwise_min(t, z);
    return p + n * (_Float16)0.01f;
}

// ---- swizzled-weight element counts (fp16) ----
#define W1SW_ELEMS 589824    // 9 lh * 2 net * 2 half * 4 chunk * 4 nt * 2 ks * 64 * 8
#define W2SW_ELEMS 147456    // 9 lh * 8 ks2 * 4 nt * 64 * 8
#define CW1_ELEMS   98304    // 3 h * 2 net * 4 chunk * 4 nt * 2 ks * 64 * 8
#define CW2_ELEMS   49152    // 3 h * 8 ks2 * 4 nt * 64 * 8
#define WALL_ELEMS (W1SW_ELEMS + W2SW_ELEMS + CW1_ELEMS + CW2_ELEMS)  // 884736

// per-layer (fallback) sizes
#define W1L_ELEMS 196608
#define W2L_ELEMS 49152

// ---------------------------------------------------------------------------
// Fast path: swizzle ALL weights (layers + pool) fp32 -> fp16 B-frag order.
// ---------------------------------------------------------------------------
__global__ __launch_bounds__(256)
void prep_all(const float* __restrict__ gW1, const float* __restrict__ mW1,
              const float* __restrict__ mW2,
              const float* __restrict__ cgW1, const float* __restrict__ cmW1,
              const float* __restrict__ cmW2,
              _Float16* __restrict__ Wall)
{
    int tid = blockIdx.x * 256 + threadIdx.x;
    if (tid >= WALL_ELEMS) return;
    float v;
    if (tid < W1SW_ELEMS) {
        int j = tid & 7, lane = (tid >> 3) & 63;
        int r1 = tid >> 9;                       // [lh][net][half][chunk][nt][ks]
        int ks = r1 & 1, nt = (r1 >> 1) & 3, chunk = (r1 >> 3) & 3;
        int half = (r1 >> 5) & 1, net = (r1 >> 6) & 1, lh = r1 >> 7;   // 0..8
        int q = lane >> 4, n16 = lane & 15;
        const float* src = net ? mW1 : gW1;
        v = src[((size_t)lh * 128 + half * 64 + ks * 32 + q * 8 + j) * 256
                + chunk * 64 + nt * 16 + n16];
    } else if (tid < W1SW_ELEMS + W2SW_ELEMS) {
        int t2 = tid - W1SW_ELEMS;
        int j = t2 & 7, lane = (t2 >> 3) & 63;
        int r1 = t2 >> 9;                        // [lh][ks2][nt]
        int nt = r1 & 3, ks2 = (r1 >> 2) & 7, lh = r1 >> 5;            // 0..8
        int q = lane >> 4, n16 = lane & 15;
        v = mW2[((size_t)lh * 256 + ks2 * 32 + q * 8 + j) * 64 + nt * 16 + n16];
    } else if (tid < W1SW_ELEMS + W2SW_ELEMS + CW1_ELEMS) {
        int t2 = tid - (W1SW_ELEMS + W2SW_ELEMS);
        int j = t2 & 7, lane = (t2 >> 3) & 63;
        int r1 = t2 >> 9;                        // [h][net][chunk][nt][ks]
        int ks = r1 & 1, nt = (r1 >> 1) & 3, chunk = (r1 >> 3) & 3;
        int net = (r1 >> 5) & 1, h = r1 >> 6;                          // 0..2
        int q = lane >> 4, n16 = lane & 15;
        const float* src = net ? cmW1 : cgW1;
        v = src[((size_t)h * 64 + ks * 32 + q * 8 + j) * 256
                + chunk * 64 + nt * 16 + n16];
    } else {
        int t2 = tid - (W1SW_ELEMS + W2SW_ELEMS + CW1_ELEMS);
        int j = t2 & 7, lane = (t2 >> 3) & 63;
        int r1 = t2 >> 9;                        // [h][ks2][nt]
        int nt = r1 & 3, ks2 = (r1 >> 2) & 7, h = r1 >> 5;             // 0..2
        int q = lane >> 4, n16 = lane & 15;
        v = cmW2[((size_t)h * 256 + ks2 * 32 + q * 8 + j) * 64 + nt * 16 + n16];
    }
    Wall[tid] = (_Float16)v;
}

// ---------------------------------------------------------------------------
// Fallback: per-layer prep into d_out scratch (round-4 proven).
// ---------------------------------------------------------------------------
__global__ __launch_bounds__(256)
void prep_layer(const float* __restrict__ gW1, const float* __restrict__ mW1,
                const float* __restrict__ mW2,
                _Float16* __restrict__ W1sw, _Float16* __restrict__ W2sw, int l)
{
    int tid = blockIdx.x * 256 + threadIdx.x;
    if (tid < W1L_ELEMS) {
        int j = tid & 7, lane = (tid >> 3) & 63;
        int r1 = tid >> 9;
        int ks = r1 & 1, nt = (r1 >> 1) & 3, chunk = (r1 >> 3) & 3;
        int half = (r1 >> 5) & 1, net = (r1 >> 6) & 1, hh = r1 >> 7;
        int q = lane >> 4, n16 = lane & 15;
        const float* src = net ? mW1 : gW1;
        float v = src[((size_t)(l * NH + hh) * 128 + half * 64 + ks * 32 + q * 8 + j) * 256
                      + chunk * 64 + nt * 16 + n16];
        W1sw[tid] = (_Float16)v;
    } else {
        int t2 = tid - W1L_ELEMS;
        if (t2 < W2L_ELEMS) {
            int j = t2 & 7, lane = (t2 >> 3) & 63;
            int r1 = t2 >> 9;
            int nt = r1 & 3, ks2 = (r1 >> 2) & 7, hh = r1 >> 5;
            int q = lane >> 4, n16 = lane & 15;
            float v = mW2[((size_t)(l * NH + hh) * 256 + ks2 * 32 + q * 8 + j) * 64
                          + nt * 16 + n16];
            W2sw[t2] = (_Float16)v;
        }
    }
}

// ---------------------------------------------------------------------------
// Embedding — round-16: REVERTED to the round-0 original (1 node / 64-thread
// block). The round-9 LDS-tiled rewrite was chasing a cold-replay profiling
// artifact (20 ms row at 1.8 GB/s was impossible) and cost ~60 us of real
// time (non-layer budget 208 -> 268 us at constant layer time). This form
// does 4x fewer VMEM instrs/thread with 4x more waves — better latency
// hiding for the same totals.
// ---------------------------------------------------------------------------
__global__ __launch_bounds__(64)
void embed_kernel(const float* __restrict__ fea, const float* __restrict__ W,
                  const float* __restrict__ b, const float* __restrict__ wts,
                  float* __restrict__ x)
{
    int n = blockIdx.x;
    int o = threadIdx.x;
    __shared__ float fs[EMBD];
    for (int e = o; e < EMBD; e += 64) fs[e] = fea[n * EMBD + e];
    __syncthreads();
    if (o < F - 1) {
        float acc = b[o];
#pragma unroll 8
        for (int e = 0; e < EMBD; ++e) acc += fs[e] * W[e * (F - 1) + o];
        x[n * F + o] = acc;
    } else {
        x[n * F + F - 1] = wts[n];
    }
}

// ---------------------------------------------------------------------------
// One graph layer — barrier-free, 4 independent waves / block, each wave owns
// 3 crystals (15 nodes, 75 edges). GEMM2 B-frags hoisted. Wave LDS 12288 B.
// (256,2): round-10 proven — 2 blocks/CU, occupancy 18%, no spill.
// Round 12 proven: transposed stage-1 mfma + packed b64 PQ writes + fdot2 gate
// (186.7 us/layer). Round 13 (PQ dbuf + full c-unroll) REGRESSED to 370 us:
// register pressure blew the (256,2) cap and spilled accumulators to scratch.
// This structure is pinned at 2 waves/SIMD; do not restructure its schedule.
// ---------------------------------------------------------------------------
#define WAVE_LDS 12288   // bytes per wave slice

__global__ __launch_bounds__(256, 2)
void layer_wave(float* __restrict__ x,
                const _Float16* __restrict__ W1sw,
                const _Float16* __restrict__ W2sw,
                const float* __restrict__ gb1, const float* __restrict__ gb2v,
                const float* __restrict__ mb1, const float* __restrict__ mb2,
                const float* __restrict__ gW2, const float* __restrict__ gpw,
                const float* __restrict__ wts, int l, int lhw0, int Ntot)
{
    __shared__ __align__(16) char smem[4 * WAVE_LDS];

    const int t = threadIdx.x, w = t >> 6, lane = t & 63;
    const int q = lane >> 4, m16 = lane & 15;

    char* wb = smem + w * WAVE_LDS;
    _Float16 (*PQ)[16][72] = (_Float16 (*)[16][72])wb;   // [4][16][72] = 9216 B
    _Float16 (*msgL)[72]   = (_Float16 (*)[72])wb;       // [80][72] = 11520 B (aliases PQ)
    float* gateS  = (float*)(wb + 11520);                // [80]
    float* anormS = (float*)(wb + 11840);                // [80]
    float* wpowS  = (float*)(wb + 12160);                // [16]

    const int nw0 = (blockIdx.x * 12 + w * CW) * K;      // first node of this wave
    const int vn  = (Ntot - nw0 < NWN) ? (Ntot - nw0) : NWN;  // valid nodes (may be <=0)

    // ---- A-fragments of x (head/half-invariant), fp16, loaded once ----
    half8 A[2];
    {
        int arow = nw0 + m16;
        if (arow > Ntot - 1) arow = Ntot - 1;            // clamp pad rows (finite junk)
        if (arow < 0) arow = 0;
        const float* xr = x + (size_t)arow * F;
#pragma unroll
        for (int ks = 0; ks < 2; ++ks) {
            float4 f0 = *(const float4*)(xr + ks * 32 + q * 8);
            float4 f1 = *(const float4*)(xr + ks * 32 + q * 8 + 4);
            half8 a;
            a[0] = (_Float16)f0.x; a[1] = (_Float16)f0.y;
            a[2] = (_Float16)f0.z; a[3] = (_Float16)f0.w;
            a[4] = (_Float16)f1.x; a[5] = (_Float16)f1.y;
            a[6] = (_Float16)f1.z; a[7] = (_Float16)f1.w;
            A[ks] = a;
        }
    }

    // ---- per-lane edge -> local node rows (75 valid edges in 5 tiles of 16) ----
    int iR[ET], jR[ET];
#pragma unroll
    for (int et = 0; et < ET; ++et) {
        int e = et * 16 + m16;
        if (e < EWE) {
            int cl = e / 25, rm = e % 25;
            iR[et] = cl * K + rm / K;
            jR[et] = cl * K + rm % K;
        } else { iR[et] = 15; jR[et] = 15; }             // pad row (clamped x, finite)
    }

    float oacc[NWN];
#pragma unroll
    for (int n = 0; n < NWN; ++n) oacc[n] = 0.f;

    for (int h = 0; h < NH; ++h) {
        const int lh = l * NH + h, lhw = lhw0 + h;

        if (lane < NWN) {
            int wi = nw0 + lane;
            if (wi > Ntot - 1) wi = Ntot - 1;
            if (wi < 0) wi = 0;
            wpowS[lane] = powf(wts[wi], gpw[lh]);
        }
        if (lane >= NWN && lane < NWN + 5) anormS[EWE + (lane - NWN)] = 0.f;  // pad slots 75..79

        f32x4 acc2[ET][4];
#pragma unroll
        for (int et = 0; et < ET; ++et)
#pragma unroll
            for (int nt = 0; nt < 4; ++nt) acc2[et][nt] = (f32x4){0.f, 0.f, 0.f, 0.f};
        float gacc[ET] = {0.f, 0.f, 0.f, 0.f, 0.f};

        for (int c = 0; c < 4; ++c) {
            // ---- GEMM2 B-frags for this chunk: issue early, reuse for 5 et ----
            half8 B2[8];
            {
                const _Float16* W2b = W2sw + ((size_t)lhw * 8 + c * 2) * 2048;
#pragma unroll
                for (int f = 0; f < 8; ++f)
                    B2[f] = *(const half8*)(W2b + ((size_t)f * 64 + lane) * 8);
            }

            // ---- stage-1: all 4 net-halves, TRANSPOSED mfma -> packed writes ----
#pragma unroll
            for (int hf = 0; hf < 4; ++hf) {
                f32x4 accS[4];
#pragma unroll
                for (int nt = 0; nt < 4; ++nt) accS[nt] = (f32x4){0.f, 0.f, 0.f, 0.f};
                const _Float16* Wb = W1sw + ((size_t)lhw * 4 + hf) * 16384 + c * 4096;
#pragma unroll
                for (int nt = 0; nt < 4; ++nt)
#pragma unroll
                    for (int ks = 0; ks < 2; ++ks) {
                        half8 B = *(const half8*)(Wb + ((nt * 2 + ks) * 64 + lane) * 8);
                        // swapped operands: D[hid][node]
                        accS[nt] = __builtin_amdgcn_mfma_f32_16x16x32_f16(
                            B, A[ks], accS[nt], 0, 0, 0);
                    }
                // lane holds hid = nt*16 + q*4 + rg for node = m16 -> one b64/nt
#pragma unroll
                for (int nt = 0; nt < 4; ++nt) {
                    h2 lo = cvt_pk(accS[nt][0], accS[nt][1]);
                    h2 hi = cvt_pk(accS[nt][2], accS[nt][3]);
                    h4 pk = __builtin_shufflevector(lo, hi, 0, 1, 2, 3);
                    *(h4*)&PQ[hf][m16][nt * 16 + q * 4] = pk;
                }
            }

            // ---- per-chunk bias slices (global, L1-hot); wg packed to f16 ----
            half8 bg8[2], bm8[2];
            h2 wgh2[2][4];
#pragma unroll
            for (int ks = 0; ks < 2; ++ks) {
                const int ub = c * 64 + ks * 32 + q * 8;
                float4 g0 = *(const float4*)(gb1 + (size_t)lh * HID + ub);
                float4 g1 = *(const float4*)(gb1 + (size_t)lh * HID + ub + 4);
                float4 m0 = *(const float4*)(mb1 + (size_t)lh * HID + ub);
                float4 m1 = *(const float4*)(mb1 + (size_t)lh * HID + ub + 4);
                float4 w0 = *(const float4*)(gW2 + (size_t)lh * HID + ub);
                float4 w1 = *(const float4*)(gW2 + (size_t)lh * HID + ub + 4);
                half8 bg, bm;
                bg[0]=(_Float16)g0.x; bg[1]=(_Float16)g0.y; bg[2]=(_Float16)g0.z; bg[3]=(_Float16)g0.w;
                bg[4]=(_Float16)g1.x; bg[5]=(_Float16)g1.y; bg[6]=(_Float16)g1.z; bg[7]=(_Float16)g1.w;
                bm[0]=(_Float16)m0.x; bm[1]=(_Float16)m0.y; bm[2]=(_Float16)m0.z; bm[3]=(_Float16)m0.w;
                bm[4]=(_Float16)m1.x; bm[5]=(_Float16)m1.y; bm[6]=(_Float16)m1.z; bm[7]=(_Float16)m1.w;
                bg8[ks] = bg; bm8[ks] = bm;
                wgh2[ks][0] = cvt_pk(w0.x, w0.y);
                wgh2[ks][1] = cvt_pk(w0.z, w0.w);
                wgh2[ks][2] = cvt_pk(w1.x, w1.y);
                wgh2[ks][3] = cvt_pk(w1.z, w1.w);
            }

            // ---- consume: gate fdot2 + hm A-frags + GEMM2 (B2 reused) ----
#pragma unroll
            for (int et = 0; et < ET; ++et) {
                half8 af[2];
#pragma unroll
                for (int ks = 0; ks < 2; ++ks) {
                    const int ub = ks * 32 + q * 8;
                    half8 pg = *(const half8*)&PQ[0][iR[et]][ub];
                    half8 qg = *(const half8*)&PQ[1][jR[et]][ub];
                    half8 pm = *(const half8*)&PQ[2][iR[et]][ub];
                    half8 qm = *(const half8*)&PQ[3][jR[et]][ub];
                    half8 tg = lrelu8(pg + qg + bg8[ks]);
                    h2 t01 = __builtin_shufflevector(tg, tg, 0, 1);
                    h2 t23 = __builtin_shufflevector(tg, tg, 2, 3);
                    h2 t45 = __builtin_shufflevector(tg, tg, 4, 5);
                    h2 t67 = __builtin_shufflevector(tg, tg, 6, 7);
                    gacc[et] = __builtin_amdgcn_fdot2(t01, wgh2[ks][0], gacc[et], false);
                    gacc[et] = __builtin_amdgcn_fdot2(t23, wgh2[ks][1], gacc[et], false);
                    gacc[et] = __builtin_amdgcn_fdot2(t45, wgh2[ks][2], gacc[et], false);
                    gacc[et] = __builtin_amdgcn_fdot2(t67, wgh2[ks][3], gacc[et], false);
                    af[ks] = lrelu8(pm + qm + bm8[ks]);
                }
#pragma unroll
                for (int nt = 0; nt < 4; ++nt)
#pragma unroll
                    for (int ks = 0; ks < 2; ++ks)
                        acc2[et][nt] = __builtin_amdgcn_mfma_f32_16x16x32_f16(
                            af[ks], B2[ks * 4 + nt], acc2[et][nt], 0, 0, 0);
            }
        }

        // ---- gate reduce across quads (k-slices) ----
        const float gb2s = gb2v[lh];
#pragma unroll
        for (int et = 0; et < ET; ++et) {
            float g = gacc[et];
            g += __shfl_xor(g, 16);
            g += __shfl_xor(g, 32);
            if (q == 0) gateS[et * 16 + m16] = g + gb2s;
        }

        // ---- segment softmax: lane n (0..14) handles local node n (5 edges) ----
        if (lane < NWN) {
            const int cl5 = (lane / K) * K;
            float gg[K], mx = -1e30f;
#pragma unroll
            for (int jj = 0; jj < K; ++jj) {
                gg[jj] = gateS[lane * K + jj];
                mx = fmaxf(mx, gg[jj]);
            }
            float s = 0.f, wv[K];
#pragma unroll
            for (int jj = 0; jj < K; ++jj) {
                wv[jj] = wpowS[cl5 + jj] * expf(gg[jj] - mx);
                s += wv[jj];
            }
            float inv = 1.f / (s + 1e-10f) * (1.f / 3.f);  // fold head mean
#pragma unroll
            for (int jj = 0; jj < K; ++jj) anormS[lane * K + jj] = wv[jj] * inv;
        }

        // ---- weighted msg -> msgL (PQ region dead) ----
        float b2v[4];
#pragma unroll
        for (int nt = 0; nt < 4; ++nt) b2v[nt] = mb2[(size_t)lh * F + nt * 16 + m16];
#pragma unroll
        for (int et = 0; et < ET; ++et) {
            f32x4 an = *(const f32x4*)&anormS[et * 16 + q * 4];
#pragma unroll
            for (int nt = 0; nt < 4; ++nt)
#pragma unroll
                for (int rg = 0; rg < 4; ++rg) {
                    float v = (acc2[et][nt][rg] + b2v[nt]) * an[rg];
                    msgL[et * 16 + q * 4 + rg][nt * 16 + m16] = (_Float16)v;
                }
        }

        // ---- aggregate: lane = output col, 15 nodes x 5 edges ----
#pragma unroll
        for (int n = 0; n < NWN; ++n) {
            float s = 0.f;
#pragma unroll
            for (int jj = 0; jj < K; ++jj) s += (float)msgL[n * K + jj][lane];
            oacc[n] += s;
        }
    }

    // ---- residual + write back (own valid rows only) ----
#pragma unroll
    for (int n = 0; n < NWN; ++n) {
        if (n < vn) {
            size_t idx = (size_t)(nw0 + n) * F + lane;
            x[idx] = oacc[n] + x[idx];
        }
    }
}

// ---------------------------------------------------------------------------
// Round 15 proven: pool_wave — pool in the layer_wave structure. Barrier-free,
// 4 independent waves/block, wave owns 3 crystals. Transposed stage-1 (2 nets),
// fdot2 gate, single node-tile consume, softmax, aggregate, store.
// ---------------------------------------------------------------------------
#define PWAVE_LDS 4800

__global__ __launch_bounds__(256, 2)
void pool_wave(const float* __restrict__ x,
               const _Float16* __restrict__ cW1sw,
               const _Float16* __restrict__ cW2sw,
               const float* __restrict__ cgb1, const float* __restrict__ cgb2v,
               const float* __restrict__ cmb1, const float* __restrict__ cmb2,
               const float* __restrict__ cgW2, const float* __restrict__ cpw,
               const float* __restrict__ wts, float* __restrict__ out, int Ctot)
{
    __shared__ __align__(16) char smem[4 * PWAVE_LDS];

    const int t = threadIdx.x, w = t >> 6, lane = t & 63;
    const int q = lane >> 4, m16 = lane & 15;

    char* wb = smem + w * PWAVE_LDS;
    _Float16 (*PQ)[16][72] = (_Float16 (*)[16][72])wb;   // [2][16][72] = 4608 B
    _Float16 (*msgL)[72]   = (_Float16 (*)[72])wb;       // [16][72] (aliases PQ)
    float* gateS  = (float*)(wb + 4608);                 // [16]
    float* anormS = (float*)(wb + 4672);                 // [16]
    float* wpowS  = (float*)(wb + 4736);                 // [16]

    const int c0  = blockIdx.x * 12 + w * CW;            // first crystal of wave
    const int nw0 = c0 * K;
    const int Ntot = Ctot * K;
    const int vc  = (Ctot - c0 < CW) ? (Ctot - c0) : CW; // valid crystals (may be <=0)

    // ---- A-fragments of x rows (same as layer_wave) ----
    half8 A[2];
    {
        int arow = nw0 + m16;
        if (arow > Ntot - 1) arow = Ntot - 1;
        if (arow < 0) arow = 0;
        const float* xr = x + (size_t)arow * F;
#pragma unroll
        for (int ks = 0; ks < 2; ++ks) {
            float4 f0 = *(const float4*)(xr + ks * 32 + q * 8);
            float4 f1 = *(const float4*)(xr + ks * 32 + q * 8 + 4);
            half8 a;
            a[0] = (_Float16)f0.x; a[1] = (_Float16)f0.y;
            a[2] = (_Float16)f0.z; a[3] = (_Float16)f0.w;
            a[4] = (_Float16)f1.x; a[5] = (_Float16)f1.y;
            a[6] = (_Float16)f1.z; a[7] = (_Float16)f1.w;
            A[ks] = a;
        }
    }

    float oacc[CW] = {0.f, 0.f, 0.f};   // per-lane output col, per crystal

    for (int h = 0; h < NH; ++h) {
        if (lane < NWN) {
            int wi = nw0 + lane;
            if (wi > Ntot - 1) wi = Ntot - 1;
            if (wi < 0) wi = 0;
            wpowS[lane] = powf(wts[wi], cpw[h]);
        }
        if (lane == NWN) anormS[15] = 0.f;               // pad node row

        f32x4 acc2[4];
#pragma unroll
        for (int nt = 0; nt < 4; ++nt) acc2[nt] = (f32x4){0.f, 0.f, 0.f, 0.f};
        float gacc = 0.f;

        for (int c = 0; c < 4; ++c) {
            // ---- GEMM2 B-frags (pool_mfma's indexing) ----
            half8 B2[8];
            {
                const _Float16* W2b = cW2sw + (size_t)h * 16384 + c * 4096;
#pragma unroll
                for (int f = 0; f < 8; ++f)
                    B2[f] = *(const half8*)(W2b + ((size_t)f * 64 + lane) * 8);
            }

            // ---- stage-1: 2 nets (0=gate, 1=msg), transposed mfma ----
#pragma unroll
            for (int net = 0; net < 2; ++net) {
                f32x4 accS[4];
#pragma unroll
                for (int nt = 0; nt < 4; ++nt) accS[nt] = (f32x4){0.f, 0.f, 0.f, 0.f};
                const _Float16* Wb = cW1sw + ((size_t)(h * 2 + net) * 4 + c) * 4096;
#pragma unroll
                for (int nt = 0; nt < 4; ++nt)
#pragma unroll
                    for (int ks = 0; ks < 2; ++ks) {
                        half8 B = *(const half8*)(Wb + ((nt * 2 + ks) * 64 + lane) * 8);
                        accS[nt] = __builtin_amdgcn_mfma_f32_16x16x32_f16(
                            B, A[ks], accS[nt], 0, 0, 0);
                    }
#pragma unroll
                for (int nt = 0; nt < 4; ++nt) {
                    h2 lo = cvt_pk(accS[nt][0], accS[nt][1]);
                    h2 hi = cvt_pk(accS[nt][2], accS[nt][3]);
                    h4 pk = __builtin_shufflevector(lo, hi, 0, 1, 2, 3);
                    *(h4*)&PQ[net][m16][nt * 16 + q * 4] = pk;
                }
            }

            // ---- per-chunk bias slices; gate W2 packed to f16 ----
            half8 bg8[2], bm8[2];
            h2 wgh2[2][4];
#pragma unroll
            for (int ks = 0; ks < 2; ++ks) {
                const int ub = c * 64 + ks * 32 + q * 8;
                float4 g0 = *(const float4*)(cgb1 + (size_t)h * HID + ub);
                float4 g1 = *(const float4*)(cgb1 + (size_t)h * HID + ub + 4);
                float4 m0 = *(const float4*)(cmb1 + (size_t)h * HID + ub);
                float4 m1 = *(const float4*)(cmb1 + (size_t)h * HID + ub + 4);
                float4 w0 = *(const float4*)(cgW2 + (size_t)h * HID + ub);
                float4 w1 = *(const float4*)(cgW2 + (size_t)h * HID + ub + 4);
                half8 bg, bm;
                bg[0]=(_Float16)g0.x; bg[1]=(_Float16)g0.y; bg[2]=(_Float16)g0.z; bg[3]=(_Float16)g0.w;
                bg[4]=(_Float16)g1.x; bg[5]=(_Float16)g1.y; bg[6]=(_Float16)g1.z; bg[7]=(_Float16)g1.w;
                bm[0]=(_Float16)m0.x; bm[1]=(_Float16)m0.y; bm[2]=(_Float16)m0.z; bm[3]=(_Float16)m0.w;
                bm[4]=(_Float16)m1.x; bm[5]=(_Float16)m1.y; bm[6]=(_Float16)m1.z; bm[7]=(_Float16)m1.w;
                bg8[ks] = bg; bm8[ks] = bm;
                wgh2[ks][0] = cvt_pk(w0.x, w0.y);
                wgh2[ks][1] = cvt_pk(w0.z, w0.w);
                wgh2[ks][2] = cvt_pk(w1.x, w1.y);
                wgh2[ks][3] = cvt_pk(w1.z, w1.w);
            }

            // ---- consume: single node tile (rows = m16, no gather) ----
            {
                half8 af[2];
#pragma unroll
                for (int ks = 0; ks < 2; ++ks) {
                    const int ub = ks * 32 + q * 8;
                    half8 pg = *(const half8*)&PQ[0][m16][ub];
                    half8 pm = *(const half8*)&PQ[1][m16][ub];
                    half8 tg = lrelu8(pg + bg8[ks]);
                    h2 t01 = __builtin_shufflevector(tg, tg, 0, 1);
                    h2 t23 = __builtin_shufflevector(tg, tg, 2, 3);
                    h2 t45 = __builtin_shufflevector(tg, tg, 4, 5);
                    h2 t67 = __builtin_shufflevector(tg, tg, 6, 7);
                    gacc = __builtin_amdgcn_fdot2(t01, wgh2[ks][0], gacc, false);
                    gacc = __builtin_amdgcn_fdot2(t23, wgh2[ks][1], gacc, false);
                    gacc = __builtin_amdgcn_fdot2(t45, wgh2[ks][2], gacc, false);
                    gacc = __builtin_amdgcn_fdot2(t67, wgh2[ks][3], gacc, false);
                    af[ks] = lrelu8(pm + bm8[ks]);
                }
#pragma unroll
                for (int nt = 0; nt < 4; ++nt)
#pragma unroll
                    for (int ks = 0; ks < 2; ++ks)
                        acc2[nt] = __builtin_amdgcn_mfma_f32_16x16x32_f16(
                            af[ks], B2[ks * 4 + nt], acc2[nt], 0, 0, 0);
            }
        }

        // ---- gate reduce across quads ----
        const float gb2s = cgb2v[h];
        {
            float g = gacc;
            g += __shfl_xor(g, 16);
            g += __shfl_xor(g, 32);
            if (q == 0) gateS[m16] = g + gb2s;
        }

        // ---- segment softmax: lane cl (0..2) handles crystal cl (5 nodes) ----
        if (lane < CW) {
            const int n0 = lane * K;
            float gg[K], mx = -1e30f;
#pragma unroll
            for (int jj = 0; jj < K; ++jj) {
                gg[jj] = gateS[n0 + jj];
                mx = fmaxf(mx, gg[jj]);
            }
            float s = 0.f, wv[K];
#pragma unroll
            for (int jj = 0; jj < K; ++jj) {
                wv[jj] = wpowS[n0 + jj] * expf(gg[jj] - mx);
                s += wv[jj];
            }
            float inv = 1.f / (s + 1e-10f) * (1.f / 3.f);  // fold head mean
#pragma unroll
            for (int jj = 0; jj < K; ++jj) anormS[n0 + jj] = wv[jj] * inv;
        }

        // ---- weighted msg -> msgL (PQ region dead after consume) ----
        float b2v[4];
#pragma unroll
        for (int nt = 0; nt < 4; ++nt) b2v[nt] = cmb2[(size_t)h * F + nt * 16 + m16];
#pragma unroll
        for (int nt = 0; nt < 4; ++nt)
#pragma unroll
            for (int rg = 0; rg < 4; ++rg) {
                int row = q * 4 + rg;
                float v = (acc2[nt][rg] + b2v[nt]) * anormS[row];
                msgL[row][nt * 16 + m16] = (_Float16)v;
            }

        // ---- aggregate: lane = output col, 3 crystals x 5 nodes ----
#pragma unroll
        for (int cl = 0; cl < CW; ++cl) {
            float s = 0.f;
#pragma unroll
            for (int jj = 0; jj < K; ++jj) s += (float)msgL[cl * K + jj][lane];
            oacc[cl] += s;
        }
    }

    // ---- store (valid crystals only) ----
#pragma unroll
    for (int cl = 0; cl < CW; ++cl)
        if (cl < vc)
            out[(size_t)(c0 + cl) * F + lane] = oacc[cl];
}

// ---------------------------------------------------------------------------
// Fallback fp32 pool (round-4 proven)
// ---------------------------------------------------------------------------
__global__ __launch_bounds__(256)
void pool_kernel(const float* __restrict__ x,
                 const float* __restrict__ cgW1, const float* __restrict__ cgb1,
                 const float* __restrict__ cgW2, const float* __restrict__ cgb2,
                 const float* __restrict__ cmW1, const float* __restrict__ cmb1,
                 const float* __restrict__ cmW2, const float* __restrict__ cmb2,
                 const float* __restrict__ cpw, const float* __restrict__ wts,
                 float* __restrict__ out)
{
    __shared__ float xs[K * F];
    __shared__ float hmS[K][HID];
    __shared__ float msgS[K][F];
    __shared__ float outacc[F];
    __shared__ float b1g[HID], b1m[HID], w2g[HID];
    __shared__ float b2mS[F];
    __shared__ float gpart[K][2];
    __shared__ float gate_s[K];
    __shared__ float anorm[K];
    __shared__ float wn[K], wpow[K];

    const int c = blockIdx.x;
    const int t = threadIdx.x;
    const int wave = t >> 6, lane = t & 63;

    for (int d = t; d < K * F; d += 256) xs[d] = x[c * K * F + d];
    if (t < F) outacc[t] = 0.f;
    if (t < K) wn[t] = wts[c * K + t];
    __syncthreads();

    for (int h = 0; h < NH; ++h) {
        if (t < HID) {
            b1g[t] = cgb1[(size_t)h * HID + t];
            b1m[t] = cmb1[(size_t)h * HID + t];
            w2g[t] = cgW2[(size_t)h * HID + t];
        }
        if (t < F) b2mS[t] = cmb2[(size_t)h * F + t];
        if (t < K) wpow[t] = powf(wn[t], cpw[h]);
        __syncthreads();

        {
            const int grp = t >> 7;
            const int up  = t & 127;
            const float* Wb = (grp == 0 ? cgW1 : cmW1) + (size_t)h * F * HID;
            const float2* W2p = (const float2*)Wb;
            float acc[K][2];
#pragma unroll
            for (int i = 0; i < K; ++i) { acc[i][0] = 0.f; acc[i][1] = 0.f; }
            for (int k = 0; k < F; ++k) {
                float2 wv = W2p[k * (HID / 2) + up];
#pragma unroll
                for (int i = 0; i < K; ++i) {
                    float xv = xs[i * F + k];
                    acc[i][0] += xv * wv.x;
                    acc[i][1] += xv * wv.y;
                }
            }
            if (grp == 0) {
#pragma unroll
                for (int i = 0; i < K; ++i) {
                    float h0 = lrelu(acc[i][0] + b1g[2 * up]);
                    float h1 = lrelu(acc[i][1] + b1g[2 * up + 1]);
                    float part = h0 * w2g[2 * up] + h1 * w2g[2 * up + 1];
#pragma unroll
                    for (int s = 32; s; s >>= 1) part += __shfl_xor(part, s);
                    if (lane == 0) gpart[i][wave & 1] = part;
                }
            } else {
#pragma unroll
                for (int i = 0; i < K; ++i) {
                    hmS[i][2 * up]     = lrelu(acc[i][0] + b1m[2 * up]);
                    hmS[i][2 * up + 1] = lrelu(acc[i][1] + b1m[2 * up + 1]);
                }
            }
        }
        __syncthreads();
        if (t < K) gate_s[t] = cgb2[h] + gpart[t][0] + gpart[t][1];

        {
            const float2* W232 = (const float2*)(cmW2 + (size_t)h * HID * F);
            if (t < K * (F / 2)) {
                int i  = t >> 5;
                int op = t & 31;
                float a0 = b2mS[2 * op], a1 = b2mS[2 * op + 1];
#pragma unroll 8
                for (int u = 0; u < HID; ++u) {
                    float2 wv = W232[u * (F / 2) + op];
                    float hv = hmS[i][u];
                    a0 += hv * wv.x;
                    a1 += hv * wv.y;
                }
                msgS[i][2 * op]     = a0;
                msgS[i][2 * op + 1] = a1;
            }
        }
        __syncthreads();

        if (t == 0) {
            float mx = -1e30f;
#pragma unroll
            for (int i = 0; i < K; ++i) mx = fmaxf(mx, gate_s[i]);
            float wv[K], s = 0.f;
#pragma unroll
            for (int i = 0; i < K; ++i) {
                wv[i] = wpow[i] * expf(gate_s[i] - mx);
                s += wv[i];
            }
            float inv = 1.f / (s + 1e-10f);
#pragma unroll
            for (int i = 0; i < K; ++i) anorm[i] = wv[i] * inv;
        }
        __syncthreads();

        if (t < F) {
            float s = 0.f;
#pragma unroll
            for (int i = 0; i < K; ++i) s += anorm[i] * msgS[i][t];
            outacc[t] += s * (1.f / 3.f);
        }
        __syncthreads();
    }

    if (t < F) out[(size_t)c * F + t] = outacc[t];
}

// ---------------------------------------------------------------------------
extern "C" void kernel_launch(void* const* d_in, const int* in_sizes, int n_in,
                              void* d_out, int out_size, void* d_ws, size_t ws_size,
                              hipStream_t stream)
{
    const float* wts  = (const float*)d_in[0];
    const float* fea  = (const float*)d_in[1];
    const float* embW = (const float*)d_in[6];
    const float* embB = (const float*)d_in[7];
    const float* gW1  = (const float*)d_in[8];
    const float* gb1  = (const float*)d_in[9];
    const float* gW2  = (const float*)d_in[10];
    const float* gb2  = (const float*)d_in[11];
    const float* mW1  = (const float*)d_in[12];
    const float* mb1  = (const float*)d_in[13];
    const float* mW2  = (const float*)d_in[14];
    const float* mb2  = (const float*)d_in[15];
    const float* gpw  = (const float*)d_in[16];
    const float* cgW1 = (const float*)d_in[17];
    const float* cgb1 = (const float*)d_in[18];
    const float* cgW2 = (const float*)d_in[19];
    const float* cgb2 = (const float*)d_in[20];
    const float* cmW1 = (const float*)d_in[21];
    const float* cmb1 = (const float*)d_in[22];
    const float* cmW2 = (const float*)d_in[23];
    const float* cmb2 = (const float*)d_in[24];
    const float* cpw  = (const float*)d_in[25];

    const int N = in_sizes[0];   // 50000
    const int C = N / K;         // 10000
    const int layer_blocks = (C + 11) / 12;   // 834 (tail block guarded)

    float* x = (float*)d_ws;                       // [N,F] fp32, 12.8 MB
    const size_t xbytes = (size_t)N * F * 4;
    const size_t need = xbytes + (size_t)WALL_ELEMS * 2;

    embed_kernel<<<N, 64, 0, stream>>>(fea, embW, embB, wts, x);

    if (ws_size >= need) {
        // ---- fast path ----
        _Float16* Wall  = (_Float16*)((char*)d_ws + xbytes);
        _Float16* W1sw  = Wall;
        _Float16* W2sw  = Wall + W1SW_ELEMS;
        _Float16* cW1sw = Wall + W1SW_ELEMS + W2SW_ELEMS;
        _Float16* cW2sw = Wall + W1SW_ELEMS + W2SW_ELEMS + CW1_ELEMS;

        prep_all<<<(WALL_ELEMS + 255) / 256, 256, 0, stream>>>(
            gW1, mW1, mW2, cgW1, cmW1, cmW2, Wall);
        for (int l = 0; l < NL; ++l)
            layer_wave<<<layer_blocks, 256, 0, stream>>>(x, W1sw, W2sw,
                                                         gb1, gb2, mb1, mb2, gW2, gpw, wts,
                                                         l, l * NH, N);
        pool_wave<<<layer_blocks, 256, 0, stream>>>(x, cW1sw, cW2sw,
                                                    cgb1, cgb2, cmb1, cmb2, cgW2, cpw, wts,
                                                    (float*)d_out, C);
    } else {
        // ---- fallback: per-layer prep into d_out scratch ----
        _Float16* W1sw = (_Float16*)d_out;
        _Float16* W2sw = (_Float16*)((char*)d_out + 393216);
        for (int l = 0; l < NL; ++l) {
            prep_layer<<<(W1L_ELEMS + W2L_ELEMS) / 256, 256, 0, stream>>>(
                gW1, mW1, mW2, W1sw, W2sw, l);
            layer_wave<<<layer_blocks, 256, 0, stream>>>(x, W1sw, W2sw,
                                                         gb1, gb2, mb1, mb2, gW2, gpw, wts,
                                                         l, 0, N);
        }
        pool_kernel<<<C, 256, 0, stream>>>(x, cgW1, cgb1, cgW2, cgb2,
                                           cmW1, cmb1, cmW2, cmb2, cpw, wts,
                                           (float*)d_out);
    }
}

// Round 10
// 723.097 us; speedup vs baseline: 1.9518x; 1.0807x over previous
//
#include <hip/hip_runtime.h>
#include <hip/hip_bf16.h>

#define K 5
#define F 64
#define EMBD 200
#define HID 256
#define NH 3
#define NL 3

// wave decomposition: 4 waves x 3 crystals = 12 crystals / block
#define CW 3            // crystals per wave
#define NWN (CW * K)    // 15 nodes per wave
#define EWE (CW * K * K) // 75 edges per wave
#define ET 5            // edge tiles of 16

typedef _Float16 half8 __attribute__((ext_vector_type(8)));
typedef _Float16 h2 __attribute__((ext_vector_type(2)));
typedef _Float16 h4 __attribute__((ext_vector_type(4)));
typedef __fp16 fp16x2 __attribute__((ext_vector_type(2)));
typedef float f32x4 __attribute__((ext_vector_type(4)));

__device__ __forceinline__ float lrelu(float v) { return v >= 0.f ? v : 0.01f * v; }

// cvt_pkrtz returns __fp16x2; bitcast to _Float16x2 (same bits, distinct clang types)
__device__ __forceinline__ h2 cvt_pk(float a, float b) {
    union { fp16x2 f; h2 h; } u;
    u.f = __builtin_amdgcn_cvt_pkrtz(a, b);
    return u.h;
}

__device__ __forceinline__ half8 lrelu8(half8 t) {
    half8 z = 0;
    half8 p = __builtin_elementwise_max(t, z);
    half8 n = __builtin_elementwise_min(t, z);
    return p + n * (_Float16)0.01f;
}

// ---- swizzled-weight element counts (fp16) ----
#define W1SW_ELEMS 589824    // 9 lh * 2 net * 2 half * 4 chunk * 4 nt * 2 ks * 64 * 8
#define W2SW_ELEMS 147456    // 9 lh * 8 ks2 * 4 nt * 64 * 8
#define CW1_ELEMS   98304    // 3 h * 2 net * 4 chunk * 4 nt * 2 ks * 64 * 8
#define CW2_ELEMS   49152    // 3 h * 8 ks2 * 4 nt * 64 * 8
#define WALL_ELEMS (W1SW_ELEMS + W2SW_ELEMS + CW1_ELEMS + CW2_ELEMS)  // 884736

// per-layer (fallback) sizes
#define W1L_ELEMS 196608
#define W2L_ELEMS 49152

// ---------------------------------------------------------------------------
// Fast path: swizzle ALL weights (layers + pool) fp32 -> fp16 B-frag order.
// ---------------------------------------------------------------------------
__global__ __launch_bounds__(256)
void prep_all(const float* __restrict__ gW1, const float* __restrict__ mW1,
              const float* __restrict__ mW2,
              const float* __restrict__ cgW1, const float* __restrict__ cmW1,
              const float* __restrict__ cmW2,
              _Float16* __restrict__ Wall)
{
    int tid = blockIdx.x * 256 + threadIdx.x;
    if (tid >= WALL_ELEMS) return;
    float v;
    if (tid < W1SW_ELEMS) {
        int j = tid & 7, lane = (tid >> 3) & 63;
        int r1 = tid >> 9;                       // [lh][net][half][chunk][nt][ks]
        int ks = r1 & 1, nt = (r1 >> 1) & 3, chunk = (r1 >> 3) & 3;
        int half = (r1 >> 5) & 1, net = (r1 >> 6) & 1, lh = r1 >> 7;   // 0..8
        int q = lane >> 4, n16 = lane & 15;
        const float* src = net ? mW1 : gW1;
        v = src[((size_t)lh * 128 + half * 64 + ks * 32 + q * 8 + j) * 256
                + chunk * 64 + nt * 16 + n16];
    } else if (tid < W1SW_ELEMS + W2SW_ELEMS) {
        int t2 = tid - W1SW_ELEMS;
        int j = t2 & 7, lane = (t2 >> 3) & 63;
        int r1 = t2 >> 9;                        // [lh][ks2][nt]
        int nt = r1 & 3, ks2 = (r1 >> 2) & 7, lh = r1 >> 5;            // 0..8
        int q = lane >> 4, n16 = lane & 15;
        v = mW2[((size_t)lh * 256 + ks2 * 32 + q * 8 + j) * 64 + nt * 16 + n16];
    } else if (tid < W1SW_ELEMS + W2SW_ELEMS + CW1_ELEMS) {
        int t2 = tid - (W1SW_ELEMS + W2SW_ELEMS);
        int j = t2 & 7, lane = (t2 >> 3) & 63;
        int r1 = t2 >> 9;                        // [h][net][chunk][nt][ks]
        int ks = r1 & 1, nt = (r1 >> 1) & 3, chunk = (r1 >> 3) & 3;
        int net = (r1 >> 5) & 1, h = r1 >> 6;                          // 0..2
        int q = lane >> 4, n16 = lane & 15;
        const float* src = net ? cmW1 : cgW1;
        v = src[((size_t)h * 64 + ks * 32 + q * 8 + j) * 256
                + chunk * 64 + nt * 16 + n16];
    } else {
        int t2 = tid - (W1SW_ELEMS + W2SW_ELEMS + CW1_ELEMS);
        int j = t2 & 7, lane = (t2 >> 3) & 63;
        int r1 = t2 >> 9;                        // [h][ks2][nt]
        int nt = r1 & 3, ks2 = (r1 >> 2) & 7, h = r1 >> 5;             // 0..2
        int q = lane >> 4, n16 = lane & 15;
        v = cmW2[((size_t)h * 256 + ks2 * 32 + q * 8 + j) * 64 + nt * 16 + n16];
    }
    Wall[tid] = (_Float16)v;
}

// ---------------------------------------------------------------------------
// Fallback: per-layer prep into d_out scratch (round-4 proven).
// ---------------------------------------------------------------------------
__global__ __launch_bounds__(256)
void prep_layer(const float* __restrict__ gW1, const float* __restrict__ mW1,
                const float* __restrict__ mW2,
                _Float16* __restrict__ W1sw, _Float16* __restrict__ W2sw, int l)
{
    int tid = blockIdx.x * 256 + threadIdx.x;
    if (tid < W1L_ELEMS) {
        int j = tid & 7, lane = (tid >> 3) & 63;
        int r1 = tid >> 9;
        int ks = r1 & 1, nt = (r1 >> 1) & 3, chunk = (r1 >> 3) & 3;
        int half = (r1 >> 5) & 1, net = (r1 >> 6) & 1, hh = r1 >> 7;
        int q = lane >> 4, n16 = lane & 15;
        const float* src = net ? mW1 : gW1;
        float v = src[((size_t)(l * NH + hh) * 128 + half * 64 + ks * 32 + q * 8 + j) * 256
                      + chunk * 64 + nt * 16 + n16];
        W1sw[tid] = (_Float16)v;
    } else {
        int t2 = tid - W1L_ELEMS;
        if (t2 < W2L_ELEMS) {
            int j = t2 & 7, lane = (t2 >> 3) & 63;
            int r1 = t2 >> 9;
            int nt = r1 & 3, ks2 = (r1 >> 2) & 7, hh = r1 >> 5;
            int q = lane >> 4, n16 = lane & 15;
            float v = mW2[((size_t)(l * NH + hh) * 256 + ks2 * 32 + q * 8 + j) * 64
                          + nt * 16 + n16];
            W2sw[t2] = (_Float16)v;
        }
    }
}

// ---------------------------------------------------------------------------
// Embedding — round-0 proven (1 node / 64-thread block).
// ---------------------------------------------------------------------------
__global__ __launch_bounds__(64)
void embed_kernel(const float* __restrict__ fea, const float* __restrict__ W,
                  const float* __restrict__ b, const float* __restrict__ wts,
                  float* __restrict__ x)
{
    int n = blockIdx.x;
    int o = threadIdx.x;
    __shared__ float fs[EMBD];
    for (int e = o; e < EMBD; e += 64) fs[e] = fea[n * EMBD + e];
    __syncthreads();
    if (o < F - 1) {
        float acc = b[o];
#pragma unroll 8
        for (int e = 0; e < EMBD; ++e) acc += fs[e] * W[e * (F - 1) + o];
        x[n * F + o] = acc;
    } else {
        x[n * F + F - 1] = wts[n];
    }
}

// ---------------------------------------------------------------------------
// Round 17: net_wave — FUSED 3 layers + pool in one dispatch. Crystals are
// fully independent (edges intra-crystal, residual per-node), so the 4
// device-wide dispatch barriers were unnecessary. Per wave (3 crystals):
// run the PROVEN layer body 3x (rolled l-loop — unrolling spills, round 13),
// residual kept in regs (xcur[15], col=lane), A-frags rebuilt via a dead LDS
// region (wb+9216, ex-msgL rows; wave-in-order DS makes read-then-write safe),
// then the PROVEN pool body using the already-current A-frags. x is never
// written to HBM (WRITE_SIZE drops 12.5 MB/layer -> out-only 2.56 MB total).
// ---------------------------------------------------------------------------
#define WAVE_LDS 12288   // bytes per wave slice

__global__ __launch_bounds__(256, 2)
void net_wave(const float* __restrict__ x,
              const _Float16* __restrict__ W1sw,
              const _Float16* __restrict__ W2sw,
              const float* __restrict__ gb1, const float* __restrict__ gb2v,
              const float* __restrict__ mb1, const float* __restrict__ mb2,
              const float* __restrict__ gW2, const float* __restrict__ gpw,
              const _Float16* __restrict__ cW1sw,
              const _Float16* __restrict__ cW2sw,
              const float* __restrict__ cgb1, const float* __restrict__ cgb2v,
              const float* __restrict__ cmb1, const float* __restrict__ cmb2,
              const float* __restrict__ cgW2, const float* __restrict__ cpw,
              const float* __restrict__ wts, float* __restrict__ out, int Ntot)
{
    __shared__ __align__(16) char smem[4 * WAVE_LDS];

    const int t = threadIdx.x, w = t >> 6, lane = t & 63;
    const int q = lane >> 4, m16 = lane & 15;

    char* wb = smem + w * WAVE_LDS;
    _Float16 (*PQ)[16][72] = (_Float16 (*)[16][72])wb;   // [4][16][72] = 9216 B
    _Float16 (*msgL)[72]   = (_Float16 (*)[72])wb;       // [80][72] = 11520 B (aliases PQ)
    _Float16 (*xS)[72]     = (_Float16 (*)[72])(wb + 9216); // [16][72] A-rebuild buf
    float* gateS  = (float*)(wb + 11520);                // [80]
    float* anormS = (float*)(wb + 11840);                // [80]
    float* wpowS  = (float*)(wb + 12160);                // [16]

    const int nw0 = (blockIdx.x * 12 + w * CW) * K;      // first node of this wave
    const int c0  = blockIdx.x * 12 + w * CW;            // first crystal
    const int Ctot = Ntot / K;
    const int vn  = (Ntot - nw0 < NWN) ? (Ntot - nw0) : NWN;
    const int vc  = (Ctot - c0 < CW) ? (Ctot - c0) : CW;
    (void)vn;

    // ---- A-fragments of x (embed output), fp16, loaded once ----
    half8 A[2];
    {
        int arow = nw0 + m16;
        if (arow > Ntot - 1) arow = Ntot - 1;            // clamp pad rows (finite junk)
        if (arow < 0) arow = 0;
        const float* xr = x + (size_t)arow * F;
#pragma unroll
        for (int ks = 0; ks < 2; ++ks) {
            float4 f0 = *(const float4*)(xr + ks * 32 + q * 8);
            float4 f1 = *(const float4*)(xr + ks * 32 + q * 8 + 4);
            half8 a;
            a[0] = (_Float16)f0.x; a[1] = (_Float16)f0.y;
            a[2] = (_Float16)f0.z; a[3] = (_Float16)f0.w;
            a[4] = (_Float16)f1.x; a[5] = (_Float16)f1.y;
            a[6] = (_Float16)f1.z; a[7] = (_Float16)f1.w;
            A[ks] = a;
        }
    }

    // ---- residual copy, per-lane col layout: xcur[n] = x[nw0+n][lane] ----
    float xcur[NWN];
#pragma unroll
    for (int n = 0; n < NWN; ++n) {
        int r = nw0 + n;
        if (r > Ntot - 1) r = Ntot - 1;
        if (r < 0) r = 0;
        xcur[n] = x[(size_t)r * F + lane];
    }

    // ---- per-lane edge -> local node rows (75 valid edges in 5 tiles of 16) ----
    int iR[ET], jR[ET];
#pragma unroll
    for (int et = 0; et < ET; ++et) {
        int e = et * 16 + m16;
        if (e < EWE) {
            int cl = e / 25, rm = e % 25;
            iR[et] = cl * K + rm / K;
            jR[et] = cl * K + rm % K;
        } else { iR[et] = 15; jR[et] = 15; }             // pad row (finite)
    }

    // ======================= 3 graph layers (rolled) =======================
#pragma clang loop unroll(disable)
    for (int l = 0; l < NL; ++l) {
        float oacc[NWN];
#pragma unroll
        for (int n = 0; n < NWN; ++n) oacc[n] = 0.f;

        for (int h = 0; h < NH; ++h) {
            const int lh = l * NH + h, lhw = lh;

            if (lane < NWN) {
                int wi = nw0 + lane;
                if (wi > Ntot - 1) wi = Ntot - 1;
                if (wi < 0) wi = 0;
                wpowS[lane] = powf(wts[wi], gpw[lh]);
            }
            if (lane >= NWN && lane < NWN + 5) anormS[EWE + (lane - NWN)] = 0.f;

            f32x4 acc2[ET][4];
#pragma unroll
            for (int et = 0; et < ET; ++et)
#pragma unroll
                for (int nt = 0; nt < 4; ++nt) acc2[et][nt] = (f32x4){0.f, 0.f, 0.f, 0.f};
            float gacc[ET] = {0.f, 0.f, 0.f, 0.f, 0.f};

            for (int c = 0; c < 4; ++c) {
                // ---- GEMM2 B-frags for this chunk ----
                half8 B2[8];
                {
                    const _Float16* W2b = W2sw + ((size_t)lhw * 8 + c * 2) * 2048;
#pragma unroll
                    for (int f = 0; f < 8; ++f)
                        B2[f] = *(const half8*)(W2b + ((size_t)f * 64 + lane) * 8);
                }

                // ---- stage-1: 4 net-halves, transposed mfma -> packed writes ----
#pragma unroll
                for (int hf = 0; hf < 4; ++hf) {
                    f32x4 accS[4];
#pragma unroll
                    for (int nt = 0; nt < 4; ++nt) accS[nt] = (f32x4){0.f, 0.f, 0.f, 0.f};
                    const _Float16* Wb = W1sw + ((size_t)lhw * 4 + hf) * 16384 + c * 4096;
#pragma unroll
                    for (int nt = 0; nt < 4; ++nt)
#pragma unroll
                        for (int ks = 0; ks < 2; ++ks) {
                            half8 B = *(const half8*)(Wb + ((nt * 2 + ks) * 64 + lane) * 8);
                            accS[nt] = __builtin_amdgcn_mfma_f32_16x16x32_f16(
                                B, A[ks], accS[nt], 0, 0, 0);
                        }
#pragma unroll
                    for (int nt = 0; nt < 4; ++nt) {
                        h2 lo = cvt_pk(accS[nt][0], accS[nt][1]);
                        h2 hi = cvt_pk(accS[nt][2], accS[nt][3]);
                        h4 pk = __builtin_shufflevector(lo, hi, 0, 1, 2, 3);
                        *(h4*)&PQ[hf][m16][nt * 16 + q * 4] = pk;
                    }
                }

                // ---- per-chunk bias slices; wg packed to f16 ----
                half8 bg8[2], bm8[2];
                h2 wgh2[2][4];
#pragma unroll
                for (int ks = 0; ks < 2; ++ks) {
                    const int ub = c * 64 + ks * 32 + q * 8;
                    float4 g0 = *(const float4*)(gb1 + (size_t)lh * HID + ub);
                    float4 g1 = *(const float4*)(gb1 + (size_t)lh * HID + ub + 4);
                    float4 m0 = *(const float4*)(mb1 + (size_t)lh * HID + ub);
                    float4 m1 = *(const float4*)(mb1 + (size_t)lh * HID + ub + 4);
                    float4 w0 = *(const float4*)(gW2 + (size_t)lh * HID + ub);
                    float4 w1 = *(const float4*)(gW2 + (size_t)lh * HID + ub + 4);
                    half8 bg, bm;
                    bg[0]=(_Float16)g0.x; bg[1]=(_Float16)g0.y; bg[2]=(_Float16)g0.z; bg[3]=(_Float16)g0.w;
                    bg[4]=(_Float16)g1.x; bg[5]=(_Float16)g1.y; bg[6]=(_Float16)g1.z; bg[7]=(_Float16)g1.w;
                    bm[0]=(_Float16)m0.x; bm[1]=(_Float16)m0.y; bm[2]=(_Float16)m0.z; bm[3]=(_Float16)m0.w;
                    bm[4]=(_Float16)m1.x; bm[5]=(_Float16)m1.y; bm[6]=(_Float16)m1.z; bm[7]=(_Float16)m1.w;
                    bg8[ks] = bg; bm8[ks] = bm;
                    wgh2[ks][0] = cvt_pk(w0.x, w0.y);
                    wgh2[ks][1] = cvt_pk(w0.z, w0.w);
                    wgh2[ks][2] = cvt_pk(w1.x, w1.y);
                    wgh2[ks][3] = cvt_pk(w1.z, w1.w);
                }

                // ---- consume: gate fdot2 + hm A-frags + GEMM2 ----
#pragma unroll
                for (int et = 0; et < ET; ++et) {
                    half8 af[2];
#pragma unroll
                    for (int ks = 0; ks < 2; ++ks) {
                        const int ub = ks * 32 + q * 8;
                        half8 pg = *(const half8*)&PQ[0][iR[et]][ub];
                        half8 qg = *(const half8*)&PQ[1][jR[et]][ub];
                        half8 pm = *(const half8*)&PQ[2][iR[et]][ub];
                        half8 qm = *(const half8*)&PQ[3][jR[et]][ub];
                        half8 tg = lrelu8(pg + qg + bg8[ks]);
                        h2 t01 = __builtin_shufflevector(tg, tg, 0, 1);
                        h2 t23 = __builtin_shufflevector(tg, tg, 2, 3);
                        h2 t45 = __builtin_shufflevector(tg, tg, 4, 5);
                        h2 t67 = __builtin_shufflevector(tg, tg, 6, 7);
                        gacc[et] = __builtin_amdgcn_fdot2(t01, wgh2[ks][0], gacc[et], false);
                        gacc[et] = __builtin_amdgcn_fdot2(t23, wgh2[ks][1], gacc[et], false);
                        gacc[et] = __builtin_amdgcn_fdot2(t45, wgh2[ks][2], gacc[et], false);
                        gacc[et] = __builtin_amdgcn_fdot2(t67, wgh2[ks][3], gacc[et], false);
                        af[ks] = lrelu8(pm + qm + bm8[ks]);
                    }
#pragma unroll
                    for (int nt = 0; nt < 4; ++nt)
#pragma unroll
                        for (int ks = 0; ks < 2; ++ks)
                            acc2[et][nt] = __builtin_amdgcn_mfma_f32_16x16x32_f16(
                                af[ks], B2[ks * 4 + nt], acc2[et][nt], 0, 0, 0);
                }
            }

            // ---- gate reduce across quads ----
            const float gb2s = gb2v[lh];
#pragma unroll
            for (int et = 0; et < ET; ++et) {
                float g = gacc[et];
                g += __shfl_xor(g, 16);
                g += __shfl_xor(g, 32);
                if (q == 0) gateS[et * 16 + m16] = g + gb2s;
            }

            // ---- segment softmax ----
            if (lane < NWN) {
                const int cl5 = (lane / K) * K;
                float gg[K], mx = -1e30f;
#pragma unroll
                for (int jj = 0; jj < K; ++jj) {
                    gg[jj] = gateS[lane * K + jj];
                    mx = fmaxf(mx, gg[jj]);
                }
                float s = 0.f, wv[K];
#pragma unroll
                for (int jj = 0; jj < K; ++jj) {
                    wv[jj] = wpowS[cl5 + jj] * expf(gg[jj] - mx);
                    s += wv[jj];
                }
                float inv = 1.f / (s + 1e-10f) * (1.f / 3.f);  // fold head mean
#pragma unroll
                for (int jj = 0; jj < K; ++jj) anormS[lane * K + jj] = wv[jj] * inv;
            }

            // ---- weighted msg -> msgL ----
            float b2v[4];
#pragma unroll
            for (int nt = 0; nt < 4; ++nt) b2v[nt] = mb2[(size_t)lh * F + nt * 16 + m16];
#pragma unroll
            for (int et = 0; et < ET; ++et) {
                f32x4 an = *(const f32x4*)&anormS[et * 16 + q * 4];
#pragma unroll
                for (int nt = 0; nt < 4; ++nt)
#pragma unroll
                    for (int rg = 0; rg < 4; ++rg) {
                        float v = (acc2[et][nt][rg] + b2v[nt]) * an[rg];
                        msgL[et * 16 + q * 4 + rg][nt * 16 + m16] = (_Float16)v;
                    }
            }

            // ---- aggregate ----
#pragma unroll
            for (int n = 0; n < NWN; ++n) {
                float s = 0.f;
#pragma unroll
                for (int jj = 0; jj < K; ++jj) s += (float)msgL[n * K + jj][lane];
                oacc[n] += s;
            }
        }

        // ---- residual in regs + A-frag rebuild via xS (dead region) ----
#pragma unroll
        for (int n = 0; n < NWN; ++n) {
            float xn = oacc[n] + xcur[n];
            xcur[n] = xn;
            xS[n][lane] = (_Float16)xn;
        }
        xS[15][lane] = (_Float16)0.f;                    // pad row finite
#pragma unroll
        for (int ks = 0; ks < 2; ++ks)
            A[ks] = *(const half8*)&xS[m16][ks * 32 + q * 8];
    }

    // ======================= pool (round-15 proven body) =======================
    _Float16 (*PQp)[16][72] = (_Float16 (*)[16][72])wb;  // [2][16][72]
    _Float16 (*msgP)[72]    = (_Float16 (*)[72])wb;      // [16][72] (aliases PQp)

    float oaccP[CW] = {0.f, 0.f, 0.f};

    for (int h = 0; h < NH; ++h) {
        if (lane < NWN) {
            int wi = nw0 + lane;
            if (wi > Ntot - 1) wi = Ntot - 1;
            if (wi < 0) wi = 0;
            wpowS[lane] = powf(wts[wi], cpw[h]);
        }
        if (lane == NWN) anormS[15] = 0.f;               // pad node row

        f32x4 acc2[4];
#pragma unroll
        for (int nt = 0; nt < 4; ++nt) acc2[nt] = (f32x4){0.f, 0.f, 0.f, 0.f};
        float gacc = 0.f;

        for (int c = 0; c < 4; ++c) {
            half8 B2[8];
            {
                const _Float16* W2b = cW2sw + (size_t)h * 16384 + c * 4096;
#pragma unroll
                for (int f = 0; f < 8; ++f)
                    B2[f] = *(const half8*)(W2b + ((size_t)f * 64 + lane) * 8);
            }

#pragma unroll
            for (int net = 0; net < 2; ++net) {
                f32x4 accS[4];
#pragma unroll
                for (int nt = 0; nt < 4; ++nt) accS[nt] = (f32x4){0.f, 0.f, 0.f, 0.f};
                const _Float16* Wb = cW1sw + ((size_t)(h * 2 + net) * 4 + c) * 4096;
#pragma unroll
                for (int nt = 0; nt < 4; ++nt)
#pragma unroll
                    for (int ks = 0; ks < 2; ++ks) {
                        half8 B = *(const half8*)(Wb + ((nt * 2 + ks) * 64 + lane) * 8);
                        accS[nt] = __builtin_amdgcn_mfma_f32_16x16x32_f16(
                            B, A[ks], accS[nt], 0, 0, 0);
                    }
#pragma unroll
                for (int nt = 0; nt < 4; ++nt) {
                    h2 lo = cvt_pk(accS[nt][0], accS[nt][1]);
                    h2 hi = cvt_pk(accS[nt][2], accS[nt][3]);
                    h4 pk = __builtin_shufflevector(lo, hi, 0, 1, 2, 3);
                    *(h4*)&PQp[net][m16][nt * 16 + q * 4] = pk;
                }
            }

            half8 bg8[2], bm8[2];
            h2 wgh2[2][4];
#pragma unroll
            for (int ks = 0; ks < 2; ++ks) {
                const int ub = c * 64 + ks * 32 + q * 8;
                float4 g0 = *(const float4*)(cgb1 + (size_t)h * HID + ub);
                float4 g1 = *(const float4*)(cgb1 + (size_t)h * HID + ub + 4);
                float4 m0 = *(const float4*)(cmb1 + (size_t)h * HID + ub);
                float4 m1 = *(const float4*)(cmb1 + (size_t)h * HID + ub + 4);
                float4 w0 = *(const float4*)(cgW2 + (size_t)h * HID + ub);
                float4 w1 = *(const float4*)(cgW2 + (size_t)h * HID + ub + 4);
                half8 bg, bm;
                bg[0]=(_Float16)g0.x; bg[1]=(_Float16)g0.y; bg[2]=(_Float16)g0.z; bg[3]=(_Float16)g0.w;
                bg[4]=(_Float16)g1.x; bg[5]=(_Float16)g1.y; bg[6]=(_Float16)g1.z; bg[7]=(_Float16)g1.w;
                bm[0]=(_Float16)m0.x; bm[1]=(_Float16)m0.y; bm[2]=(_Float16)m0.z; bm[3]=(_Float16)m0.w;
                bm[4]=(_Float16)m1.x; bm[5]=(_Float16)m1.y; bm[6]=(_Float16)m1.z; bm[7]=(_Float16)m1.w;
                bg8[ks] = bg; bm8[ks] = bm;
                wgh2[ks][0] = cvt_pk(w0.x, w0.y);
                wgh2[ks][1] = cvt_pk(w0.z, w0.w);
                wgh2[ks][2] = cvt_pk(w1.x, w1.y);
                wgh2[ks][3] = cvt_pk(w1.z, w1.w);
            }

            {
                half8 af[2];
#pragma unroll
                for (int ks = 0; ks < 2; ++ks) {
                    const int ub = ks * 32 + q * 8;
                    half8 pg = *(const half8*)&PQp[0][m16][ub];
                    half8 pm = *(const half8*)&PQp[1][m16][ub];
                    half8 tg = lrelu8(pg + bg8[ks]);
                    h2 t01 = __builtin_shufflevector(tg, tg, 0, 1);
                    h2 t23 = __builtin_shufflevector(tg, tg, 2, 3);
                    h2 t45 = __builtin_shufflevector(tg, tg, 4, 5);
                    h2 t67 = __builtin_shufflevector(tg, tg, 6, 7);
                    gacc = __builtin_amdgcn_fdot2(t01, wgh2[ks][0], gacc, false);
                    gacc = __builtin_amdgcn_fdot2(t23, wgh2[ks][1], gacc, false);
                    gacc = __builtin_amdgcn_fdot2(t45, wgh2[ks][2], gacc, false);
                    gacc = __builtin_amdgcn_fdot2(t67, wgh2[ks][3], gacc, false);
                    af[ks] = lrelu8(pm + bm8[ks]);
                }
#pragma unroll
                for (int nt = 0; nt < 4; ++nt)
#pragma unroll
                    for (int ks = 0; ks < 2; ++ks)
                        acc2[nt] = __builtin_amdgcn_mfma_f32_16x16x32_f16(
                            af[ks], B2[ks * 4 + nt], acc2[nt], 0, 0, 0);
            }
        }

        const float gb2s = cgb2v[h];
        {
            float g = gacc;
            g += __shfl_xor(g, 16);
            g += __shfl_xor(g, 32);
            if (q == 0) gateS[m16] = g + gb2s;
        }

        if (lane < CW) {
            const int n0 = lane * K;
            float gg[K], mx = -1e30f;
#pragma unroll
            for (int jj = 0; jj < K; ++jj) {
                gg[jj] = gateS[n0 + jj];
                mx = fmaxf(mx, gg[jj]);
            }
            float s = 0.f, wv[K];
#pragma unroll
            for (int jj = 0; jj < K; ++jj) {
                wv[jj] = wpowS[n0 + jj] * expf(gg[jj] - mx);
                s += wv[jj];
            }
            float inv = 1.f / (s + 1e-10f) * (1.f / 3.f);
#pragma unroll
            for (int jj = 0; jj < K; ++jj) anormS[n0 + jj] = wv[jj] * inv;
        }

        float b2v[4];
#pragma unroll
        for (int nt = 0; nt < 4; ++nt) b2v[nt] = cmb2[(size_t)h * F + nt * 16 + m16];
#pragma unroll
        for (int nt = 0; nt < 4; ++nt)
#pragma unroll
            for (int rg = 0; rg < 4; ++rg) {
                int row = q * 4 + rg;
                float v = (acc2[nt][rg] + b2v[nt]) * anormS[row];
                msgP[row][nt * 16 + m16] = (_Float16)v;
            }

#pragma unroll
        for (int cl = 0; cl < CW; ++cl) {
            float s = 0.f;
#pragma unroll
            for (int jj = 0; jj < K; ++jj) s += (float)msgP[cl * K + jj][lane];
            oaccP[cl] += s;
        }
    }

#pragma unroll
    for (int cl = 0; cl < CW; ++cl)
        if (cl < vc)
            out[(size_t)(c0 + cl) * F + lane] = oaccP[cl];
}

// ---------------------------------------------------------------------------
// Fallback layer kernel (round-12 proven, writes x) — used when ws too small.
// ---------------------------------------------------------------------------
__global__ __launch_bounds__(256, 2)
void layer_wave(float* __restrict__ x,
                const _Float16* __restrict__ W1sw,
                const _Float16* __restrict__ W2sw,
                const float* __restrict__ gb1, const float* __restrict__ gb2v,
                const float* __restrict__ mb1, const float* __restrict__ mb2,
                const float* __restrict__ gW2, const float* __restrict__ gpw,
                const float* __restrict__ wts, int l, int lhw0, int Ntot)
{
    __shared__ __align__(16) char smem[4 * WAVE_LDS];

    const int t = threadIdx.x, w = t >> 6, lane = t & 63;
    const int q = lane >> 4, m16 = lane & 15;

    char* wb = smem + w * WAVE_LDS;
    _Float16 (*PQ)[16][72] = (_Float16 (*)[16][72])wb;
    _Float16 (*msgL)[72]   = (_Float16 (*)[72])wb;
    float* gateS  = (float*)(wb + 11520);
    float* anormS = (float*)(wb + 11840);
    float* wpowS  = (float*)(wb + 12160);

    const int nw0 = (blockIdx.x * 12 + w * CW) * K;
    const int vn  = (Ntot - nw0 < NWN) ? (Ntot - nw0) : NWN;

    half8 A[2];
    {
        int arow = nw0 + m16;
        if (arow > Ntot - 1) arow = Ntot - 1;
        if (arow < 0) arow = 0;
        const float* xr = x + (size_t)arow * F;
#pragma unroll
        for (int ks = 0; ks < 2; ++ks) {
            float4 f0 = *(const float4*)(xr + ks * 32 + q * 8);
            float4 f1 = *(const float4*)(xr + ks * 32 + q * 8 + 4);
            half8 a;
            a[0] = (_Float16)f0.x; a[1] = (_Float16)f0.y;
            a[2] = (_Float16)f0.z; a[3] = (_Float16)f0.w;
            a[4] = (_Float16)f1.x; a[5] = (_Float16)f1.y;
            a[6] = (_Float16)f1.z; a[7] = (_Float16)f1.w;
            A[ks] = a;
        }
    }

    int iR[ET], jR[ET];
#pragma unroll
    for (int et = 0; et < ET; ++et) {
        int e = et * 16 + m16;
        if (e < EWE) {
            int cl = e / 25, rm = e % 25;
            iR[et] = cl * K + rm / K;
            jR[et] = cl * K + rm % K;
        } else { iR[et] = 15; jR[et] = 15; }
    }

    float oacc[NWN];
#pragma unroll
    for (int n = 0; n < NWN; ++n) oacc[n] = 0.f;

    for (int h = 0; h < NH; ++h) {
        const int lh = l * NH + h, lhw = lhw0 + h;

        if (lane < NWN) {
            int wi = nw0 + lane;
            if (wi > Ntot - 1) wi = Ntot - 1;
            if (wi < 0) wi = 0;
            wpowS[lane] = powf(wts[wi], gpw[lh]);
        }
        if (lane >= NWN && lane < NWN + 5) anormS[EWE + (lane - NWN)] = 0.f;

        f32x4 acc2[ET][4];
#pragma unroll
        for (int et = 0; et < ET; ++et)
#pragma unroll
            for (int nt = 0; nt < 4; ++nt) acc2[et][nt] = (f32x4){0.f, 0.f, 0.f, 0.f};
        float gacc[ET] = {0.f, 0.f, 0.f, 0.f, 0.f};

        for (int c = 0; c < 4; ++c) {
            half8 B2[8];
            {
                const _Float16* W2b = W2sw + ((size_t)lhw * 8 + c * 2) * 2048;
#pragma unroll
                for (int f = 0; f < 8; ++f)
                    B2[f] = *(const half8*)(W2b + ((size_t)f * 64 + lane) * 8);
            }

#pragma unroll
            for (int hf = 0; hf < 4; ++hf) {
                f32x4 accS[4];
#pragma unroll
                for (int nt = 0; nt < 4; ++nt) accS[nt] = (f32x4){0.f, 0.f, 0.f, 0.f};
                const _Float16* Wb = W1sw + ((size_t)lhw * 4 + hf) * 16384 + c * 4096;
#pragma unroll
                for (int nt = 0; nt < 4; ++nt)
#pragma unroll
                    for (int ks = 0; ks < 2; ++ks) {
                        half8 B = *(const half8*)(Wb + ((nt * 2 + ks) * 64 + lane) * 8);
                        accS[nt] = __builtin_amdgcn_mfma_f32_16x16x32_f16(
                            B, A[ks], accS[nt], 0, 0, 0);
                    }
#pragma unroll
                for (int nt = 0; nt < 4; ++nt) {
                    h2 lo = cvt_pk(accS[nt][0], accS[nt][1]);
                    h2 hi = cvt_pk(accS[nt][2], accS[nt][3]);
                    h4 pk = __builtin_shufflevector(lo, hi, 0, 1, 2, 3);
                    *(h4*)&PQ[hf][m16][nt * 16 + q * 4] = pk;
                }
            }

            half8 bg8[2], bm8[2];
            h2 wgh2[2][4];
#pragma unroll
            for (int ks = 0; ks < 2; ++ks) {
                const int ub = c * 64 + ks * 32 + q * 8;
                float4 g0 = *(const float4*)(gb1 + (size_t)lh * HID + ub);
                float4 g1 = *(const float4*)(gb1 + (size_t)lh * HID + ub + 4);
                float4 m0 = *(const float4*)(mb1 + (size_t)lh * HID + ub);
                float4 m1 = *(const float4*)(mb1 + (size_t)lh * HID + ub + 4);
                float4 w0 = *(const float4*)(gW2 + (size_t)lh * HID + ub);
                float4 w1 = *(const float4*)(gW2 + (size_t)lh * HID + ub + 4);
                half8 bg, bm;
                bg[0]=(_Float16)g0.x; bg[1]=(_Float16)g0.y; bg[2]=(_Float16)g0.z; bg[3]=(_Float16)g0.w;
                bg[4]=(_Float16)g1.x; bg[5]=(_Float16)g1.y; bg[6]=(_Float16)g1.z; bg[7]=(_Float16)g1.w;
                bm[0]=(_Float16)m0.x; bm[1]=(_Float16)m0.y; bm[2]=(_Float16)m0.z; bm[3]=(_Float16)m0.w;
                bm[4]=(_Float16)m1.x; bm[5]=(_Float16)m1.y; bm[6]=(_Float16)m1.z; bm[7]=(_Float16)m1.w;
                bg8[ks] = bg; bm8[ks] = bm;
                wgh2[ks][0] = cvt_pk(w0.x, w0.y);
                wgh2[ks][1] = cvt_pk(w0.z, w0.w);
                wgh2[ks][2] = cvt_pk(w1.x, w1.y);
                wgh2[ks][3] = cvt_pk(w1.z, w1.w);
            }

#pragma unroll
            for (int et = 0; et < ET; ++et) {
                half8 af[2];
#pragma unroll
                for (int ks = 0; ks < 2; ++ks) {
                    const int ub = ks * 32 + q * 8;
                    half8 pg = *(const half8*)&PQ[0][iR[et]][ub];
                    half8 qg = *(const half8*)&PQ[1][jR[et]][ub];
                    half8 pm = *(const half8*)&PQ[2][iR[et]][ub];
                    half8 qm = *(const half8*)&PQ[3][jR[et]][ub];
                    half8 tg = lrelu8(pg + qg + bg8[ks]);
                    h2 t01 = __builtin_shufflevector(tg, tg, 0, 1);
                    h2 t23 = __builtin_shufflevector(tg, tg, 2, 3);
                    h2 t45 = __builtin_shufflevector(tg, tg, 4, 5);
                    h2 t67 = __builtin_shufflevector(tg, tg, 6, 7);
                    gacc[et] = __builtin_amdgcn_fdot2(t01, wgh2[ks][0], gacc[et], false);
                    gacc[et] = __builtin_amdgcn_fdot2(t23, wgh2[ks][1], gacc[et], false);
                    gacc[et] = __builtin_amdgcn_fdot2(t45, wgh2[ks][2], gacc[et], false);
                    gacc[et] = __builtin_amdgcn_fdot2(t67, wgh2[ks][3], gacc[et], false);
                    af[ks] = lrelu8(pm + qm + bm8[ks]);
                }
#pragma unroll
                for (int nt = 0; nt < 4; ++nt)
#pragma unroll
                    for (int ks = 0; ks < 2; ++ks)
                        acc2[et][nt] = __builtin_amdgcn_mfma_f32_16x16x32_f16(
                            af[ks], B2[ks * 4 + nt], acc2[et][nt], 0, 0, 0);
            }
        }

        const float gb2s = gb2v[lh];
#pragma unroll
        for (int et = 0; et < ET; ++et) {
            float g = gacc[et];
            g += __shfl_xor(g, 16);
            g += __shfl_xor(g, 32);
            if (q == 0) gateS[et * 16 + m16] = g + gb2s;
        }

        if (lane < NWN) {
            const int cl5 = (lane / K) * K;
            float gg[K], mx = -1e30f;
#pragma unroll
            for (int jj = 0; jj < K; ++jj) {
                gg[jj] = gateS[lane * K + jj];
                mx = fmaxf(mx, gg[jj]);
            }
            float s = 0.f, wv[K];
#pragma unroll
            for (int jj = 0; jj < K; ++jj) {
                wv[jj] = wpowS[cl5 + jj] * expf(gg[jj] - mx);
                s += wv[jj];
            }
            float inv = 1.f / (s + 1e-10f) * (1.f / 3.f);
#pragma unroll
            for (int jj = 0; jj < K; ++jj) anormS[lane * K + jj] = wv[jj] * inv;
        }

        float b2v[4];
#pragma unroll
        for (int nt = 0; nt < 4; ++nt) b2v[nt] = mb2[(size_t)lh * F + nt * 16 + m16];
#pragma unroll
        for (int et = 0; et < ET; ++et) {
            f32x4 an = *(const f32x4*)&anormS[et * 16 + q * 4];
#pragma unroll
            for (int nt = 0; nt < 4; ++nt)
#pragma unroll
                for (int rg = 0; rg < 4; ++rg) {
                    float v = (acc2[et][nt][rg] + b2v[nt]) * an[rg];
                    msgL[et * 16 + q * 4 + rg][nt * 16 + m16] = (_Float16)v;
                }
        }

#pragma unroll
        for (int n = 0; n < NWN; ++n) {
            float s = 0.f;
#pragma unroll
            for (int jj = 0; jj < K; ++jj) s += (float)msgL[n * K + jj][lane];
            oacc[n] += s;
        }
    }

#pragma unroll
    for (int n = 0; n < NWN; ++n) {
        if (n < vn) {
            size_t idx = (size_t)(nw0 + n) * F + lane;
            x[idx] = oacc[n] + x[idx];
        }
    }
}

// ---------------------------------------------------------------------------
// Fallback fp32 pool (round-4 proven)
// ---------------------------------------------------------------------------
__global__ __launch_bounds__(256)
void pool_kernel(const float* __restrict__ x,
                 const float* __restrict__ cgW1, const float* __restrict__ cgb1,
                 const float* __restrict__ cgW2, const float* __restrict__ cgb2,
                 const float* __restrict__ cmW1, const float* __restrict__ cmb1,
                 const float* __restrict__ cmW2, const float* __restrict__ cmb2,
                 const float* __restrict__ cpw, const float* __restrict__ wts,
                 float* __restrict__ out)
{
    __shared__ float xs[K * F];
    __shared__ float hmS[K][HID];
    __shared__ float msgS[K][F];
    __shared__ float outacc[F];
    __shared__ float b1g[HID], b1m[HID], w2g[HID];
    __shared__ float b2mS[F];
    __shared__ float gpart[K][2];
    __shared__ float gate_s[K];
    __shared__ float anorm[K];
    __shared__ float wn[K], wpow[K];

    const int c = blockIdx.x;
    const int t = threadIdx.x;
    const int wave = t >> 6, lane = t & 63;

    for (int d = t; d < K * F; d += 256) xs[d] = x[c * K * F + d];
    if (t < F) outacc[t] = 0.f;
    if (t < K) wn[t] = wts[c * K + t];
    __syncthreads();

    for (int h = 0; h < NH; ++h) {
        if (t < HID) {
            b1g[t] = cgb1[(size_t)h * HID + t];
            b1m[t] = cmb1[(size_t)h * HID + t];
            w2g[t] = cgW2[(size_t)h * HID + t];
        }
        if (t < F) b2mS[t] = cmb2[(size_t)h * F + t];
        if (t < K) wpow[t] = powf(wn[t], cpw[h]);
        __syncthreads();

        {
            const int grp = t >> 7;
            const int up  = t & 127;
            const float* Wb = (grp == 0 ? cgW1 : cmW1) + (size_t)h * F * HID;
            const float2* W2p = (const float2*)Wb;
            float acc[K][2];
#pragma unroll
            for (int i = 0; i < K; ++i) { acc[i][0] = 0.f; acc[i][1] = 0.f; }
            for (int k = 0; k < F; ++k) {
                float2 wv = W2p[k * (HID / 2) + up];
#pragma unroll
                for (int i = 0; i < K; ++i) {
                    float xv = xs[i * F + k];
                    acc[i][0] += xv * wv.x;
                    acc[i][1] += xv * wv.y;
                }
            }
            if (grp == 0) {
#pragma unroll
                for (int i = 0; i < K; ++i) {
                    float h0 = lrelu(acc[i][0] + b1g[2 * up]);
                    float h1 = lrelu(acc[i][1] + b1g[2 * up + 1]);
                    float part = h0 * w2g[2 * up] + h1 * w2g[2 * up + 1];
#pragma unroll
                    for (int s = 32; s; s >>= 1) part += __shfl_xor(part, s);
                    if (lane == 0) gpart[i][wave & 1] = part;
                }
            } else {
#pragma unroll
                for (int i = 0; i < K; ++i) {
                    hmS[i][2 * up]     = lrelu(acc[i][0] + b1m[2 * up]);
                    hmS[i][2 * up + 1] = lrelu(acc[i][1] + b1m[2 * up + 1]);
                }
            }
        }
        __syncthreads();
        if (t < K) gate_s[t] = cgb2[h] + gpart[t][0] + gpart[t][1];

        {
            const float2* W232 = (const float2*)(cmW2 + (size_t)h * HID * F);
            if (t < K * (F / 2)) {
                int i  = t >> 5;
                int op = t & 31;
                float a0 = b2mS[2 * op], a1 = b2mS[2 * op + 1];
#pragma unroll 8
                for (int u = 0; u < HID; ++u) {
                    float2 wv = W232[u * (F / 2) + op];
                    float hv = hmS[i][u];
                    a0 += hv * wv.x;
                    a1 += hv * wv.y;
                }
                msgS[i][2 * op]     = a0;
                msgS[i][2 * op + 1] = a1;
            }
        }
        __syncthreads();

        if (t == 0) {
            float mx = -1e30f;
#pragma unroll
            for (int i = 0; i < K; ++i) mx = fmaxf(mx, gate_s[i]);
            float wv[K], s = 0.f;
#pragma unroll
            for (int i = 0; i < K; ++i) {
                wv[i] = wpow[i] * expf(gate_s[i] - mx);
                s += wv[i];
            }
            float inv = 1.f / (s + 1e-10f);
#pragma unroll
            for (int i = 0; i < K; ++i) anorm[i] = wv[i] * inv;
        }
        __syncthreads();

        if (t < F) {
            float s = 0.f;
#pragma unroll
            for (int i = 0; i < K; ++i) s += anorm[i] * msgS[i][t];
            outacc[t] += s * (1.f / 3.f);
        }
        __syncthreads();
    }

    if (t < F) out[(size_t)c * F + t] = outacc[t];
}

// ---------------------------------------------------------------------------
extern "C" void kernel_launch(void* const* d_in, const int* in_sizes, int n_in,
                              void* d_out, int out_size, void* d_ws, size_t ws_size,
                              hipStream_t stream)
{
    const float* wts  = (const float*)d_in[0];
    const float* fea  = (const float*)d_in[1];
    const float* embW = (const float*)d_in[6];
    const float* embB = (const float*)d_in[7];
    const float* gW1  = (const float*)d_in[8];
    const float* gb1  = (const float*)d_in[9];
    const float* gW2  = (const float*)d_in[10];
    const float* gb2  = (const float*)d_in[11];
    const float* mW1  = (const float*)d_in[12];
    const float* mb1  = (const float*)d_in[13];
    const float* mW2  = (const float*)d_in[14];
    const float* mb2  = (const float*)d_in[15];
    const float* gpw  = (const float*)d_in[16];
    const float* cgW1 = (const float*)d_in[17];
    const float* cgb1 = (const float*)d_in[18];
    const float* cgW2 = (const float*)d_in[19];
    const float* cgb2 = (const float*)d_in[20];
    const float* cmW1 = (const float*)d_in[21];
    const float* cmb1 = (const float*)d_in[22];
    const float* cmW2 = (const float*)d_in[23];
    const float* cmb2 = (const float*)d_in[24];
    const float* cpw  = (const float*)d_in[25];

    const int N = in_sizes[0];   // 50000
    const int C = N / K;         // 10000
    const int layer_blocks = (C + 11) / 12;   // 834 (tail block guarded)

    float* x = (float*)d_ws;                       // [N,F] fp32, 12.8 MB
    const size_t xbytes = (size_t)N * F * 4;
    const size_t need = xbytes + (size_t)WALL_ELEMS * 2;

    embed_kernel<<<N, 64, 0, stream>>>(fea, embW, embB, wts, x);

    if (ws_size >= need) {
        // ---- fast path: prep + single fused network kernel ----
        _Float16* Wall  = (_Float16*)((char*)d_ws + xbytes);
        _Float16* W1sw  = Wall;
        _Float16* W2sw  = Wall + W1SW_ELEMS;
        _Float16* cW1sw = Wall + W1SW_ELEMS + W2SW_ELEMS;
        _Float16* cW2sw = Wall + W1SW_ELEMS + W2SW_ELEMS + CW1_ELEMS;

        prep_all<<<(WALL_ELEMS + 255) / 256, 256, 0, stream>>>(
            gW1, mW1, mW2, cgW1, cmW1, cmW2, Wall);
        net_wave<<<layer_blocks, 256, 0, stream>>>(
            x, W1sw, W2sw, gb1, gb2, mb1, mb2, gW2, gpw,
            cW1sw, cW2sw, cgb1, cgb2, cmb1, cmb2, cgW2, cpw,
            wts, (float*)d_out, N);
    } else {
        // ---- fallback: per-layer prep into d_out scratch ----
        _Float16* W1sw = (_Float16*)d_out;
        _Float16* W2sw = (_Float16*)((char*)d_out + 393216);
        for (int l = 0; l < NL; ++l) {
            prep_layer<<<(W1L_ELEMS + W2L_ELEMS) / 256, 256, 0, stream>>>(
                gW1, mW1, mW2, W1sw, W2sw, l);
            layer_wave<<<layer_blocks, 256, 0, stream>>>(x, W1sw, W2sw,
                                                         gb1, gb2, mb1, mb2, gW2, gpw, wts,
                                                         l, 0, N);
        }
        pool_kernel<<<C, 256, 0, stream>>>(x, cgW1, cgb1, cgW2, cgb2,
                                           cmW1, cmb1, cmW2, cmb2, cpw, wts,
                                           (float*)d_out);
    }
}

// Round 11
// 675.561 us; speedup vs baseline: 2.0891x; 1.0704x over previous
//
#include <hip/hip_runtime.h>
#include <hip/hip_bf16.h>

#define K 5
#define F 64
#define EMBD 200
#define HID 256
#define NH 3
#define NL 3

// wave decomposition: 4 waves x 3 crystals = 12 crystals / block
#define CW 3            // crystals per wave
#define NWN (CW * K)    // 15 nodes per wave
#define EWE (CW * K * K) // 75 edges per wave
#define ET 5            // edge tiles of 16

typedef _Float16 half8 __attribute__((ext_vector_type(8)));
typedef _Float16 h2 __attribute__((ext_vector_type(2)));
typedef _Float16 h4 __attribute__((ext_vector_type(4)));
typedef __fp16 fp16x2 __attribute__((ext_vector_type(2)));
typedef float f32x4 __attribute__((ext_vector_type(4)));

__device__ __forceinline__ float lrelu(float v) { return v >= 0.f ? v : 0.01f * v; }

// cvt_pkrtz returns __fp16x2; bitcast to _Float16x2 (same bits, distinct clang types)
__device__ __forceinline__ h2 cvt_pk(float a, float b) {
    union { fp16x2 f; h2 h; } u;
    u.f = __builtin_amdgcn_cvt_pkrtz(a, b);
    return u.h;
}

__device__ __forceinline__ half8 lrelu8(half8 t) {
    half8 z = 0;
    half8 p = __builtin_elementwise_max(t, z);
    half8 n = __builtin_elementwise_min(t, z);
    return p + n * (_Float16)0.01f;
}

// ---- swizzled-weight element counts (fp16) ----
#define W1SW_ELEMS 589824    // 9 lh * 2 net * 2 half * 4 chunk * 4 nt * 2 ks * 64 * 8
#define W2SW_ELEMS 147456    // 9 lh * 8 ks2 * 4 nt * 64 * 8
#define CW1_ELEMS   98304    // 3 h * 2 net * 4 chunk * 4 nt * 2 ks * 64 * 8
#define CW2_ELEMS   49152    // 3 h * 8 ks2 * 4 nt * 64 * 8
#define WALL_ELEMS (W1SW_ELEMS + W2SW_ELEMS + CW1_ELEMS + CW2_ELEMS)  // 884736
// embed W swizzle: 7 ksteps (224 rows padded) * 4 nt * 64 lane * 8 j
#define EMBSW_ELEMS 14336
#define WALL2_ELEMS (WALL_ELEMS + EMBSW_ELEMS)   // 899072

// per-layer (fallback) sizes
#define W1L_ELEMS 196608
#define W2L_ELEMS 49152

// ---------------------------------------------------------------------------
// Fast path: swizzle ALL weights (layers + pool + embed) fp32 -> fp16 frags.
// ---------------------------------------------------------------------------
__global__ __launch_bounds__(256)
void prep_all(const float* __restrict__ gW1, const float* __restrict__ mW1,
              const float* __restrict__ mW2,
              const float* __restrict__ cgW1, const float* __restrict__ cmW1,
              const float* __restrict__ cmW2, const float* __restrict__ embW,
              _Float16* __restrict__ Wall)
{
    int tid = blockIdx.x * 256 + threadIdx.x;
    if (tid >= WALL2_ELEMS) return;
    float v;
    if (tid < W1SW_ELEMS) {
        int j = tid & 7, lane = (tid >> 3) & 63;
        int r1 = tid >> 9;                       // [lh][net][half][chunk][nt][ks]
        int ks = r1 & 1, nt = (r1 >> 1) & 3, chunk = (r1 >> 3) & 3;
        int half = (r1 >> 5) & 1, net = (r1 >> 6) & 1, lh = r1 >> 7;   // 0..8
        int q = lane >> 4, n16 = lane & 15;
        const float* src = net ? mW1 : gW1;
        v = src[((size_t)lh * 128 + half * 64 + ks * 32 + q * 8 + j) * 256
                + chunk * 64 + nt * 16 + n16];
    } else if (tid < W1SW_ELEMS + W2SW_ELEMS) {
        int t2 = tid - W1SW_ELEMS;
        int j = t2 & 7, lane = (t2 >> 3) & 63;
        int r1 = t2 >> 9;                        // [lh][ks2][nt]
        int nt = r1 & 3, ks2 = (r1 >> 2) & 7, lh = r1 >> 5;            // 0..8
        int q = lane >> 4, n16 = lane & 15;
        v = mW2[((size_t)lh * 256 + ks2 * 32 + q * 8 + j) * 64 + nt * 16 + n16];
    } else if (tid < W1SW_ELEMS + W2SW_ELEMS + CW1_ELEMS) {
        int t2 = tid - (W1SW_ELEMS + W2SW_ELEMS);
        int j = t2 & 7, lane = (t2 >> 3) & 63;
        int r1 = t2 >> 9;                        // [h][net][chunk][nt][ks]
        int ks = r1 & 1, nt = (r1 >> 1) & 3, chunk = (r1 >> 3) & 3;
        int net = (r1 >> 5) & 1, h = r1 >> 6;                          // 0..2
        int q = lane >> 4, n16 = lane & 15;
        const float* src = net ? cmW1 : cgW1;
        v = src[((size_t)h * 64 + ks * 32 + q * 8 + j) * 256
                + chunk * 64 + nt * 16 + n16];
    } else if (tid < WALL_ELEMS) {
        int t2 = tid - (W1SW_ELEMS + W2SW_ELEMS + CW1_ELEMS);
        int j = t2 & 7, lane = (t2 >> 3) & 63;
        int r1 = t2 >> 9;                        // [h][ks2][nt]
        int nt = r1 & 3, ks2 = (r1 >> 2) & 7, h = r1 >> 5;             // 0..2
        int q = lane >> 4, n16 = lane & 15;
        v = cmW2[((size_t)h * 256 + ks2 * 32 + q * 8 + j) * 64 + nt * 16 + n16];
    } else {
        // embed W: frag(lane=(q,n16), j) = embW[row = kk*32+q*8+j][col = nt*16+n16]
        int t2 = tid - WALL_ELEMS;
        int j = t2 & 7, lane = (t2 >> 3) & 63;
        int r1 = t2 >> 9;                        // [kk][nt]
        int nt = r1 & 3, kk = r1 >> 2;                                 // 0..6
        int q = lane >> 4, n16 = lane & 15;
        int row = kk * 32 + q * 8 + j, col = nt * 16 + n16;
        v = (row < EMBD && col < F - 1) ? embW[(size_t)row * (F - 1) + col] : 0.f;
    }
    Wall[tid] = (_Float16)v;
}

// ---------------------------------------------------------------------------
// Fallback: per-layer prep into d_out scratch (round-4 proven).
// ---------------------------------------------------------------------------
__global__ __launch_bounds__(256)
void prep_layer(const float* __restrict__ gW1, const float* __restrict__ mW1,
                const float* __restrict__ mW2,
                _Float16* __restrict__ W1sw, _Float16* __restrict__ W2sw, int l)
{
    int tid = blockIdx.x * 256 + threadIdx.x;
    if (tid < W1L_ELEMS) {
        int j = tid & 7, lane = (tid >> 3) & 63;
        int r1 = tid >> 9;
        int ks = r1 & 1, nt = (r1 >> 1) & 3, chunk = (r1 >> 3) & 3;
        int half = (r1 >> 5) & 1, net = (r1 >> 6) & 1, hh = r1 >> 7;
        int q = lane >> 4, n16 = lane & 15;
        const float* src = net ? mW1 : gW1;
        float v = src[((size_t)(l * NH + hh) * 128 + half * 64 + ks * 32 + q * 8 + j) * 256
                      + chunk * 64 + nt * 16 + n16];
        W1sw[tid] = (_Float16)v;
    } else {
        int t2 = tid - W1L_ELEMS;
        if (t2 < W2L_ELEMS) {
            int j = t2 & 7, lane = (t2 >> 3) & 63;
            int r1 = t2 >> 9;
            int nt = r1 & 3, ks2 = (r1 >> 2) & 7, hh = r1 >> 5;
            int q = lane >> 4, n16 = lane & 15;
            float v = mW2[((size_t)(l * NH + hh) * 256 + ks2 * 32 + q * 8 + j) * 64
                          + nt * 16 + n16];
            W2sw[t2] = (_Float16)v;
        }
    }
}

// ---------------------------------------------------------------------------
// Embedding — round-0 proven; used by FALLBACK path only (fast path fuses it).
// ---------------------------------------------------------------------------
__global__ __launch_bounds__(64)
void embed_kernel(const float* __restrict__ fea, const float* __restrict__ W,
                  const float* __restrict__ b, const float* __restrict__ wts,
                  float* __restrict__ x)
{
    int n = blockIdx.x;
    int o = threadIdx.x;
    __shared__ float fs[EMBD];
    for (int e = o; e < EMBD; e += 64) fs[e] = fea[n * EMBD + e];
    __syncthreads();
    if (o < F - 1) {
        float acc = b[o];
#pragma unroll 8
        for (int e = 0; e < EMBD; ++e) acc += fs[e] * W[e * (F - 1) + o];
        x[n * F + o] = acc;
    } else {
        x[n * F + F - 1] = wts[n];
    }
}

// ---------------------------------------------------------------------------
// Round 18: net_wave — FUSED embed + 3 layers + pool in ONE dispatch.
// Embed is matmul-shaped ([15 nodes x 200] @ [200 x 63] per wave): done with
// 7 kstep x 4 nt transposed MFMAs (mfma(Wf, feaFrag) -> D[o][node], same lane
// algebra as stage-1; a B-frag of M is an A-frag of M^T so the established
// swizzle carries over). Kills the 50000-block embed dispatch (~70 us of L2 W
// streaming) and x entirely. Bias via clamped scalar loads; col 63 <- wts;
// results staged through fp32 LDS xF to build xcur + A-frags (same rebuild
// path as the inter-layer residual). l-loop rolled (unroll spills, r13).
// ---------------------------------------------------------------------------
#define WAVE_LDS 12288   // bytes per wave slice
#define XFS 68           // xF row stride (floats); 272 B = 16-aligned

__global__ __launch_bounds__(256, 2)
void net_wave(const float* __restrict__ fea, const float* __restrict__ embB,
              const _Float16* __restrict__ embWsw,
              const _Float16* __restrict__ W1sw,
              const _Float16* __restrict__ W2sw,
              const float* __restrict__ gb1, const float* __restrict__ gb2v,
              const float* __restrict__ mb1, const float* __restrict__ mb2,
              const float* __restrict__ gW2, const float* __restrict__ gpw,
              const _Float16* __restrict__ cW1sw,
              const _Float16* __restrict__ cW2sw,
              const float* __restrict__ cgb1, const float* __restrict__ cgb2v,
              const float* __restrict__ cmb1, const float* __restrict__ cmb2,
              const float* __restrict__ cgW2, const float* __restrict__ cpw,
              const float* __restrict__ wts, float* __restrict__ out, int Ntot)
{
    __shared__ __align__(16) char smem[4 * WAVE_LDS];

    const int t = threadIdx.x, w = t >> 6, lane = t & 63;
    const int q = lane >> 4, m16 = lane & 15;

    char* wb = smem + w * WAVE_LDS;
    _Float16 (*PQ)[16][72] = (_Float16 (*)[16][72])wb;   // [4][16][72] = 9216 B
    _Float16 (*msgL)[72]   = (_Float16 (*)[72])wb;       // [80][72] (aliases PQ)
    _Float16 (*xS)[72]     = (_Float16 (*)[72])(wb + 9216); // [16][72] A-rebuild buf
    float* gateS  = (float*)(wb + 11520);                // [80]
    float* anormS = (float*)(wb + 11840);                // [80]
    float* wpowS  = (float*)(wb + 12160);                // [16]

    const int nw0 = (blockIdx.x * 12 + w * CW) * K;      // first node of this wave
    const int c0  = blockIdx.x * 12 + w * CW;            // first crystal
    const int Ctot = Ntot / K;
    const int vc  = (Ctot - c0 < CW) ? (Ctot - c0) : CW;

    // ======================= fused embed =======================
    // xF[node][o] fp32 lives in the (currently dead) PQ region.
    float* xF = (float*)wb;
    {
        int arow = nw0 + m16;
        if (arow > Ntot - 1) arow = Ntot - 1;            // clamp pad rows
        if (arow < 0) arow = 0;
        const float* fr = fea + (size_t)arow * EMBD;
        f32x4 accE[4];
#pragma unroll
        for (int nt = 0; nt < 4; ++nt) accE[nt] = (f32x4){0.f, 0.f, 0.f, 0.f};
#pragma unroll
        for (int kk = 0; kk < 7; ++kk) {
            half8 Bf;
            if (kk < 6 || q == 0) {                      // kk==6,q>=1 -> cols>=200
                float4 f0 = *(const float4*)(fr + kk * 32 + q * 8);
                float4 f1 = *(const float4*)(fr + kk * 32 + q * 8 + 4);
                Bf[0]=(_Float16)f0.x; Bf[1]=(_Float16)f0.y;
                Bf[2]=(_Float16)f0.z; Bf[3]=(_Float16)f0.w;
                Bf[4]=(_Float16)f1.x; Bf[5]=(_Float16)f1.y;
                Bf[6]=(_Float16)f1.z; Bf[7]=(_Float16)f1.w;
            } else Bf = 0;
#pragma unroll
            for (int nt = 0; nt < 4; ++nt) {
                half8 Wf = *(const half8*)(embWsw + ((size_t)(kk * 4 + nt) * 64 + lane) * 8);
                accE[nt] = __builtin_amdgcn_mfma_f32_16x16x32_f16(Wf, Bf, accE[nt], 0, 0, 0);
            }
        }
        const float wv = wts[arow];
#pragma unroll
        for (int nt = 0; nt < 4; ++nt)
#pragma unroll
            for (int rg = 0; rg < 4; ++rg) {
                int o = nt * 16 + q * 4 + rg;
                float val = accE[nt][rg] + embB[o < F - 1 ? o : F - 2];
                if (o == F - 1) val = wv;                // weight column
                xF[m16 * XFS + o] = val;
            }
    }

    // residual copy (col=lane) + initial A-frags, both from xF
    float xcur[NWN];
#pragma unroll
    for (int n = 0; n < NWN; ++n) xcur[n] = xF[n * XFS + lane];
    half8 A[2];
#pragma unroll
    for (int ks = 0; ks < 2; ++ks) {
        float4 f0 = *(const float4*)&xF[m16 * XFS + ks * 32 + q * 8];
        float4 f1 = *(const float4*)&xF[m16 * XFS + ks * 32 + q * 8 + 4];
        half8 a;
        a[0] = (_Float16)f0.x; a[1] = (_Float16)f0.y;
        a[2] = (_Float16)f0.z; a[3] = (_Float16)f0.w;
        a[4] = (_Float16)f1.x; a[5] = (_Float16)f1.y;
        a[6] = (_Float16)f1.z; a[7] = (_Float16)f1.w;
        A[ks] = a;
    }

    // ---- per-lane edge -> local node rows (75 valid edges in 5 tiles of 16) ----
    int iR[ET], jR[ET];
#pragma unroll
    for (int et = 0; et < ET; ++et) {
        int e = et * 16 + m16;
        if (e < EWE) {
            int cl = e / 25, rm = e % 25;
            iR[et] = cl * K + rm / K;
            jR[et] = cl * K + rm % K;
        } else { iR[et] = 15; jR[et] = 15; }             // pad row (finite)
    }

    // ======================= 3 graph layers (rolled) =======================
#pragma clang loop unroll(disable)
    for (int l = 0; l < NL; ++l) {
        float oacc[NWN];
#pragma unroll
        for (int n = 0; n < NWN; ++n) oacc[n] = 0.f;

        for (int h = 0; h < NH; ++h) {
            const int lh = l * NH + h, lhw = lh;

            if (lane < NWN) {
                int wi = nw0 + lane;
                if (wi > Ntot - 1) wi = Ntot - 1;
                if (wi < 0) wi = 0;
                wpowS[lane] = powf(wts[wi], gpw[lh]);
            }
            if (lane >= NWN && lane < NWN + 5) anormS[EWE + (lane - NWN)] = 0.f;

            f32x4 acc2[ET][4];
#pragma unroll
            for (int et = 0; et < ET; ++et)
#pragma unroll
                for (int nt = 0; nt < 4; ++nt) acc2[et][nt] = (f32x4){0.f, 0.f, 0.f, 0.f};
            float gacc[ET] = {0.f, 0.f, 0.f, 0.f, 0.f};

            for (int c = 0; c < 4; ++c) {
                // ---- GEMM2 B-frags for this chunk ----
                half8 B2[8];
                {
                    const _Float16* W2b = W2sw + ((size_t)lhw * 8 + c * 2) * 2048;
#pragma unroll
                    for (int f = 0; f < 8; ++f)
                        B2[f] = *(const half8*)(W2b + ((size_t)f * 64 + lane) * 8);
                }

                // ---- stage-1: 4 net-halves, transposed mfma -> packed writes ----
#pragma unroll
                for (int hf = 0; hf < 4; ++hf) {
                    f32x4 accS[4];
#pragma unroll
                    for (int nt = 0; nt < 4; ++nt) accS[nt] = (f32x4){0.f, 0.f, 0.f, 0.f};
                    const _Float16* Wb = W1sw + ((size_t)lhw * 4 + hf) * 16384 + c * 4096;
#pragma unroll
                    for (int nt = 0; nt < 4; ++nt)
#pragma unroll
                        for (int ks = 0; ks < 2; ++ks) {
                            half8 B = *(const half8*)(Wb + ((nt * 2 + ks) * 64 + lane) * 8);
                            accS[nt] = __builtin_amdgcn_mfma_f32_16x16x32_f16(
                                B, A[ks], accS[nt], 0, 0, 0);
                        }
#pragma unroll
                    for (int nt = 0; nt < 4; ++nt) {
                        h2 lo = cvt_pk(accS[nt][0], accS[nt][1]);
                        h2 hi = cvt_pk(accS[nt][2], accS[nt][3]);
                        h4 pk = __builtin_shufflevector(lo, hi, 0, 1, 2, 3);
                        *(h4*)&PQ[hf][m16][nt * 16 + q * 4] = pk;
                    }
                }

                // ---- per-chunk bias slices; wg packed to f16 ----
                half8 bg8[2], bm8[2];
                h2 wgh2[2][4];
#pragma unroll
                for (int ks = 0; ks < 2; ++ks) {
                    const int ub = c * 64 + ks * 32 + q * 8;
                    float4 g0 = *(const float4*)(gb1 + (size_t)lh * HID + ub);
                    float4 g1 = *(const float4*)(gb1 + (size_t)lh * HID + ub + 4);
                    float4 m0 = *(const float4*)(mb1 + (size_t)lh * HID + ub);
                    float4 m1 = *(const float4*)(mb1 + (size_t)lh * HID + ub + 4);
                    float4 w0 = *(const float4*)(gW2 + (size_t)lh * HID + ub);
                    float4 w1 = *(const float4*)(gW2 + (size_t)lh * HID + ub + 4);
                    half8 bg, bm;
                    bg[0]=(_Float16)g0.x; bg[1]=(_Float16)g0.y; bg[2]=(_Float16)g0.z; bg[3]=(_Float16)g0.w;
                    bg[4]=(_Float16)g1.x; bg[5]=(_Float16)g1.y; bg[6]=(_Float16)g1.z; bg[7]=(_Float16)g1.w;
                    bm[0]=(_Float16)m0.x; bm[1]=(_Float16)m0.y; bm[2]=(_Float16)m0.z; bm[3]=(_Float16)m0.w;
                    bm[4]=(_Float16)m1.x; bm[5]=(_Float16)m1.y; bm[6]=(_Float16)m1.z; bm[7]=(_Float16)m1.w;
                    bg8[ks] = bg; bm8[ks] = bm;
                    wgh2[ks][0] = cvt_pk(w0.x, w0.y);
                    wgh2[ks][1] = cvt_pk(w0.z, w0.w);
                    wgh2[ks][2] = cvt_pk(w1.x, w1.y);
                    wgh2[ks][3] = cvt_pk(w1.z, w1.w);
                }

                // ---- consume: gate fdot2 + hm A-frags + GEMM2 ----
#pragma unroll
                for (int et = 0; et < ET; ++et) {
                    half8 af[2];
#pragma unroll
                    for (int ks = 0; ks < 2; ++ks) {
                        const int ub = ks * 32 + q * 8;
                        half8 pg = *(const half8*)&PQ[0][iR[et]][ub];
                        half8 qg = *(const half8*)&PQ[1][jR[et]][ub];
                        half8 pm = *(const half8*)&PQ[2][iR[et]][ub];
                        half8 qm = *(const half8*)&PQ[3][jR[et]][ub];
                        half8 tg = lrelu8(pg + qg + bg8[ks]);
                        h2 t01 = __builtin_shufflevector(tg, tg, 0, 1);
                        h2 t23 = __builtin_shufflevector(tg, tg, 2, 3);
                        h2 t45 = __builtin_shufflevector(tg, tg, 4, 5);
                        h2 t67 = __builtin_shufflevector(tg, tg, 6, 7);
                        gacc[et] = __builtin_amdgcn_fdot2(t01, wgh2[ks][0], gacc[et], false);
                        gacc[et] = __builtin_amdgcn_fdot2(t23, wgh2[ks][1], gacc[et], false);
                        gacc[et] = __builtin_amdgcn_fdot2(t45, wgh2[ks][2], gacc[et], false);
                        gacc[et] = __builtin_amdgcn_fdot2(t67, wgh2[ks][3], gacc[et], false);
                        af[ks] = lrelu8(pm + qm + bm8[ks]);
                    }
#pragma unroll
                    for (int nt = 0; nt < 4; ++nt)
#pragma unroll
                        for (int ks = 0; ks < 2; ++ks)
                            acc2[et][nt] = __builtin_amdgcn_mfma_f32_16x16x32_f16(
                                af[ks], B2[ks * 4 + nt], acc2[et][nt], 0, 0, 0);
                }
            }

            // ---- gate reduce across quads ----
            const float gb2s = gb2v[lh];
#pragma unroll
            for (int et = 0; et < ET; ++et) {
                float g = gacc[et];
                g += __shfl_xor(g, 16);
                g += __shfl_xor(g, 32);
                if (q == 0) gateS[et * 16 + m16] = g + gb2s;
            }

            // ---- segment softmax ----
            if (lane < NWN) {
                const int cl5 = (lane / K) * K;
                float gg[K], mx = -1e30f;
#pragma unroll
                for (int jj = 0; jj < K; ++jj) {
                    gg[jj] = gateS[lane * K + jj];
                    mx = fmaxf(mx, gg[jj]);
                }
                float s = 0.f, wv[K];
#pragma unroll
                for (int jj = 0; jj < K; ++jj) {
                    wv[jj] = wpowS[cl5 + jj] * expf(gg[jj] - mx);
                    s += wv[jj];
                }
                float inv = 1.f / (s + 1e-10f) * (1.f / 3.f);  // fold head mean
#pragma unroll
                for (int jj = 0; jj < K; ++jj) anormS[lane * K + jj] = wv[jj] * inv;
            }

            // ---- weighted msg -> msgL ----
            float b2v[4];
#pragma unroll
            for (int nt = 0; nt < 4; ++nt) b2v[nt] = mb2[(size_t)lh * F + nt * 16 + m16];
#pragma unroll
            for (int et = 0; et < ET; ++et) {
                f32x4 an = *(const f32x4*)&anormS[et * 16 + q * 4];
#pragma unroll
                for (int nt = 0; nt < 4; ++nt)
#pragma unroll
                    for (int rg = 0; rg < 4; ++rg) {
                        float v = (acc2[et][nt][rg] + b2v[nt]) * an[rg];
                        msgL[et * 16 + q * 4 + rg][nt * 16 + m16] = (_Float16)v;
                    }
            }

            // ---- aggregate ----
#pragma unroll
            for (int n = 0; n < NWN; ++n) {
                float s = 0.f;
#pragma unroll
                for (int jj = 0; jj < K; ++jj) s += (float)msgL[n * K + jj][lane];
                oacc[n] += s;
            }
        }

        // ---- residual in regs + A-frag rebuild via xS (dead region) ----
#pragma unroll
        for (int n = 0; n < NWN; ++n) {
            float xn = oacc[n] + xcur[n];
            xcur[n] = xn;
            xS[n][lane] = (_Float16)xn;
        }
        xS[15][lane] = (_Float16)0.f;                    // pad row finite
#pragma unroll
        for (int ks = 0; ks < 2; ++ks)
            A[ks] = *(const half8*)&xS[m16][ks * 32 + q * 8];
    }

    // ======================= pool (round-15 proven body) =======================
    _Float16 (*PQp)[16][72] = (_Float16 (*)[16][72])wb;  // [2][16][72]
    _Float16 (*msgP)[72]    = (_Float16 (*)[72])wb;      // [16][72] (aliases PQp)

    float oaccP[CW] = {0.f, 0.f, 0.f};

    for (int h = 0; h < NH; ++h) {
        if (lane < NWN) {
            int wi = nw0 + lane;
            if (wi > Ntot - 1) wi = Ntot - 1;
            if (wi < 0) wi = 0;
            wpowS[lane] = powf(wts[wi], cpw[h]);
        }
        if (lane == NWN) anormS[15] = 0.f;               // pad node row

        f32x4 acc2[4];
#pragma unroll
        for (int nt = 0; nt < 4; ++nt) acc2[nt] = (f32x4){0.f, 0.f, 0.f, 0.f};
        float gacc = 0.f;

        for (int c = 0; c < 4; ++c) {
            half8 B2[8];
            {
                const _Float16* W2b = cW2sw + (size_t)h * 16384 + c * 4096;
#pragma unroll
                for (int f = 0; f < 8; ++f)
                    B2[f] = *(const half8*)(W2b + ((size_t)f * 64 + lane) * 8);
            }

#pragma unroll
            for (int net = 0; net < 2; ++net) {
                f32x4 accS[4];
#pragma unroll
                for (int nt = 0; nt < 4; ++nt) accS[nt] = (f32x4){0.f, 0.f, 0.f, 0.f};
                const _Float16* Wb = cW1sw + ((size_t)(h * 2 + net) * 4 + c) * 4096;
#pragma unroll
                for (int nt = 0; nt < 4; ++nt)
#pragma unroll
                    for (int ks = 0; ks < 2; ++ks) {
                        half8 B = *(const half8*)(Wb + ((nt * 2 + ks) * 64 + lane) * 8);
                        accS[nt] = __builtin_amdgcn_mfma_f32_16x16x32_f16(
                            B, A[ks], accS[nt], 0, 0, 0);
                    }
#pragma unroll
                for (int nt = 0; nt < 4; ++nt) {
                    h2 lo = cvt_pk(accS[nt][0], accS[nt][1]);
                    h2 hi = cvt_pk(accS[nt][2], accS[nt][3]);
                    h4 pk = __builtin_shufflevector(lo, hi, 0, 1, 2, 3);
                    *(h4*)&PQp[net][m16][nt * 16 + q * 4] = pk;
                }
            }

            half8 bg8[2], bm8[2];
            h2 wgh2[2][4];
#pragma unroll
            for (int ks = 0; ks < 2; ++ks) {
                const int ub = c * 64 + ks * 32 + q * 8;
                float4 g0 = *(const float4*)(cgb1 + (size_t)h * HID + ub);
                float4 g1 = *(const float4*)(cgb1 + (size_t)h * HID + ub + 4);
                float4 m0 = *(const float4*)(cmb1 + (size_t)h * HID + ub);
                float4 m1 = *(const float4*)(cmb1 + (size_t)h * HID + ub + 4);
                float4 w0 = *(const float4*)(cgW2 + (size_t)h * HID + ub);
                float4 w1 = *(const float4*)(cgW2 + (size_t)h * HID + ub + 4);
                half8 bg, bm;
                bg[0]=(_Float16)g0.x; bg[1]=(_Float16)g0.y; bg[2]=(_Float16)g0.z; bg[3]=(_Float16)g0.w;
                bg[4]=(_Float16)g1.x; bg[5]=(_Float16)g1.y; bg[6]=(_Float16)g1.z; bg[7]=(_Float16)g1.w;
                bm[0]=(_Float16)m0.x; bm[1]=(_Float16)m0.y; bm[2]=(_Float16)m0.z; bm[3]=(_Float16)m0.w;
                bm[4]=(_Float16)m1.x; bm[5]=(_Float16)m1.y; bm[6]=(_Float16)m1.z; bm[7]=(_Float16)m1.w;
                bg8[ks] = bg; bm8[ks] = bm;
                wgh2[ks][0] = cvt_pk(w0.x, w0.y);
                wgh2[ks][1] = cvt_pk(w0.z, w0.w);
                wgh2[ks][2] = cvt_pk(w1.x, w1.y);
                wgh2[ks][3] = cvt_pk(w1.z, w1.w);
            }

            {
                half8 af[2];
#pragma unroll
                for (int ks = 0; ks < 2; ++ks) {
                    const int ub = ks * 32 + q * 8;
                    half8 pg = *(const half8*)&PQp[0][m16][ub];
                    half8 pm = *(const half8*)&PQp[1][m16][ub];
                    half8 tg = lrelu8(pg + bg8[ks]);
                    h2 t01 = __builtin_shufflevector(tg, tg, 0, 1);
                    h2 t23 = __builtin_shufflevector(tg, tg, 2, 3);
                    h2 t45 = __builtin_shufflevector(tg, tg, 4, 5);
                    h2 t67 = __builtin_shufflevector(tg, tg, 6, 7);
                    gacc = __builtin_amdgcn_fdot2(t01, wgh2[ks][0], gacc, false);
                    gacc = __builtin_amdgcn_fdot2(t23, wgh2[ks][1], gacc, false);
                    gacc = __builtin_amdgcn_fdot2(t45, wgh2[ks][2], gacc, false);
                    gacc = __builtin_amdgcn_fdot2(t67, wgh2[ks][3], gacc, false);
                    af[ks] = lrelu8(pm + bm8[ks]);
                }
#pragma unroll
                for (int nt = 0; nt < 4; ++nt)
#pragma unroll
                    for (int ks = 0; ks < 2; ++ks)
                        acc2[nt] = __builtin_amdgcn_mfma_f32_16x16x32_f16(
                            af[ks], B2[ks * 4 + nt], acc2[nt], 0, 0, 0);
            }
        }

        const float gb2s = cgb2v[h];
        {
            float g = gacc;
            g += __shfl_xor(g, 16);
            g += __shfl_xor(g, 32);
            if (q == 0) gateS[m16] = g + gb2s;
        }

        if (lane < CW) {
            const int n0 = lane * K;
            float gg[K], mx = -1e30f;
#pragma unroll
            for (int jj = 0; jj < K; ++jj) {
                gg[jj] = gateS[n0 + jj];
                mx = fmaxf(mx, gg[jj]);
            }
            float s = 0.f, wv[K];
#pragma unroll
            for (int jj = 0; jj < K; ++jj) {
                wv[jj] = wpowS[n0 + jj] * expf(gg[jj] - mx);
                s += wv[jj];
            }
            float inv = 1.f / (s + 1e-10f) * (1.f / 3.f);
#pragma unroll
            for (int jj = 0; jj < K; ++jj) anormS[n0 + jj] = wv[jj] * inv;
        }

        float b2v[4];
#pragma unroll
        for (int nt = 0; nt < 4; ++nt) b2v[nt] = cmb2[(size_t)h * F + nt * 16 + m16];
#pragma unroll
        for (int nt = 0; nt < 4; ++nt)
#pragma unroll
            for (int rg = 0; rg < 4; ++rg) {
                int row = q * 4 + rg;
                float v = (acc2[nt][rg] + b2v[nt]) * anormS[row];
                msgP[row][nt * 16 + m16] = (_Float16)v;
            }

#pragma unroll
        for (int cl = 0; cl < CW; ++cl) {
            float s = 0.f;
#pragma unroll
            for (int jj = 0; jj < K; ++jj) s += (float)msgP[cl * K + jj][lane];
            oaccP[cl] += s;
        }
    }

#pragma unroll
    for (int cl = 0; cl < CW; ++cl)
        if (cl < vc)
            out[(size_t)(c0 + cl) * F + lane] = oaccP[cl];
}

// ---------------------------------------------------------------------------
// Fallback layer kernel (round-12 proven, writes x) — used when ws too small.
// ---------------------------------------------------------------------------
__global__ __launch_bounds__(256, 2)
void layer_wave(float* __restrict__ x,
                const _Float16* __restrict__ W1sw,
                const _Float16* __restrict__ W2sw,
                const float* __restrict__ gb1, const float* __restrict__ gb2v,
                const float* __restrict__ mb1, const float* __restrict__ mb2,
                const float* __restrict__ gW2, const float* __restrict__ gpw,
                const float* __restrict__ wts, int l, int lhw0, int Ntot)
{
    __shared__ __align__(16) char smem[4 * WAVE_LDS];

    const int t = threadIdx.x, w = t >> 6, lane = t & 63;
    const int q = lane >> 4, m16 = lane & 15;

    char* wb = smem + w * WAVE_LDS;
    _Float16 (*PQ)[16][72] = (_Float16 (*)[16][72])wb;
    _Float16 (*msgL)[72]   = (_Float16 (*)[72])wb;
    float* gateS  = (float*)(wb + 11520);
    float* anormS = (float*)(wb + 11840);
    float* wpowS  = (float*)(wb + 12160);

    const int nw0 = (blockIdx.x * 12 + w * CW) * K;
    const int vn  = (Ntot - nw0 < NWN) ? (Ntot - nw0) : NWN;

    half8 A[2];
    {
        int arow = nw0 + m16;
        if (arow > Ntot - 1) arow = Ntot - 1;
        if (arow < 0) arow = 0;
        const float* xr = x + (size_t)arow * F;
#pragma unroll
        for (int ks = 0; ks < 2; ++ks) {
            float4 f0 = *(const float4*)(xr + ks * 32 + q * 8);
            float4 f1 = *(const float4*)(xr + ks * 32 + q * 8 + 4);
            half8 a;
            a[0] = (_Float16)f0.x; a[1] = (_Float16)f0.y;
            a[2] = (_Float16)f0.z; a[3] = (_Float16)f0.w;
            a[4] = (_Float16)f1.x; a[5] = (_Float16)f1.y;
            a[6] = (_Float16)f1.z; a[7] = (_Float16)f1.w;
            A[ks] = a;
        }
    }

    int iR[ET], jR[ET];
#pragma unroll
    for (int et = 0; et < ET; ++et) {
        int e = et * 16 + m16;
        if (e < EWE) {
            int cl = e / 25, rm = e % 25;
            iR[et] = cl * K + rm / K;
            jR[et] = cl * K + rm % K;
        } else { iR[et] = 15; jR[et] = 15; }
    }

    float oacc[NWN];
#pragma unroll
    for (int n = 0; n < NWN; ++n) oacc[n] = 0.f;

    for (int h = 0; h < NH; ++h) {
        const int lh = l * NH + h, lhw = lhw0 + h;

        if (lane < NWN) {
            int wi = nw0 + lane;
            if (wi > Ntot - 1) wi = Ntot - 1;
            if (wi < 0) wi = 0;
            wpowS[lane] = powf(wts[wi], gpw[lh]);
        }
        if (lane >= NWN && lane < NWN + 5) anormS[EWE + (lane - NWN)] = 0.f;

        f32x4 acc2[ET][4];
#pragma unroll
        for (int et = 0; et < ET; ++et)
#pragma unroll
            for (int nt = 0; nt < 4; ++nt) acc2[et][nt] = (f32x4){0.f, 0.f, 0.f, 0.f};
        float gacc[ET] = {0.f, 0.f, 0.f, 0.f, 0.f};

        for (int c = 0; c < 4; ++c) {
            half8 B2[8];
            {
                const _Float16* W2b = W2sw + ((size_t)lhw * 8 + c * 2) * 2048;
#pragma unroll
                for (int f = 0; f < 8; ++f)
                    B2[f] = *(const half8*)(W2b + ((size_t)f * 64 + lane) * 8);
            }

#pragma unroll
            for (int hf = 0; hf < 4; ++hf) {
                f32x4 accS[4];
#pragma unroll
                for (int nt = 0; nt < 4; ++nt) accS[nt] = (f32x4){0.f, 0.f, 0.f, 0.f};
                const _Float16* Wb = W1sw + ((size_t)lhw * 4 + hf) * 16384 + c * 4096;
#pragma unroll
                for (int nt = 0; nt < 4; ++nt)
#pragma unroll
                    for (int ks = 0; ks < 2; ++ks) {
                        half8 B = *(const half8*)(Wb + ((nt * 2 + ks) * 64 + lane) * 8);
                        accS[nt] = __builtin_amdgcn_mfma_f32_16x16x32_f16(
                            B, A[ks], accS[nt], 0, 0, 0);
                    }
#pragma unroll
                for (int nt = 0; nt < 4; ++nt) {
                    h2 lo = cvt_pk(accS[nt][0], accS[nt][1]);
                    h2 hi = cvt_pk(accS[nt][2], accS[nt][3]);
                    h4 pk = __builtin_shufflevector(lo, hi, 0, 1, 2, 3);
                    *(h4*)&PQ[hf][m16][nt * 16 + q * 4] = pk;
                }
            }

            half8 bg8[2], bm8[2];
            h2 wgh2[2][4];
#pragma unroll
            for (int ks = 0; ks < 2; ++ks) {
                const int ub = c * 64 + ks * 32 + q * 8;
                float4 g0 = *(const float4*)(gb1 + (size_t)lh * HID + ub);
                float4 g1 = *(const float4*)(gb1 + (size_t)lh * HID + ub + 4);
                float4 m0 = *(const float4*)(mb1 + (size_t)lh * HID + ub);
                float4 m1 = *(const float4*)(mb1 + (size_t)lh * HID + ub + 4);
                float4 w0 = *(const float4*)(gW2 + (size_t)lh * HID + ub);
                float4 w1 = *(const float4*)(gW2 + (size_t)lh * HID + ub + 4);
                half8 bg, bm;
                bg[0]=(_Float16)g0.x; bg[1]=(_Float16)g0.y; bg[2]=(_Float16)g0.z; bg[3]=(_Float16)g0.w;
                bg[4]=(_Float16)g1.x; bg[5]=(_Float16)g1.y; bg[6]=(_Float16)g1.z; bg[7]=(_Float16)g1.w;
                bm[0]=(_Float16)m0.x; bm[1]=(_Float16)m0.y; bm[2]=(_Float16)m0.z; bm[3]=(_Float16)m0.w;
                bm[4]=(_Float16)m1.x; bm[5]=(_Float16)m1.y; bm[6]=(_Float16)m1.z; bm[7]=(_Float16)m1.w;
                bg8[ks] = bg; bm8[ks] = bm;
                wgh2[ks][0] = cvt_pk(w0.x, w0.y);
                wgh2[ks][1] = cvt_pk(w0.z, w0.w);
                wgh2[ks][2] = cvt_pk(w1.x, w1.y);
                wgh2[ks][3] = cvt_pk(w1.z, w1.w);
            }

#pragma unroll
            for (int et = 0; et < ET; ++et) {
                half8 af[2];
#pragma unroll
                for (int ks = 0; ks < 2; ++ks) {
                    const int ub = ks * 32 + q * 8;
                    half8 pg = *(const half8*)&PQ[0][iR[et]][ub];
                    half8 qg = *(const half8*)&PQ[1][jR[et]][ub];
                    half8 pm = *(const half8*)&PQ[2][iR[et]][ub];
                    half8 qm = *(const half8*)&PQ[3][jR[et]][ub];
                    half8 tg = lrelu8(pg + qg + bg8[ks]);
                    h2 t01 = __builtin_shufflevector(tg, tg, 0, 1);
                    h2 t23 = __builtin_shufflevector(tg, tg, 2, 3);
                    h2 t45 = __builtin_shufflevector(tg, tg, 4, 5);
                    h2 t67 = __builtin_shufflevector(tg, tg, 6, 7);
                    gacc[et] = __builtin_amdgcn_fdot2(t01, wgh2[ks][0], gacc[et], false);
                    gacc[et] = __builtin_amdgcn_fdot2(t23, wgh2[ks][1], gacc[et], false);
                    gacc[et] = __builtin_amdgcn_fdot2(t45, wgh2[ks][2], gacc[et], false);
                    gacc[et] = __builtin_amdgcn_fdot2(t67, wgh2[ks][3], gacc[et], false);
                    af[ks] = lrelu8(pm + qm + bm8[ks]);
                }
#pragma unroll
                for (int nt = 0; nt < 4; ++nt)
#pragma unroll
                    for (int ks = 0; ks < 2; ++ks)
                        acc2[et][nt] = __builtin_amdgcn_mfma_f32_16x16x32_f16(
                            af[ks], B2[ks * 4 + nt], acc2[et][nt], 0, 0, 0);
            }
        }

        const float gb2s = gb2v[lh];
#pragma unroll
        for (int et = 0; et < ET; ++et) {
            float g = gacc[et];
            g += __shfl_xor(g, 16);
            g += __shfl_xor(g, 32);
            if (q == 0) gateS[et * 16 + m16] = g + gb2s;
        }

        if (lane < NWN) {
            const int cl5 = (lane / K) * K;
            float gg[K], mx = -1e30f;
#pragma unroll
            for (int jj = 0; jj < K; ++jj) {
                gg[jj] = gateS[lane * K + jj];
                mx = fmaxf(mx, gg[jj]);
            }
            float s = 0.f, wv[K];
#pragma unroll
            for (int jj = 0; jj < K; ++jj) {
                wv[jj] = wpowS[cl5 + jj] * expf(gg[jj] - mx);
                s += wv[jj];
            }
            float inv = 1.f / (s + 1e-10f) * (1.f / 3.f);
#pragma unroll
            for (int jj = 0; jj < K; ++jj) anormS[lane * K + jj] = wv[jj] * inv;
        }

        float b2v[4];
#pragma unroll
        for (int nt = 0; nt < 4; ++nt) b2v[nt] = mb2[(size_t)lh * F + nt * 16 + m16];
#pragma unroll
        for (int et = 0; et < ET; ++et) {
            f32x4 an = *(const f32x4*)&anormS[et * 16 + q * 4];
#pragma unroll
            for (int nt = 0; nt < 4; ++nt)
#pragma unroll
                for (int rg = 0; rg < 4; ++rg) {
                    float v = (acc2[et][nt][rg] + b2v[nt]) * an[rg];
                    msgL[et * 16 + q * 4 + rg][nt * 16 + m16] = (_Float16)v;
                }
        }

#pragma unroll
        for (int n = 0; n < NWN; ++n) {
            float s = 0.f;
#pragma unroll
            for (int jj = 0; jj < K; ++jj) s += (float)msgL[n * K + jj][lane];
            oacc[n] += s;
        }
    }

#pragma unroll
    for (int n = 0; n < NWN; ++n) {
        if (n < vn) {
            size_t idx = (size_t)(nw0 + n) * F + lane;
            x[idx] = oacc[n] + x[idx];
        }
    }
}

// ---------------------------------------------------------------------------
// Fallback fp32 pool (round-4 proven)
// ---------------------------------------------------------------------------
__global__ __launch_bounds__(256)
void pool_kernel(const float* __restrict__ x,
                 const float* __restrict__ cgW1, const float* __restrict__ cgb1,
                 const float* __restrict__ cgW2, const float* __restrict__ cgb2,
                 const float* __restrict__ cmW1, const float* __restrict__ cmb1,
                 const float* __restrict__ cmW2, const float* __restrict__ cmb2,
                 const float* __restrict__ cpw, const float* __restrict__ wts,
                 float* __restrict__ out)
{
    __shared__ float xs[K * F];
    __shared__ float hmS[K][HID];
    __shared__ float msgS[K][F];
    __shared__ float outacc[F];
    __shared__ float b1g[HID], b1m[HID], w2g[HID];
    __shared__ float b2mS[F];
    __shared__ float gpart[K][2];
    __shared__ float gate_s[K];
    __shared__ float anorm[K];
    __shared__ float wn[K], wpow[K];

    const int c = blockIdx.x;
    const int t = threadIdx.x;
    const int wave = t >> 6, lane = t & 63;

    for (int d = t; d < K * F; d += 256) xs[d] = x[c * K * F + d];
    if (t < F) outacc[t] = 0.f;
    if (t < K) wn[t] = wts[c * K + t];
    __syncthreads();

    for (int h = 0; h < NH; ++h) {
        if (t < HID) {
            b1g[t] = cgb1[(size_t)h * HID + t];
            b1m[t] = cmb1[(size_t)h * HID + t];
            w2g[t] = cgW2[(size_t)h * HID + t];
        }
        if (t < F) b2mS[t] = cmb2[(size_t)h * F + t];
        if (t < K) wpow[t] = powf(wn[t], cpw[h]);
        __syncthreads();

        {
            const int grp = t >> 7;
            const int up  = t & 127;
            const float* Wb = (grp == 0 ? cgW1 : cmW1) + (size_t)h * F * HID;
            const float2* W2p = (const float2*)Wb;
            float acc[K][2];
#pragma unroll
            for (int i = 0; i < K; ++i) { acc[i][0] = 0.f; acc[i][1] = 0.f; }
            for (int k = 0; k < F; ++k) {
                float2 wv = W2p[k * (HID / 2) + up];
#pragma unroll
                for (int i = 0; i < K; ++i) {
                    float xv = xs[i * F + k];
                    acc[i][0] += xv * wv.x;
                    acc[i][1] += xv * wv.y;
                }
            }
            if (grp == 0) {
#pragma unroll
                for (int i = 0; i < K; ++i) {
                    float h0 = lrelu(acc[i][0] + b1g[2 * up]);
                    float h1 = lrelu(acc[i][1] + b1g[2 * up + 1]);
                    float part = h0 * w2g[2 * up] + h1 * w2g[2 * up + 1];
#pragma unroll
                    for (int s = 32; s; s >>= 1) part += __shfl_xor(part, s);
                    if (lane == 0) gpart[i][wave & 1] = part;
                }
            } else {
#pragma unroll
                for (int i = 0; i < K; ++i) {
                    hmS[i][2 * up]     = lrelu(acc[i][0] + b1m[2 * up]);
                    hmS[i][2 * up + 1] = lrelu(acc[i][1] + b1m[2 * up + 1]);
                }
            }
        }
        __syncthreads();
        if (t < K) gate_s[t] = cgb2[h] + gpart[t][0] + gpart[t][1];

        {
            const float2* W232 = (const float2*)(cmW2 + (size_t)h * HID * F);
            if (t < K * (F / 2)) {
                int i  = t >> 5;
                int op = t & 31;
                float a0 = b2mS[2 * op], a1 = b2mS[2 * op + 1];
#pragma unroll 8
                for (int u = 0; u < HID; ++u) {
                    float2 wv = W232[u * (F / 2) + op];
                    float hv = hmS[i][u];
                    a0 += hv * wv.x;
                    a1 += hv * wv.y;
                }
                msgS[i][2 * op]     = a0;
                msgS[i][2 * op + 1] = a1;
            }
        }
        __syncthreads();

        if (t == 0) {
            float mx = -1e30f;
#pragma unroll
            for (int i = 0; i < K; ++i) mx = fmaxf(mx, gate_s[i]);
            float wv[K], s = 0.f;
#pragma unroll
            for (int i = 0; i < K; ++i) {
                wv[i] = wpow[i] * expf(gate_s[i] - mx);
                s += wv[i];
            }
            float inv = 1.f / (s + 1e-10f);
#pragma unroll
            for (int i = 0; i < K; ++i) anorm[i] = wv[i] * inv;
        }
        __syncthreads();

        if (t < F) {
            float s = 0.f;
#pragma unroll
            for (int i = 0; i < K; ++i) s += anorm[i] * msgS[i][t];
            outacc[t] += s * (1.f / 3.f);
        }
        __syncthreads();
    }

    if (t < F) out[(size_t)c * F + t] = outacc[t];
}

// ---------------------------------------------------------------------------
extern "C" void kernel_launch(void* const* d_in, const int* in_sizes, int n_in,
                              void* d_out, int out_size, void* d_ws, size_t ws_size,
                              hipStream_t stream)
{
    const float* wts  = (const float*)d_in[0];
    const float* fea  = (const float*)d_in[1];
    const float* embW = (const float*)d_in[6];
    const float* embB = (const float*)d_in[7];
    const float* gW1  = (const float*)d_in[8];
    const float* gb1  = (const float*)d_in[9];
    const float* gW2  = (const float*)d_in[10];
    const float* gb2  = (const float*)d_in[11];
    const float* mW1  = (const float*)d_in[12];
    const float* mb1  = (const float*)d_in[13];
    const float* mW2  = (const float*)d_in[14];
    const float* mb2  = (const float*)d_in[15];
    const float* gpw  = (const float*)d_in[16];
    const float* cgW1 = (const float*)d_in[17];
    const float* cgb1 = (const float*)d_in[18];
    const float* cgW2 = (const float*)d_in[19];
    const float* cgb2 = (const float*)d_in[20];
    const float* cmW1 = (const float*)d_in[21];
    const float* cmb1 = (const float*)d_in[22];
    const float* cmW2 = (const float*)d_in[23];
    const float* cmb2 = (const float*)d_in[24];
    const float* cpw  = (const float*)d_in[25];

    const int N = in_sizes[0];   // 50000
    const int C = N / K;         // 10000
    const int layer_blocks = (C + 11) / 12;   // 834 (tail block guarded)

    float* x = (float*)d_ws;                       // [N,F] fp32 (fallback only)
    const size_t xbytes = (size_t)N * F * 4;
    const size_t need = xbytes + (size_t)WALL2_ELEMS * 2;

    if (ws_size >= need) {
        // ---- fast path: prep + ONE fused network kernel (embed included) ----
        _Float16* Wall  = (_Float16*)((char*)d_ws + xbytes);
        _Float16* W1sw  = Wall;
        _Float16* W2sw  = Wall + W1SW_ELEMS;
        _Float16* cW1sw = Wall + W1SW_ELEMS + W2SW_ELEMS;
        _Float16* cW2sw = Wall + W1SW_ELEMS + W2SW_ELEMS + CW1_ELEMS;
        _Float16* eWsw  = Wall + WALL_ELEMS;

        prep_all<<<(WALL2_ELEMS + 255) / 256, 256, 0, stream>>>(
            gW1, mW1, mW2, cgW1, cmW1, cmW2, embW, Wall);
        net_wave<<<layer_blocks, 256, 0, stream>>>(
            fea, embB, eWsw, W1sw, W2sw, gb1, gb2, mb1, mb2, gW2, gpw,
            cW1sw, cW2sw, cgb1, cgb2, cmb1, cmb2, cgW2, cpw,
            wts, (float*)d_out, N);
    } else {
        // ---- fallback: embed + per-layer prep into d_out scratch ----
        embed_kernel<<<N, 64, 0, stream>>>(fea, embW, embB, wts, x);
        _Float16* W1sw = (_Float16*)d_out;
        _Float16* W2sw = (_Float16*)((char*)d_out + 393216);
        for (int l = 0; l < NL; ++l) {
            prep_layer<<<(W1L_ELEMS + W2L_ELEMS) / 256, 256, 0, stream>>>(
                gW1, mW1, mW2, W1sw, W2sw, l);
            layer_wave<<<layer_blocks, 256, 0, stream>>>(x, W1sw, W2sw,
                                                         gb1, gb2, mb1, mb2, gW2, gpw, wts,
                                                         l, 0, N);
        }
        pool_kernel<<<C, 256, 0, stream>>>(x, cgW1, cgb1, cgW2, cgb2,
                                           cmW1, cmb1, cmW2, cmb2, cpw, wts,
                                           (float*)d_out);
    }
}

// Round 12
// 627.209 us; speedup vs baseline: 2.2501x; 1.0771x over previous
//
#include <hip/hip_runtime.h>
#include <hip/hip_bf16.h>

#define K 5
#define F 64
#define EMBD 200
#define HID 256
#define NH 3
#define NL 3

// wave decomposition: 4 waves x 3 crystals = 12 crystals / block
#define CW 3            // crystals per wave
#define NWN (CW * K)    // 15 nodes per wave
#define EWE (CW * K * K) // 75 edges per wave
#define ET 5            // edge tiles of 16

typedef _Float16 half8 __attribute__((ext_vector_type(8)));
typedef _Float16 h2 __attribute__((ext_vector_type(2)));
typedef _Float16 h4 __attribute__((ext_vector_type(4)));
typedef __fp16 fp16x2 __attribute__((ext_vector_type(2)));
typedef float f32x4 __attribute__((ext_vector_type(4)));

__device__ __forceinline__ float lrelu(float v) { return v >= 0.f ? v : 0.01f * v; }

// cvt_pkrtz returns __fp16x2; bitcast to _Float16x2 (same bits, distinct clang types)
__device__ __forceinline__ h2 cvt_pk(float a, float b) {
    union { fp16x2 f; h2 h; } u;
    u.f = __builtin_amdgcn_cvt_pkrtz(a, b);
    return u.h;
}

__device__ __forceinline__ half8 lrelu8(half8 t) {
    half8 z = 0;
    half8 p = __builtin_elementwise_max(t, z);
    half8 n = __builtin_elementwise_min(t, z);
    return p + n * (_Float16)0.01f;
}

// ---- swizzled-weight element counts (fp16) ----
#define W1SW_ELEMS 589824    // 9 lh * 2 net * 2 half * 4 chunk * 4 nt * 2 ks * 64 * 8
#define W2SW_ELEMS 147456    // 9 lh * 8 ks2 * 4 nt * 64 * 8
#define CW1_ELEMS   98304    // 3 h * 2 net * 4 chunk * 4 nt * 2 ks * 64 * 8
#define CW2_ELEMS   49152    // 3 h * 8 ks2 * 4 nt * 64 * 8
#define WALL_ELEMS (W1SW_ELEMS + W2SW_ELEMS + CW1_ELEMS + CW2_ELEMS)  // 884736
// embed W swizzle: 7 ksteps (224 rows padded) * 4 nt * 64 lane * 8 j
#define EMBSW_ELEMS 14336
#define WALL2_ELEMS (WALL_ELEMS + EMBSW_ELEMS)   // 899072
// f16 bias/gate tables: layers 3 arrays x 9 lh x 256, pool 3 arrays x 3 h x 256
#define BIASH_ELEMS 9216
#define WALL3_ELEMS (WALL2_ELEMS + BIASH_ELEMS)  // 908288
// biasH section offsets (elements)
#define BH_GB1  0
#define BH_MB1  2304
#define BH_WG   4608
#define BH_CGB1 6912
#define BH_CMB1 7680
#define BH_CWG  8448

// per-layer (fallback) sizes
#define W1L_ELEMS 196608
#define W2L_ELEMS 49152

// ---------------------------------------------------------------------------
// Fast path: swizzle ALL weights (layers + pool + embed) fp32 -> fp16 frags,
// plus f16 bias/gate-W2 tables (round 19).
// ---------------------------------------------------------------------------
__global__ __launch_bounds__(256)
void prep_all(const float* __restrict__ gW1, const float* __restrict__ mW1,
              const float* __restrict__ mW2,
              const float* __restrict__ cgW1, const float* __restrict__ cmW1,
              const float* __restrict__ cmW2, const float* __restrict__ embW,
              const float* __restrict__ gb1, const float* __restrict__ mb1,
              const float* __restrict__ gW2, const float* __restrict__ cgb1,
              const float* __restrict__ cmb1, const float* __restrict__ cgW2,
              _Float16* __restrict__ Wall)
{
    int tid = blockIdx.x * 256 + threadIdx.x;
    if (tid >= WALL3_ELEMS) return;
    float v;
    if (tid < W1SW_ELEMS) {
        int j = tid & 7, lane = (tid >> 3) & 63;
        int r1 = tid >> 9;                       // [lh][net][half][chunk][nt][ks]
        int ks = r1 & 1, nt = (r1 >> 1) & 3, chunk = (r1 >> 3) & 3;
        int half = (r1 >> 5) & 1, net = (r1 >> 6) & 1, lh = r1 >> 7;   // 0..8
        int q = lane >> 4, n16 = lane & 15;
        const float* src = net ? mW1 : gW1;
        v = src[((size_t)lh * 128 + half * 64 + ks * 32 + q * 8 + j) * 256
                + chunk * 64 + nt * 16 + n16];
    } else if (tid < W1SW_ELEMS + W2SW_ELEMS) {
        int t2 = tid - W1SW_ELEMS;
        int j = t2 & 7, lane = (t2 >> 3) & 63;
        int r1 = t2 >> 9;                        // [lh][ks2][nt]
        int nt = r1 & 3, ks2 = (r1 >> 2) & 7, lh = r1 >> 5;            // 0..8
        int q = lane >> 4, n16 = lane & 15;
        v = mW2[((size_t)lh * 256 + ks2 * 32 + q * 8 + j) * 64 + nt * 16 + n16];
    } else if (tid < W1SW_ELEMS + W2SW_ELEMS + CW1_ELEMS) {
        int t2 = tid - (W1SW_ELEMS + W2SW_ELEMS);
        int j = t2 & 7, lane = (t2 >> 3) & 63;
        int r1 = t2 >> 9;                        // [h][net][chunk][nt][ks]
        int ks = r1 & 1, nt = (r1 >> 1) & 3, chunk = (r1 >> 3) & 3;
        int net = (r1 >> 5) & 1, h = r1 >> 6;                          // 0..2
        int q = lane >> 4, n16 = lane & 15;
        const float* src = net ? cmW1 : cgW1;
        v = src[((size_t)h * 64 + ks * 32 + q * 8 + j) * 256
                + chunk * 64 + nt * 16 + n16];
    } else if (tid < WALL_ELEMS) {
        int t2 = tid - (W1SW_ELEMS + W2SW_ELEMS + CW1_ELEMS);
        int j = t2 & 7, lane = (t2 >> 3) & 63;
        int r1 = t2 >> 9;                        // [h][ks2][nt]
        int nt = r1 & 3, ks2 = (r1 >> 2) & 7, h = r1 >> 5;             // 0..2
        int q = lane >> 4, n16 = lane & 15;
        v = cmW2[((size_t)h * 256 + ks2 * 32 + q * 8 + j) * 64 + nt * 16 + n16];
    } else if (tid < WALL2_ELEMS) {
        // embed W: frag(lane=(q,n16), j) = embW[row = kk*32+q*8+j][col = nt*16+n16]
        int t2 = tid - WALL_ELEMS;
        int j = t2 & 7, lane = (t2 >> 3) & 63;
        int r1 = t2 >> 9;                        // [kk][nt]
        int nt = r1 & 3, kk = r1 >> 2;                                 // 0..6
        int q = lane >> 4, n16 = lane & 15;
        int row = kk * 32 + q * 8 + j, col = nt * 16 + n16;
        v = (row < EMBD && col < F - 1) ? embW[(size_t)row * (F - 1) + col] : 0.f;
    } else {
        // f16 bias/gate-W2 tables (straight copies)
        int t3 = tid - WALL2_ELEMS;
        if (t3 < 6912) {
            int arr = t3 / 2304, idx = t3 % 2304;                      // lh*256+u
            const float* s = arr == 0 ? gb1 : arr == 1 ? mb1 : gW2;
            v = s[idx];
        } else {
            int t4 = t3 - 6912;
            int arr = t4 / 768, idx = t4 % 768;                        // h*256+u
            const float* s = arr == 0 ? cgb1 : arr == 1 ? cmb1 : cgW2;
            v = s[idx];
        }
    }
    Wall[tid] = (_Float16)v;
}

// ---------------------------------------------------------------------------
// Fallback: per-layer prep into d_out scratch (round-4 proven).
// ---------------------------------------------------------------------------
__global__ __launch_bounds__(256)
void prep_layer(const float* __restrict__ gW1, const float* __restrict__ mW1,
                const float* __restrict__ mW2,
                _Float16* __restrict__ W1sw, _Float16* __restrict__ W2sw, int l)
{
    int tid = blockIdx.x * 256 + threadIdx.x;
    if (tid < W1L_ELEMS) {
        int j = tid & 7, lane = (tid >> 3) & 63;
        int r1 = tid >> 9;
        int ks = r1 & 1, nt = (r1 >> 1) & 3, chunk = (r1 >> 3) & 3;
        int half = (r1 >> 5) & 1, net = (r1 >> 6) & 1, hh = r1 >> 7;
        int q = lane >> 4, n16 = lane & 15;
        const float* src = net ? mW1 : gW1;
        float v = src[((size_t)(l * NH + hh) * 128 + half * 64 + ks * 32 + q * 8 + j) * 256
                      + chunk * 64 + nt * 16 + n16];
        W1sw[tid] = (_Float16)v;
    } else {
        int t2 = tid - W1L_ELEMS;
        if (t2 < W2L_ELEMS) {
            int j = t2 & 7, lane = (t2 >> 3) & 63;
            int r1 = t2 >> 9;
            int nt = r1 & 3, ks2 = (r1 >> 2) & 7, hh = r1 >> 5;
            int q = lane >> 4, n16 = lane & 15;
            float v = mW2[((size_t)(l * NH + hh) * 256 + ks2 * 32 + q * 8 + j) * 64
                          + nt * 16 + n16];
            W2sw[t2] = (_Float16)v;
        }
    }
}

// ---------------------------------------------------------------------------
// Embedding — round-0 proven; used by FALLBACK path only (fast path fuses it).
// ---------------------------------------------------------------------------
__global__ __launch_bounds__(64)
void embed_kernel(const float* __restrict__ fea, const float* __restrict__ W,
                  const float* __restrict__ b, const float* __restrict__ wts,
                  float* __restrict__ x)
{
    int n = blockIdx.x;
    int o = threadIdx.x;
    __shared__ float fs[EMBD];
    for (int e = o; e < EMBD; e += 64) fs[e] = fea[n * EMBD + e];
    __syncthreads();
    if (o < F - 1) {
        float acc = b[o];
#pragma unroll 8
        for (int e = 0; e < EMBD; ++e) acc += fs[e] * W[e * (F - 1) + o];
        x[n * F + o] = acc;
    } else {
        x[n * F + F - 1] = wts[n];
    }
}

// ---------------------------------------------------------------------------
// Round 18/19: net_wave — FUSED embed + 3 layers + pool in ONE dispatch.
// Round 19: per-chunk bias/gate-W2 f32->f16 runtime conversion replaced by
// precomputed f16 tables (biasH) — 3 half8 loads per ks vs 6 float4 loads +
// ~40 v_cvt per chunk. h2 extraction from half8 is free sub-register use.
// l-loop rolled (unroll spills, r13). x never touches HBM.
// ---------------------------------------------------------------------------
#define WAVE_LDS 12288   // bytes per wave slice
#define XFS 68           // xF row stride (floats); 272 B = 16-aligned

__global__ __launch_bounds__(256, 2)
void net_wave(const float* __restrict__ fea, const float* __restrict__ embB,
              const _Float16* __restrict__ embWsw,
              const _Float16* __restrict__ W1sw,
              const _Float16* __restrict__ W2sw,
              const _Float16* __restrict__ biasH,
              const float* __restrict__ mb2, const float* __restrict__ gb2v,
              const float* __restrict__ gpw,
              const _Float16* __restrict__ cW1sw,
              const _Float16* __restrict__ cW2sw,
              const float* __restrict__ cgb2v, const float* __restrict__ cmb2,
              const float* __restrict__ cpw,
              const float* __restrict__ wts, float* __restrict__ out, int Ntot)
{
    __shared__ __align__(16) char smem[4 * WAVE_LDS];

    const int t = threadIdx.x, w = t >> 6, lane = t & 63;
    const int q = lane >> 4, m16 = lane & 15;

    char* wb = smem + w * WAVE_LDS;
    _Float16 (*PQ)[16][72] = (_Float16 (*)[16][72])wb;   // [4][16][72] = 9216 B
    _Float16 (*msgL)[72]   = (_Float16 (*)[72])wb;       // [80][72] (aliases PQ)
    _Float16 (*xS)[72]     = (_Float16 (*)[72])(wb + 9216); // [16][72] A-rebuild buf
    float* gateS  = (float*)(wb + 11520);                // [80]
    float* anormS = (float*)(wb + 11840);                // [80]
    float* wpowS  = (float*)(wb + 12160);                // [16]

    const int nw0 = (blockIdx.x * 12 + w * CW) * K;      // first node of this wave
    const int c0  = blockIdx.x * 12 + w * CW;            // first crystal
    const int Ctot = Ntot / K;
    const int vc  = (Ctot - c0 < CW) ? (Ctot - c0) : CW;

    // ======================= fused embed =======================
    // xF[node][o] fp32 lives in the (currently dead) PQ region.
    float* xF = (float*)wb;
    {
        int arow = nw0 + m16;
        if (arow > Ntot - 1) arow = Ntot - 1;            // clamp pad rows
        if (arow < 0) arow = 0;
        const float* fr = fea + (size_t)arow * EMBD;
        f32x4 accE[4];
#pragma unroll
        for (int nt = 0; nt < 4; ++nt) accE[nt] = (f32x4){0.f, 0.f, 0.f, 0.f};
#pragma unroll
        for (int kk = 0; kk < 7; ++kk) {
            half8 Bf;
            if (kk < 6 || q == 0) {                      // kk==6,q>=1 -> cols>=200
                float4 f0 = *(const float4*)(fr + kk * 32 + q * 8);
                float4 f1 = *(const float4*)(fr + kk * 32 + q * 8 + 4);
                Bf[0]=(_Float16)f0.x; Bf[1]=(_Float16)f0.y;
                Bf[2]=(_Float16)f0.z; Bf[3]=(_Float16)f0.w;
                Bf[4]=(_Float16)f1.x; Bf[5]=(_Float16)f1.y;
                Bf[6]=(_Float16)f1.z; Bf[7]=(_Float16)f1.w;
            } else Bf = 0;
#pragma unroll
            for (int nt = 0; nt < 4; ++nt) {
                half8 Wf = *(const half8*)(embWsw + ((size_t)(kk * 4 + nt) * 64 + lane) * 8);
                accE[nt] = __builtin_amdgcn_mfma_f32_16x16x32_f16(Wf, Bf, accE[nt], 0, 0, 0);
            }
        }
        const float wv = wts[arow];
#pragma unroll
        for (int nt = 0; nt < 4; ++nt)
#pragma unroll
            for (int rg = 0; rg < 4; ++rg) {
                int o = nt * 16 + q * 4 + rg;
                float val = accE[nt][rg] + embB[o < F - 1 ? o : F - 2];
                if (o == F - 1) val = wv;                // weight column
                xF[m16 * XFS + o] = val;
            }
    }

    // residual copy (col=lane) + initial A-frags, both from xF
    float xcur[NWN];
#pragma unroll
    for (int n = 0; n < NWN; ++n) xcur[n] = xF[n * XFS + lane];
    half8 A[2];
#pragma unroll
    for (int ks = 0; ks < 2; ++ks) {
        float4 f0 = *(const float4*)&xF[m16 * XFS + ks * 32 + q * 8];
        float4 f1 = *(const float4*)&xF[m16 * XFS + ks * 32 + q * 8 + 4];
        half8 a;
        a[0] = (_Float16)f0.x; a[1] = (_Float16)f0.y;
        a[2] = (_Float16)f0.z; a[3] = (_Float16)f0.w;
        a[4] = (_Float16)f1.x; a[5] = (_Float16)f1.y;
        a[6] = (_Float16)f1.z; a[7] = (_Float16)f1.w;
        A[ks] = a;
    }

    // ---- per-lane edge -> local node rows (75 valid edges in 5 tiles of 16) ----
    int iR[ET], jR[ET];
#pragma unroll
    for (int et = 0; et < ET; ++et) {
        int e = et * 16 + m16;
        if (e < EWE) {
            int cl = e / 25, rm = e % 25;
            iR[et] = cl * K + rm / K;
            jR[et] = cl * K + rm % K;
        } else { iR[et] = 15; jR[et] = 15; }             // pad row (finite)
    }

    // ======================= 3 graph layers (rolled) =======================
#pragma clang loop unroll(disable)
    for (int l = 0; l < NL; ++l) {
        float oacc[NWN];
#pragma unroll
        for (int n = 0; n < NWN; ++n) oacc[n] = 0.f;

        for (int h = 0; h < NH; ++h) {
            const int lh = l * NH + h, lhw = lh;

            if (lane < NWN) {
                int wi = nw0 + lane;
                if (wi > Ntot - 1) wi = Ntot - 1;
                if (wi < 0) wi = 0;
                wpowS[lane] = powf(wts[wi], gpw[lh]);
            }
            if (lane >= NWN && lane < NWN + 5) anormS[EWE + (lane - NWN)] = 0.f;

            f32x4 acc2[ET][4];
#pragma unroll
            for (int et = 0; et < ET; ++et)
#pragma unroll
                for (int nt = 0; nt < 4; ++nt) acc2[et][nt] = (f32x4){0.f, 0.f, 0.f, 0.f};
            float gacc[ET] = {0.f, 0.f, 0.f, 0.f, 0.f};

            for (int c = 0; c < 4; ++c) {
                // ---- GEMM2 B-frags for this chunk ----
                half8 B2[8];
                {
                    const _Float16* W2b = W2sw + ((size_t)lhw * 8 + c * 2) * 2048;
#pragma unroll
                    for (int f = 0; f < 8; ++f)
                        B2[f] = *(const half8*)(W2b + ((size_t)f * 64 + lane) * 8);
                }

                // ---- stage-1: 4 net-halves, transposed mfma -> packed writes ----
#pragma unroll
                for (int hf = 0; hf < 4; ++hf) {
                    f32x4 accS[4];
#pragma unroll
                    for (int nt = 0; nt < 4; ++nt) accS[nt] = (f32x4){0.f, 0.f, 0.f, 0.f};
                    const _Float16* Wb = W1sw + ((size_t)lhw * 4 + hf) * 16384 + c * 4096;
#pragma unroll
                    for (int nt = 0; nt < 4; ++nt)
#pragma unroll
                        for (int ks = 0; ks < 2; ++ks) {
                            half8 B = *(const half8*)(Wb + ((nt * 2 + ks) * 64 + lane) * 8);
                            accS[nt] = __builtin_amdgcn_mfma_f32_16x16x32_f16(
                                B, A[ks], accS[nt], 0, 0, 0);
                        }
#pragma unroll
                    for (int nt = 0; nt < 4; ++nt) {
                        h2 lo = cvt_pk(accS[nt][0], accS[nt][1]);
                        h2 hi = cvt_pk(accS[nt][2], accS[nt][3]);
                        h4 pk = __builtin_shufflevector(lo, hi, 0, 1, 2, 3);
                        *(h4*)&PQ[hf][m16][nt * 16 + q * 4] = pk;
                    }
                }

                // ---- per-chunk bias slices from precomputed f16 tables ----
                half8 bg8[2], bm8[2];
                h2 wgh2[2][4];
#pragma unroll
                for (int ks = 0; ks < 2; ++ks) {
                    const int ub = c * 64 + ks * 32 + q * 8;
                    bg8[ks] = *(const half8*)(biasH + BH_GB1 + (size_t)lh * HID + ub);
                    bm8[ks] = *(const half8*)(biasH + BH_MB1 + (size_t)lh * HID + ub);
                    half8 wv8 = *(const half8*)(biasH + BH_WG + (size_t)lh * HID + ub);
                    wgh2[ks][0] = __builtin_shufflevector(wv8, wv8, 0, 1);
                    wgh2[ks][1] = __builtin_shufflevector(wv8, wv8, 2, 3);
                    wgh2[ks][2] = __builtin_shufflevector(wv8, wv8, 4, 5);
                    wgh2[ks][3] = __builtin_shufflevector(wv8, wv8, 6, 7);
                }

                // ---- consume: gate fdot2 + hm A-frags + GEMM2 ----
#pragma unroll
                for (int et = 0; et < ET; ++et) {
                    half8 af[2];
#pragma unroll
                    for (int ks = 0; ks < 2; ++ks) {
                        const int ub = ks * 32 + q * 8;
                        half8 pg = *(const half8*)&PQ[0][iR[et]][ub];
                        half8 qg = *(const half8*)&PQ[1][jR[et]][ub];
                        half8 pm = *(const half8*)&PQ[2][iR[et]][ub];
                        half8 qm = *(const half8*)&PQ[3][jR[et]][ub];
                        half8 tg = lrelu8(pg + qg + bg8[ks]);
                        h2 t01 = __builtin_shufflevector(tg, tg, 0, 1);
                        h2 t23 = __builtin_shufflevector(tg, tg, 2, 3);
                        h2 t45 = __builtin_shufflevector(tg, tg, 4, 5);
                        h2 t67 = __builtin_shufflevector(tg, tg, 6, 7);
                        gacc[et] = __builtin_amdgcn_fdot2(t01, wgh2[ks][0], gacc[et], false);
                        gacc[et] = __builtin_amdgcn_fdot2(t23, wgh2[ks][1], gacc[et], false);
                        gacc[et] = __builtin_amdgcn_fdot2(t45, wgh2[ks][2], gacc[et], false);
                        gacc[et] = __builtin_amdgcn_fdot2(t67, wgh2[ks][3], gacc[et], false);
                        af[ks] = lrelu8(pm + qm + bm8[ks]);
                    }
#pragma unroll
                    for (int nt = 0; nt < 4; ++nt)
#pragma unroll
                        for (int ks = 0; ks < 2; ++ks)
                            acc2[et][nt] = __builtin_amdgcn_mfma_f32_16x16x32_f16(
                                af[ks], B2[ks * 4 + nt], acc2[et][nt], 0, 0, 0);
                }
            }

            // ---- gate reduce across quads ----
            const float gb2s = gb2v[lh];
#pragma unroll
            for (int et = 0; et < ET; ++et) {
                float g = gacc[et];
                g += __shfl_xor(g, 16);
                g += __shfl_xor(g, 32);
                if (q == 0) gateS[et * 16 + m16] = g + gb2s;
            }

            // ---- segment softmax ----
            if (lane < NWN) {
                const int cl5 = (lane / K) * K;
                float gg[K], mx = -1e30f;
#pragma unroll
                for (int jj = 0; jj < K; ++jj) {
                    gg[jj] = gateS[lane * K + jj];
                    mx = fmaxf(mx, gg[jj]);
                }
                float s = 0.f, wv[K];
#pragma unroll
                for (int jj = 0; jj < K; ++jj) {
                    wv[jj] = wpowS[cl5 + jj] * expf(gg[jj] - mx);
                    s += wv[jj];
                }
                float inv = 1.f / (s + 1e-10f) * (1.f / 3.f);  // fold head mean
#pragma unroll
                for (int jj = 0; jj < K; ++jj) anormS[lane * K + jj] = wv[jj] * inv;
            }

            // ---- weighted msg -> msgL ----
            float b2v[4];
#pragma unroll
            for (int nt = 0; nt < 4; ++nt) b2v[nt] = mb2[(size_t)lh * F + nt * 16 + m16];
#pragma unroll
            for (int et = 0; et < ET; ++et) {
                f32x4 an = *(const f32x4*)&anormS[et * 16 + q * 4];
#pragma unroll
                for (int nt = 0; nt < 4; ++nt)
#pragma unroll
                    for (int rg = 0; rg < 4; ++rg) {
                        float v = (acc2[et][nt][rg] + b2v[nt]) * an[rg];
                        msgL[et * 16 + q * 4 + rg][nt * 16 + m16] = (_Float16)v;
                    }
            }

            // ---- aggregate ----
#pragma unroll
            for (int n = 0; n < NWN; ++n) {
                float s = 0.f;
#pragma unroll
                for (int jj = 0; jj < K; ++jj) s += (float)msgL[n * K + jj][lane];
                oacc[n] += s;
            }
        }

        // ---- residual in regs + A-frag rebuild via xS (dead region) ----
#pragma unroll
        for (int n = 0; n < NWN; ++n) {
            float xn = oacc[n] + xcur[n];
            xcur[n] = xn;
            xS[n][lane] = (_Float16)xn;
        }
        xS[15][lane] = (_Float16)0.f;                    // pad row finite
#pragma unroll
        for (int ks = 0; ks < 2; ++ks)
            A[ks] = *(const half8*)&xS[m16][ks * 32 + q * 8];
    }

    // ======================= pool (round-15 proven body) =======================
    _Float16 (*PQp)[16][72] = (_Float16 (*)[16][72])wb;  // [2][16][72]
    _Float16 (*msgP)[72]    = (_Float16 (*)[72])wb;      // [16][72] (aliases PQp)

    float oaccP[CW] = {0.f, 0.f, 0.f};

    for (int h = 0; h < NH; ++h) {
        if (lane < NWN) {
            int wi = nw0 + lane;
            if (wi > Ntot - 1) wi = Ntot - 1;
            if (wi < 0) wi = 0;
            wpowS[lane] = powf(wts[wi], cpw[h]);
        }
        if (lane == NWN) anormS[15] = 0.f;               // pad node row

        f32x4 acc2[4];
#pragma unroll
        for (int nt = 0; nt < 4; ++nt) acc2[nt] = (f32x4){0.f, 0.f, 0.f, 0.f};
        float gacc = 0.f;

        for (int c = 0; c < 4; ++c) {
            half8 B2[8];
            {
                const _Float16* W2b = cW2sw + (size_t)h * 16384 + c * 4096;
#pragma unroll
                for (int f = 0; f < 8; ++f)
                    B2[f] = *(const half8*)(W2b + ((size_t)f * 64 + lane) * 8);
            }

#pragma unroll
            for (int net = 0; net < 2; ++net) {
                f32x4 accS[4];
#pragma unroll
                for (int nt = 0; nt < 4; ++nt) accS[nt] = (f32x4){0.f, 0.f, 0.f, 0.f};
                const _Float16* Wb = cW1sw + ((size_t)(h * 2 + net) * 4 + c) * 4096;
#pragma unroll
                for (int nt = 0; nt < 4; ++nt)
#pragma unroll
                    for (int ks = 0; ks < 2; ++ks) {
                        half8 B = *(const half8*)(Wb + ((nt * 2 + ks) * 64 + lane) * 8);
                        accS[nt] = __builtin_amdgcn_mfma_f32_16x16x32_f16(
                            B, A[ks], accS[nt], 0, 0, 0);
                    }
#pragma unroll
                for (int nt = 0; nt < 4; ++nt) {
                    h2 lo = cvt_pk(accS[nt][0], accS[nt][1]);
                    h2 hi = cvt_pk(accS[nt][2], accS[nt][3]);
                    h4 pk = __builtin_shufflevector(lo, hi, 0, 1, 2, 3);
                    *(h4*)&PQp[net][m16][nt * 16 + q * 4] = pk;
                }
            }

            // ---- bias slices from precomputed f16 tables ----
            half8 bg8[2], bm8[2];
            h2 wgh2[2][4];
#pragma unroll
            for (int ks = 0; ks < 2; ++ks) {
                const int ub = c * 64 + ks * 32 + q * 8;
                bg8[ks] = *(const half8*)(biasH + BH_CGB1 + (size_t)h * HID + ub);
                bm8[ks] = *(const half8*)(biasH + BH_CMB1 + (size_t)h * HID + ub);
                half8 wv8 = *(const half8*)(biasH + BH_CWG + (size_t)h * HID + ub);
                wgh2[ks][0] = __builtin_shufflevector(wv8, wv8, 0, 1);
                wgh2[ks][1] = __builtin_shufflevector(wv8, wv8, 2, 3);
                wgh2[ks][2] = __builtin_shufflevector(wv8, wv8, 4, 5);
                wgh2[ks][3] = __builtin_shufflevector(wv8, wv8, 6, 7);
            }

            {
                half8 af[2];
#pragma unroll
                for (int ks = 0; ks < 2; ++ks) {
                    const int ub = ks * 32 + q * 8;
                    half8 pg = *(const half8*)&PQp[0][m16][ub];
                    half8 pm = *(const half8*)&PQp[1][m16][ub];
                    half8 tg = lrelu8(pg + bg8[ks]);
                    h2 t01 = __builtin_shufflevector(tg, tg, 0, 1);
                    h2 t23 = __builtin_shufflevector(tg, tg, 2, 3);
                    h2 t45 = __builtin_shufflevector(tg, tg, 4, 5);
                    h2 t67 = __builtin_shufflevector(tg, tg, 6, 7);
                    gacc = __builtin_amdgcn_fdot2(t01, wgh2[ks][0], gacc, false);
                    gacc = __builtin_amdgcn_fdot2(t23, wgh2[ks][1], gacc, false);
                    gacc = __builtin_amdgcn_fdot2(t45, wgh2[ks][2], gacc, false);
                    gacc = __builtin_amdgcn_fdot2(t67, wgh2[ks][3], gacc, false);
                    af[ks] = lrelu8(pm + bm8[ks]);
                }
#pragma unroll
                for (int nt = 0; nt < 4; ++nt)
#pragma unroll
                    for (int ks = 0; ks < 2; ++ks)
                        acc2[nt] = __builtin_amdgcn_mfma_f32_16x16x32_f16(
                            af[ks], B2[ks * 4 + nt], acc2[nt], 0, 0, 0);
            }
        }

        const float gb2s = cgb2v[h];
        {
            float g = gacc;
            g += __shfl_xor(g, 16);
            g += __shfl_xor(g, 32);
            if (q == 0) gateS[m16] = g + gb2s;
        }

        if (lane < CW) {
            const int n0 = lane * K;
            float gg[K], mx = -1e30f;
#pragma unroll
            for (int jj = 0; jj < K; ++jj) {
                gg[jj] = gateS[n0 + jj];
                mx = fmaxf(mx, gg[jj]);
            }
            float s = 0.f, wv[K];
#pragma unroll
            for (int jj = 0; jj < K; ++jj) {
                wv[jj] = wpowS[n0 + jj] * expf(gg[jj] - mx);
                s += wv[jj];
            }
            float inv = 1.f / (s + 1e-10f) * (1.f / 3.f);
#pragma unroll
            for (int jj = 0; jj < K; ++jj) anormS[n0 + jj] = wv[jj] * inv;
        }

        float b2v[4];
#pragma unroll
        for (int nt = 0; nt < 4; ++nt) b2v[nt] = cmb2[(size_t)h * F + nt * 16 + m16];
#pragma unroll
        for (int nt = 0; nt < 4; ++nt)
#pragma unroll
            for (int rg = 0; rg < 4; ++rg) {
                int row = q * 4 + rg;
                float v = (acc2[nt][rg] + b2v[nt]) * anormS[row];
                msgP[row][nt * 16 + m16] = (_Float16)v;
            }

#pragma unroll
        for (int cl = 0; cl < CW; ++cl) {
            float s = 0.f;
#pragma unroll
            for (int jj = 0; jj < K; ++jj) s += (float)msgP[cl * K + jj][lane];
            oaccP[cl] += s;
        }
    }

#pragma unroll
    for (int cl = 0; cl < CW; ++cl)
        if (cl < vc)
            out[(size_t)(c0 + cl) * F + lane] = oaccP[cl];
}

// ---------------------------------------------------------------------------
// Fallback layer kernel (round-12 proven, writes x) — used when ws too small.
// ---------------------------------------------------------------------------
__global__ __launch_bounds__(256, 2)
void layer_wave(float* __restrict__ x,
                const _Float16* __restrict__ W1sw,
                const _Float16* __restrict__ W2sw,
                const float* __restrict__ gb1, const float* __restrict__ gb2v,
                const float* __restrict__ mb1, const float* __restrict__ mb2,
                const float* __restrict__ gW2, const float* __restrict__ gpw,
                const float* __restrict__ wts, int l, int lhw0, int Ntot)
{
    __shared__ __align__(16) char smem[4 * WAVE_LDS];

    const int t = threadIdx.x, w = t >> 6, lane = t & 63;
    const int q = lane >> 4, m16 = lane & 15;

    char* wb = smem + w * WAVE_LDS;
    _Float16 (*PQ)[16][72] = (_Float16 (*)[16][72])wb;
    _Float16 (*msgL)[72]   = (_Float16 (*)[72])wb;
    float* gateS  = (float*)(wb + 11520);
    float* anormS = (float*)(wb + 11840);
    float* wpowS  = (float*)(wb + 12160);

    const int nw0 = (blockIdx.x * 12 + w * CW) * K;
    const int vn  = (Ntot - nw0 < NWN) ? (Ntot - nw0) : NWN;

    half8 A[2];
    {
        int arow = nw0 + m16;
        if (arow > Ntot - 1) arow = Ntot - 1;
        if (arow < 0) arow = 0;
        const float* xr = x + (size_t)arow * F;
#pragma unroll
        for (int ks = 0; ks < 2; ++ks) {
            float4 f0 = *(const float4*)(xr + ks * 32 + q * 8);
            float4 f1 = *(const float4*)(xr + ks * 32 + q * 8 + 4);
            half8 a;
            a[0] = (_Float16)f0.x; a[1] = (_Float16)f0.y;
            a[2] = (_Float16)f0.z; a[3] = (_Float16)f0.w;
            a[4] = (_Float16)f1.x; a[5] = (_Float16)f1.y;
            a[6] = (_Float16)f1.z; a[7] = (_Float16)f1.w;
            A[ks] = a;
        }
    }

    int iR[ET], jR[ET];
#pragma unroll
    for (int et = 0; et < ET; ++et) {
        int e = et * 16 + m16;
        if (e < EWE) {
            int cl = e / 25, rm = e % 25;
            iR[et] = cl * K + rm / K;
            jR[et] = cl * K + rm % K;
        } else { iR[et] = 15; jR[et] = 15; }
    }

    float oacc[NWN];
#pragma unroll
    for (int n = 0; n < NWN; ++n) oacc[n] = 0.f;

    for (int h = 0; h < NH; ++h) {
        const int lh = l * NH + h, lhw = lhw0 + h;

        if (lane < NWN) {
            int wi = nw0 + lane;
            if (wi > Ntot - 1) wi = Ntot - 1;
            if (wi < 0) wi = 0;
            wpowS[lane] = powf(wts[wi], gpw[lh]);
        }
        if (lane >= NWN && lane < NWN + 5) anormS[EWE + (lane - NWN)] = 0.f;

        f32x4 acc2[ET][4];
#pragma unroll
        for (int et = 0; et < ET; ++et)
#pragma unroll
            for (int nt = 0; nt < 4; ++nt) acc2[et][nt] = (f32x4){0.f, 0.f, 0.f, 0.f};
        float gacc[ET] = {0.f, 0.f, 0.f, 0.f, 0.f};

        for (int c = 0; c < 4; ++c) {
            half8 B2[8];
            {
                const _Float16* W2b = W2sw + ((size_t)lhw * 8 + c * 2) * 2048;
#pragma unroll
                for (int f = 0; f < 8; ++f)
                    B2[f] = *(const half8*)(W2b + ((size_t)f * 64 + lane) * 8);
            }

#pragma unroll
            for (int hf = 0; hf < 4; ++hf) {
                f32x4 accS[4];
#pragma unroll
                for (int nt = 0; nt < 4; ++nt) accS[nt] = (f32x4){0.f, 0.f, 0.f, 0.f};
                const _Float16* Wb = W1sw + ((size_t)lhw * 4 + hf) * 16384 + c * 4096;
#pragma unroll
                for (int nt = 0; nt < 4; ++nt)
#pragma unroll
                    for (int ks = 0; ks < 2; ++ks) {
                        half8 B = *(const half8*)(Wb + ((nt * 2 + ks) * 64 + lane) * 8);
                        accS[nt] = __builtin_amdgcn_mfma_f32_16x16x32_f16(
                            B, A[ks], accS[nt], 0, 0, 0);
                    }
#pragma unroll
                for (int nt = 0; nt < 4; ++nt) {
                    h2 lo = cvt_pk(accS[nt][0], accS[nt][1]);
                    h2 hi = cvt_pk(accS[nt][2], accS[nt][3]);
                    h4 pk = __builtin_shufflevector(lo, hi, 0, 1, 2, 3);
                    *(h4*)&PQ[hf][m16][nt * 16 + q * 4] = pk;
                }
            }

            half8 bg8[2], bm8[2];
            h2 wgh2[2][4];
#pragma unroll
            for (int ks = 0; ks < 2; ++ks) {
                const int ub = c * 64 + ks * 32 + q * 8;
                float4 g0 = *(const float4*)(gb1 + (size_t)lh * HID + ub);
                float4 g1 = *(const float4*)(gb1 + (size_t)lh * HID + ub + 4);
                float4 m0 = *(const float4*)(mb1 + (size_t)lh * HID + ub);
                float4 m1 = *(const float4*)(mb1 + (size_t)lh * HID + ub + 4);
                float4 w0 = *(const float4*)(gW2 + (size_t)lh * HID + ub);
                float4 w1 = *(const float4*)(gW2 + (size_t)lh * HID + ub + 4);
                half8 bg, bm;
                bg[0]=(_Float16)g0.x; bg[1]=(_Float16)g0.y; bg[2]=(_Float16)g0.z; bg[3]=(_Float16)g0.w;
                bg[4]=(_Float16)g1.x; bg[5]=(_Float16)g1.y; bg[6]=(_Float16)g1.z; bg[7]=(_Float16)g1.w;
                bm[0]=(_Float16)m0.x; bm[1]=(_Float16)m0.y; bm[2]=(_Float16)m0.z; bm[3]=(_Float16)m0.w;
                bm[4]=(_Float16)m1.x; bm[5]=(_Float16)m1.y; bm[6]=(_Float16)m1.z; bm[7]=(_Float16)m1.w;
                bg8[ks] = bg; bm8[ks] = bm;
                wgh2[ks][0] = cvt_pk(w0.x, w0.y);
                wgh2[ks][1] = cvt_pk(w0.z, w0.w);
                wgh2[ks][2] = cvt_pk(w1.x, w1.y);
                wgh2[ks][3] = cvt_pk(w1.z, w1.w);
            }

#pragma unroll
            for (int et = 0; et < ET; ++et) {
                half8 af[2];
#pragma unroll
                for (int ks = 0; ks < 2; ++ks) {
                    const int ub = ks * 32 + q * 8;
                    half8 pg = *(const half8*)&PQ[0][iR[et]][ub];
                    half8 qg = *(const half8*)&PQ[1][jR[et]][ub];
                    half8 pm = *(const half8*)&PQ[2][iR[et]][ub];
                    half8 qm = *(const half8*)&PQ[3][jR[et]][ub];
                    half8 tg = lrelu8(pg + qg + bg8[ks]);
                    h2 t01 = __builtin_shufflevector(tg, tg, 0, 1);
                    h2 t23 = __builtin_shufflevector(tg, tg, 2, 3);
                    h2 t45 = __builtin_shufflevector(tg, tg, 4, 5);
                    h2 t67 = __builtin_shufflevector(tg, tg, 6, 7);
                    gacc[et] = __builtin_amdgcn_fdot2(t01, wgh2[ks][0], gacc[et], false);
                    gacc[et] = __builtin_amdgcn_fdot2(t23, wgh2[ks][1], gacc[et], false);
                    gacc[et] = __builtin_amdgcn_fdot2(t45, wgh2[ks][2], gacc[et], false);
                    gacc[et] = __builtin_amdgcn_fdot2(t67, wgh2[ks][3], gacc[et], false);
                    af[ks] = lrelu8(pm + qm + bm8[ks]);
                }
#pragma unroll
                for (int nt = 0; nt < 4; ++nt)
#pragma unroll
                    for (int ks = 0; ks < 2; ++ks)
                        acc2[et][nt] = __builtin_amdgcn_mfma_f32_16x16x32_f16(
                            af[ks], B2[ks * 4 + nt], acc2[et][nt], 0, 0, 0);
            }
        }

        const float gb2s = gb2v[lh];
#pragma unroll
        for (int et = 0; et < ET; ++et) {
            float g = gacc[et];
            g += __shfl_xor(g, 16);
            g += __shfl_xor(g, 32);
            if (q == 0) gateS[et * 16 + m16] = g + gb2s;
        }

        if (lane < NWN) {
            const int cl5 = (lane / K) * K;
            float gg[K], mx = -1e30f;
#pragma unroll
            for (int jj = 0; jj < K; ++jj) {
                gg[jj] = gateS[lane * K + jj];
                mx = fmaxf(mx, gg[jj]);
            }
            float s = 0.f, wv[K];
#pragma unroll
            for (int jj = 0; jj < K; ++jj) {
                wv[jj] = wpowS[cl5 + jj] * expf(gg[jj] - mx);
                s += wv[jj];
            }
            float inv = 1.f / (s + 1e-10f) * (1.f / 3.f);
#pragma unroll
            for (int jj = 0; jj < K; ++jj) anormS[lane * K + jj] = wv[jj] * inv;
        }

        float b2v[4];
#pragma unroll
        for (int nt = 0; nt < 4; ++nt) b2v[nt] = mb2[(size_t)lh * F + nt * 16 + m16];
#pragma unroll
        for (int et = 0; et < ET; ++et) {
            f32x4 an = *(const f32x4*)&anormS[et * 16 + q * 4];
#pragma unroll
            for (int nt = 0; nt < 4; ++nt)
#pragma unroll
                for (int rg = 0; rg < 4; ++rg) {
                    float v = (acc2[et][nt][rg] + b2v[nt]) * an[rg];
                    msgL[et * 16 + q * 4 + rg][nt * 16 + m16] = (_Float16)v;
                }
        }

#pragma unroll
        for (int n = 0; n < NWN; ++n) {
            float s = 0.f;
#pragma unroll
            for (int jj = 0; jj < K; ++jj) s += (float)msgL[n * K + jj][lane];
            oacc[n] += s;
        }
    }

#pragma unroll
    for (int n = 0; n < NWN; ++n) {
        if (n < vn) {
            size_t idx = (size_t)(nw0 + n) * F + lane;
            x[idx] = oacc[n] + x[idx];
        }
    }
}

// ---------------------------------------------------------------------------
// Fallback fp32 pool (round-4 proven)
// ---------------------------------------------------------------------------
__global__ __launch_bounds__(256)
void pool_kernel(const float* __restrict__ x,
                 const float* __restrict__ cgW1, const float* __restrict__ cgb1,
                 const float* __restrict__ cgW2, const float* __restrict__ cgb2,
                 const float* __restrict__ cmW1, const float* __restrict__ cmb1,
                 const float* __restrict__ cmW2, const float* __restrict__ cmb2,
                 const float* __restrict__ cpw, const float* __restrict__ wts,
                 float* __restrict__ out)
{
    __shared__ float xs[K * F];
    __shared__ float hmS[K][HID];
    __shared__ float msgS[K][F];
    __shared__ float outacc[F];
    __shared__ float b1g[HID], b1m[HID], w2g[HID];
    __shared__ float b2mS[F];
    __shared__ float gpart[K][2];
    __shared__ float gate_s[K];
    __shared__ float anorm[K];
    __shared__ float wn[K], wpow[K];

    const int c = blockIdx.x;
    const int t = threadIdx.x;
    const int wave = t >> 6, lane = t & 63;

    for (int d = t; d < K * F; d += 256) xs[d] = x[c * K * F + d];
    if (t < F) outacc[t] = 0.f;
    if (t < K) wn[t] = wts[c * K + t];
    __syncthreads();

    for (int h = 0; h < NH; ++h) {
        if (t < HID) {
            b1g[t] = cgb1[(size_t)h * HID + t];
            b1m[t] = cmb1[(size_t)h * HID + t];
            w2g[t] = cgW2[(size_t)h * HID + t];
        }
        if (t < F) b2mS[t] = cmb2[(size_t)h * F + t];
        if (t < K) wpow[t] = powf(wn[t], cpw[h]);
        __syncthreads();

        {
            const int grp = t >> 7;
            const int up  = t & 127;
            const float* Wb = (grp == 0 ? cgW1 : cmW1) + (size_t)h * F * HID;
            const float2* W2p = (const float2*)Wb;
            float acc[K][2];
#pragma unroll
            for (int i = 0; i < K; ++i) { acc[i][0] = 0.f; acc[i][1] = 0.f; }
            for (int k = 0; k < F; ++k) {
                float2 wv = W2p[k * (HID / 2) + up];
#pragma unroll
                for (int i = 0; i < K; ++i) {
                    float xv = xs[i * F + k];
                    acc[i][0] += xv * wv.x;
                    acc[i][1] += xv * wv.y;
                }
            }
            if (grp == 0) {
#pragma unroll
                for (int i = 0; i < K; ++i) {
                    float h0 = lrelu(acc[i][0] + b1g[2 * up]);
                    float h1 = lrelu(acc[i][1] + b1g[2 * up + 1]);
                    float part = h0 * w2g[2 * up] + h1 * w2g[2 * up + 1];
#pragma unroll
                    for (int s = 32; s; s >>= 1) part += __shfl_xor(part, s);
                    if (lane == 0) gpart[i][wave & 1] = part;
                }
            } else {
#pragma unroll
                for (int i = 0; i < K; ++i) {
                    hmS[i][2 * up]     = lrelu(acc[i][0] + b1m[2 * up]);
                    hmS[i][2 * up + 1] = lrelu(acc[i][1] + b1m[2 * up + 1]);
                }
            }
        }
        __syncthreads();
        if (t < K) gate_s[t] = cgb2[h] + gpart[t][0] + gpart[t][1];

        {
            const float2* W232 = (const float2*)(cmW2 + (size_t)h * HID * F);
            if (t < K * (F / 2)) {
                int i  = t >> 5;
                int op = t & 31;
                float a0 = b2mS[2 * op], a1 = b2mS[2 * op + 1];
#pragma unroll 8
                for (int u = 0; u < HID; ++u) {
                    float2 wv = W232[u * (F / 2) + op];
                    float hv = hmS[i][u];
                    a0 += hv * wv.x;
                    a1 += hv * wv.y;
                }
                msgS[i][2 * op]     = a0;
                msgS[i][2 * op + 1] = a1;
            }
        }
        __syncthreads();

        if (t == 0) {
            float mx = -1e30f;
#pragma unroll
            for (int i = 0; i < K; ++i) mx = fmaxf(mx, gate_s[i]);
            float wv[K], s = 0.f;
#pragma unroll
            for (int i = 0; i < K; ++i) {
                wv[i] = wpow[i] * expf(gate_s[i] - mx);
                s += wv[i];
            }
            float inv = 1.f / (s + 1e-10f);
#pragma unroll
            for (int i = 0; i < K; ++i) anorm[i] = wv[i] * inv;
        }
        __syncthreads();

        if (t < F) {
            float s = 0.f;
#pragma unroll
            for (int i = 0; i < K; ++i) s += anorm[i] * msgS[i][t];
            outacc[t] += s * (1.f / 3.f);
        }
        __syncthreads();
    }

    if (t < F) out[(size_t)c * F + t] = outacc[t];
}

// ---------------------------------------------------------------------------
extern "C" void kernel_launch(void* const* d_in, const int* in_sizes, int n_in,
                              void* d_out, int out_size, void* d_ws, size_t ws_size,
                              hipStream_t stream)
{
    const float* wts  = (const float*)d_in[0];
    const float* fea  = (const float*)d_in[1];
    const float* embW = (const float*)d_in[6];
    const float* embB = (const float*)d_in[7];
    const float* gW1  = (const float*)d_in[8];
    const float* gb1  = (const float*)d_in[9];
    const float* gW2  = (const float*)d_in[10];
    const float* gb2  = (const float*)d_in[11];
    const float* mW1  = (const float*)d_in[12];
    const float* mb1  = (const float*)d_in[13];
    const float* mW2  = (const float*)d_in[14];
    const float* mb2  = (const float*)d_in[15];
    const float* gpw  = (const float*)d_in[16];
    const float* cgW1 = (const float*)d_in[17];
    const float* cgb1 = (const float*)d_in[18];
    const float* cgW2 = (const float*)d_in[19];
    const float* cgb2 = (const float*)d_in[20];
    const float* cmW1 = (const float*)d_in[21];
    const float* cmb1 = (const float*)d_in[22];
    const float* cmW2 = (const float*)d_in[23];
    const float* cmb2 = (const float*)d_in[24];
    const float* cpw  = (const float*)d_in[25];

    const int N = in_sizes[0];   // 50000
    const int C = N / K;         // 10000
    const int layer_blocks = (C + 11) / 12;   // 834 (tail block guarded)

    float* x = (float*)d_ws;                       // [N,F] fp32 (fallback only)
    const size_t xbytes = (size_t)N * F * 4;
    const size_t need = xbytes + (size_t)WALL3_ELEMS * 2;

    if (ws_size >= need) {
        // ---- fast path: prep + ONE fused network kernel (embed included) ----
        _Float16* Wall  = (_Float16*)((char*)d_ws + xbytes);
        _Float16* W1sw  = Wall;
        _Float16* W2sw  = Wall + W1SW_ELEMS;
        _Float16* cW1sw = Wall + W1SW_ELEMS + W2SW_ELEMS;
        _Float16* cW2sw = Wall + W1SW_ELEMS + W2SW_ELEMS + CW1_ELEMS;
        _Float16* eWsw  = Wall + WALL_ELEMS;
        _Float16* biasH = Wall + WALL2_ELEMS;

        prep_all<<<(WALL3_ELEMS + 255) / 256, 256, 0, stream>>>(
            gW1, mW1, mW2, cgW1, cmW1, cmW2, embW,
            gb1, mb1, gW2, cgb1, cmb1, cgW2, Wall);
        net_wave<<<layer_blocks, 256, 0, stream>>>(
            fea, embB, eWsw, W1sw, W2sw, biasH, mb2, gb2, gpw,
            cW1sw, cW2sw, cgb2, cmb2, cpw,
            wts, (float*)d_out, N);
    } else {
        // ---- fallback: embed + per-layer prep into d_out scratch ----
        embed_kernel<<<N, 64, 0, stream>>>(fea, embW, embB, wts, x);
        _Float16* W1sw = (_Float16*)d_out;
        _Float16* W2sw = (_Float16*)((char*)d_out + 393216);
        for (int l = 0; l < NL; ++l) {
            prep_layer<<<(W1L_ELEMS + W2L_ELEMS) / 256, 256, 0, stream>>>(
                gW1, mW1, mW2, W1sw, W2sw, l);
            layer_wave<<<layer_blocks, 256, 0, stream>>>(x, W1sw, W2sw,
                                                         gb1, gb2, mb1, mb2, gW2, gpw, wts,
                                                         l, 0, N);
        }
        pool_kernel<<<C, 256, 0, stream>>>(x, cgW1, cgb1, cgW2, cgb2,
                                           cmW1, cmb1, cmW2, cmb2, cpw, wts,
                                           (float*)d_out);
    }
}